// Round 5
// baseline (645.582 us; speedup 1.0000x reference)
//
#include <hip/hip_runtime.h>
#include <cstdint>

#define S_LEN 4096
#define D_DIM 256

// workspace layout (float offsets)
#define OFF_MINP 0
#define OFF_WPT  16
#define OFF_WTH  (OFF_WPT + 768*256)     // WeffT hi, 768x768 ushort = 294912 floats
#define OFF_WTL  (OFF_WTH + 294912)      // WeffT lo
#define OFF_C    (OFF_WTL + 294912)      // == old OFF_C, downstream unchanged
#define OFF_HH   (OFF_C + 8*768*4096)
#define OFF_V    (OFF_HH + 8*2*256*4096)
#define OFF_U    (OFF_V + 8*256*4096)

// FF weight splits live at the head of the V region (vb is only written by
// k_conv_mfma #1, which runs AFTER k_ff has consumed these — stream-order safe).

typedef __attribute__((ext_vector_type(8))) short short8;
typedef __attribute__((ext_vector_type(4))) float f32x4;

__device__ __forceinline__ unsigned int f2bf(float x) {
    union { float f; unsigned int u; } v; v.f = x;
    unsigned int r = v.u + 0x7fffu + ((v.u >> 16) & 1u);   // RNE
    return r >> 16;
}
__device__ __forceinline__ float bf2f(unsigned int h) {
    union { unsigned int u; float f; } v; v.u = h << 16; return v.f;
}

// ---------------- min valid position per batch ----------------
__global__ __launch_bounds__(256) void k_minpos(const int* __restrict__ pos, float* __restrict__ minp)
{
    const int b = blockIdx.x;
    const int tid = threadIdx.x;
    int mn = 0x7fffffff;
    const int* p = pos + (size_t)b * S_LEN;
    for (int s = tid; s < S_LEN; s += 256) {
        const int v = p[s];
        if (v != -1) mn = min(mn, v);
    }
    __shared__ int red[256];
    red[tid] = mn;
    __syncthreads();
    for (int st = 128; st > 0; st >>= 1) {
        if (tid < st) red[tid] = min(red[tid], red[tid + st]);
        __syncthreads();
    }
    if (tid == 0) minp[b] = (float)red[0];
}

// ---------------- transpose W_proj (256x768) -> WpT (768x256) ----------------
__global__ __launch_bounds__(256) void k_wpt(const float* __restrict__ Wp, float* __restrict__ WpT)
{
    __shared__ float t[32][33];
    const int e0 = blockIdx.x * 32;   // 0..767
    const int d0 = blockIdx.y * 32;   // 0..255
    const int lx = threadIdx.x & 31, ly = threadIdx.x >> 5; // 32x8
#pragma unroll
    for (int q = 0; q < 4; ++q)
        t[ly + 8*q][lx] = Wp[(size_t)(d0 + ly + 8*q) * 768 + e0 + lx];
    __syncthreads();
#pragma unroll
    for (int q = 0; q < 4; ++q)
        WpT[(size_t)(e0 + ly + 8*q) * 256 + d0 + lx] = t[lx][ly + 8*q];
}

// ---------------- generic transpose + bf16 hi/lo split: W[K][N] -> out[N][K] ----------------
__global__ __launch_bounds__(256) void k_tsplit(const float* __restrict__ W, const int K, const int N,
                                                unsigned short* __restrict__ oh, unsigned short* __restrict__ ol)
{
    __shared__ float t[32][33];
    const int n0 = blockIdx.x * 32;
    const int k0 = blockIdx.y * 32;
    const int lx = threadIdx.x & 31, ly = threadIdx.x >> 5;
#pragma unroll
    for (int q = 0; q < 4; ++q)
        t[ly + 8*q][lx] = W[(size_t)(k0 + ly + 8*q) * N + n0 + lx];
    __syncthreads();
#pragma unroll
    for (int q = 0; q < 4; ++q) {
        const float v = t[lx][ly + 8*q];
        const unsigned int h = f2bf(v);
        oh[(size_t)(n0 + ly + 8*q) * K + k0 + lx] = (unsigned short)h;
        ol[(size_t)(n0 + ly + 8*q) * K + k0 + lx] = (unsigned short)f2bf(v - bf2f(h));
    }
}

// ---------------- WeffT[o][t*256+d] = sum_i WpT[g*256+i][d] * conv_w[o][i][t], split hi/lo bf16 ----------------
__global__ __launch_bounds__(256) void k_weff(const float* __restrict__ WpT, const float* __restrict__ cw,
                                              unsigned short* __restrict__ wth, unsigned short* __restrict__ wtl)
{
    const int o = blockIdx.x;       // 768
    const int d = threadIdx.x;      // 256
    const int g = o >> 8;
    __shared__ float cwrow[768];
    for (int i = threadIdx.x; i < 768; i += 256) cwrow[i] = cw[(size_t)o * 768 + i];
    __syncthreads();
    float a0 = 0.f, a1 = 0.f, a2 = 0.f;
    const float* wb = WpT + (size_t)(g * 256) * 256 + d;
#pragma unroll 4
    for (int i = 0; i < 256; ++i) {
        const float wv = wb[(size_t)i * 256];
        a0 += wv * cwrow[i*3+0];
        a1 += wv * cwrow[i*3+1];
        a2 += wv * cwrow[i*3+2];
    }
    const float av[3] = {a0, a1, a2};
#pragma unroll
    for (int t = 0; t < 3; ++t) {
        const unsigned int hb = f2bf(av[t]);
        const unsigned int lb = f2bf(av[t] - bf2f(hb));
        wth[(size_t)o * 768 + t * 256 + d] = (unsigned short)hb;
        wtl[(size_t)o * 768 + t * 256 + d] = (unsigned short)lb;
    }
}

// ---------------- MFMA conv-GEMM: c[b][o][s] = mask*(conv_b[o] + sum_{t,d} emb[b][s+t-1][d]*Weff[t][d][o]) ----
// 256(s) x 128(o) block tile, 4 waves each owning 64 s x 128 o (mt=4) — halves LDS-port
// traffic per FLOP vs mt=2 (B-frags feed 8 MFMAs each). 2-pass split (A bf16 RNE, B hi/lo),
// reg-prefetched staging (identical structure to the verified mt=2 version).
#define CG_LDA 40   // 32 + 8 pad (16B frag alignment preserved: 80B rows)
__global__ __launch_bounds__(256, 2) void k_convgemm(
    const float* __restrict__ emb, const int* __restrict__ pos,
    const unsigned short* __restrict__ wth, const unsigned short* __restrict__ wtl,
    const float* __restrict__ convb, float* __restrict__ c)
{
    const int b  = blockIdx.z;
    const int o0 = blockIdx.y * 128;
    const int s0 = blockIdx.x * 256;
    const int tid  = threadIdx.x;
    const int wave = tid >> 6, lane = tid & 63;
    const int m16  = lane & 15, quad = lane >> 4;

    __shared__ __align__(16) unsigned short As[258 * CG_LDA];
    __shared__ __align__(16) unsigned short Bh[128 * CG_LDA];
    __shared__ __align__(16) unsigned short Bl[128 * CG_LDA];

    // A staging: thread t -> row r = t (0..255), all 32 k-cols of the chunk
    const int rA = tid;
    const int srowA = s0 + rA - 1;
    const bool vA = (srowA >= 0 && srowA < S_LEN);
    const float* embA = emb + ((size_t)b * S_LEN + (vA ? srowA : 0)) * D_DIM;
    // A tail rows 256..257: threads 0..15, 4 k-cols each (8 chunks x 2 rows)
    const int rT = 256 + (tid >> 3);
    const int cT = (tid & 7) * 4;
    const int srowT = s0 + rT - 1;
    const bool vT = (tid < 16) && (srowT >= 0 && srowT < S_LEN);
    const float* embT = emb + ((size_t)b * S_LEN + ((tid < 16 && vT) ? srowT : 0)) * D_DIM + cT;

    // B staging: tasks {tid, tid+256}: row task>>2, 8 k-cols at (task&3)*8
    const int rB0 = tid >> 2,        gB0 = (tid & 3) * 8;
    const int rB1 = 64 + (tid >> 2), gB1 = gB0;

    float4 apf[8]; float4 apfT;
    uint4 bph0, bpl0, bph1, bpl1;

    // preload A(c8=0) and B(seg 0: t=0,c8=0)
#pragma unroll
    for (int q = 0; q < 8; ++q) apf[q] = vA ? *(const float4*)(embA + q * 4) : make_float4(0.f,0.f,0.f,0.f);
    apfT = vT ? *(const float4*)(embT) : make_float4(0.f,0.f,0.f,0.f);
    {
        const size_t gi0 = (size_t)(o0 + rB0) * 768 + gB0;
        const size_t gi1 = (size_t)(o0 + rB1) * 768 + gB1;
        bph0 = *(const uint4*)(wth + gi0); bpl0 = *(const uint4*)(wtl + gi0);
        bph1 = *(const uint4*)(wth + gi1); bpl1 = *(const uint4*)(wtl + gi1);
    }

    f32x4 acc[4][8];
#pragma unroll
    for (int mt = 0; mt < 4; ++mt)
#pragma unroll
        for (int nt = 0; nt < 8; ++nt)
#pragma unroll
            for (int e = 0; e < 4; ++e) acc[mt][nt][e] = 0.f;

    for (int c8 = 0; c8 < 8; ++c8) {
        for (int t = 0; t < 3; ++t) {
            __syncthreads();   // consumers of previous tiles done
            if (t == 0) {
                // write A (bf16 RNE) from prefetch regs: 4 uint4s covering 32 k
#pragma unroll
                for (int q = 0; q < 4; ++q) {
                    const float4 v0 = apf[2*q], v1 = apf[2*q+1];
                    uint4 hp;
                    hp.x = f2bf(v0.x) | (f2bf(v0.y) << 16);
                    hp.y = f2bf(v0.z) | (f2bf(v0.w) << 16);
                    hp.z = f2bf(v1.x) | (f2bf(v1.y) << 16);
                    hp.w = f2bf(v1.z) | (f2bf(v1.w) << 16);
                    *(uint4*)&As[rA * CG_LDA + q * 8] = hp;
                }
                if (tid < 16) {
                    const float4 v = apfT;
                    uint2 hp;
                    hp.x = f2bf(v.x) | (f2bf(v.y) << 16);
                    hp.y = f2bf(v.z) | (f2bf(v.w) << 16);
                    *(uint2*)&As[rT * CG_LDA + cT] = hp;
                }
                if (c8 < 7) {
                    const int base = (c8 + 1) * 32;
#pragma unroll
                    for (int q = 0; q < 8; ++q) apf[q] = vA ? *(const float4*)(embA + base + q * 4) : make_float4(0.f,0.f,0.f,0.f);
                    apfT = vT ? *(const float4*)(embT + base) : make_float4(0.f,0.f,0.f,0.f);
                }
            }
            // write B from prefetch regs
            *(uint4*)&Bh[rB0 * CG_LDA + gB0] = bph0;
            *(uint4*)&Bl[rB0 * CG_LDA + gB0] = bpl0;
            *(uint4*)&Bh[rB1 * CG_LDA + gB1] = bph1;
            *(uint4*)&Bl[rB1 * CG_LDA + gB1] = bpl1;
            // prefetch next segment's B
            if (!(c8 == 7 && t == 2)) {
                const int t2  = (t == 2) ? 0 : (t + 1);
                const int c82 = c8 + (t == 2);
                const int kbase = t2 * 256 + c82 * 32;
                const size_t gi0 = (size_t)(o0 + rB0) * 768 + kbase + gB0;
                const size_t gi1 = (size_t)(o0 + rB1) * 768 + kbase + gB1;
                bph0 = *(const uint4*)(wth + gi0); bpl0 = *(const uint4*)(wtl + gi0);
                bph1 = *(const uint4*)(wth + gi1); bpl1 = *(const uint4*)(wtl + gi1);
            }
            __syncthreads();   // tiles ready
            // MFMA segment (2-pass)
            short8 ah[4];
#pragma unroll
            for (int mt = 0; mt < 4; ++mt) {
                const int ar = (wave * 64 + mt * 16 + m16 + t) * CG_LDA + quad * 8;
                ah[mt] = *(const short8*)&As[ar];
            }
#pragma unroll
            for (int nt = 0; nt < 8; ++nt) {
                const int br = (nt * 16 + m16) * CG_LDA + quad * 8;
                const short8 bh = *(const short8*)&Bh[br];
                const short8 bl = *(const short8*)&Bl[br];
#pragma unroll
                for (int mt = 0; mt < 4; ++mt) {
                    acc[mt][nt] = __builtin_amdgcn_mfma_f32_16x16x32_bf16(ah[mt], bh, acc[mt][nt], 0, 0, 0);
                    acc[mt][nt] = __builtin_amdgcn_mfma_f32_16x16x32_bf16(ah[mt], bl, acc[mt][nt], 0, 0, 0);
                }
            }
        }
    }
    __syncthreads();

    // epilogue: +bias, *mask, store c[b][o][s] (float4 over s)
    float msk[4][4];
#pragma unroll
    for (int mt = 0; mt < 4; ++mt) {
        const int s = s0 + wave * 64 + mt * 16 + quad * 4;
        const int4 p4 = *(const int4*)(pos + (size_t)b * S_LEN + s);
        msk[mt][0] = (p4.x != -1) ? 1.f : 0.f;
        msk[mt][1] = (p4.y != -1) ? 1.f : 0.f;
        msk[mt][2] = (p4.z != -1) ? 1.f : 0.f;
        msk[mt][3] = (p4.w != -1) ? 1.f : 0.f;
    }
#pragma unroll
    for (int nt = 0; nt < 8; ++nt) {
        const int o = o0 + nt * 16 + m16;
        const float cb = convb[o];
#pragma unroll
        for (int mt = 0; mt < 4; ++mt) {
            const int s = s0 + wave * 64 + mt * 16 + quad * 4;
            float4 r;
            r.x = (acc[mt][nt][0] + cb) * msk[mt][0];
            r.y = (acc[mt][nt][1] + cb) * msk[mt][1];
            r.z = (acc[mt][nt][2] + cb) * msk[mt][2];
            r.w = (acc[mt][nt][3] + cb) * msk[mt][3];
            *(float4*)(c + ((size_t)(b * 768 + o)) * S_LEN + s) = r;
        }
    }
}

// ---------------- RoPE + FF (MFMA, LDS-staged B) + L1-normalize -> hh[b][i][d][s] ----------------
#define FF_LDA 264   // 256 + 8 ushort pad: rows 528B apart (33*16B, 2-way banks = free)
#define FF_LDB 136   // 128 + 8 pad: rows 272B apart (17*16B)
__global__ __launch_bounds__(256, 2) void k_ff(
    const float* __restrict__ emb, const int* __restrict__ pos, const float* __restrict__ minp,
    const unsigned short* __restrict__ w1th, const unsigned short* __restrict__ w1tl,
    const float* __restrict__ b1,
    const float* __restrict__ lng, const float* __restrict__ lnb,
    const unsigned short* __restrict__ w2th, const unsigned short* __restrict__ w2tl,
    const float* __restrict__ b2, const float* __restrict__ ffs, float* __restrict__ hh)
{
    const int b   = blockIdx.y;
    const int s0  = blockIdx.x * 64;
    const int tid = threadIdx.x;
    const int wave = tid >> 6, lane = tid & 63;
    const int m16  = lane & 15, quad = lane >> 4;

    __shared__ __align__(16) unsigned short Th[64 * FF_LDA];
    __shared__ __align__(16) unsigned short Tl[64 * FF_LDA];
    __shared__ __align__(16) unsigned short Bsh[16 * FF_LDB];
    __shared__ __align__(16) unsigned short Bsl[16 * FF_LDB];
    __shared__ float th_s[128];

    if (tid < 128) th_s[tid] = expf(-(float)tid * 0.07195578415606394f);
    __syncthreads();

    // ---- RoPE -> Th/Tl (each thread: 1/4 of one row = 64 cols = 32 pairs) ----
    {
        const int r    = tid >> 2;            // 0..63
        const int col0 = (tid & 3) * 64;
        const int s    = s0 + r;
        const int p    = pos[(size_t)b * S_LEN + s];
        const float adj = (p == -1) ? -1.f : ((float)p - minp[b]);
        const float* ep = emb + ((size_t)b * S_LEN + s) * D_DIM;
#pragma unroll
        for (int p8 = 0; p8 < 8; ++p8) {
            const int cbase = col0 + p8 * 8;
            const float4 va = *(const float4*)(ep + cbase);
            const float4 vb4 = *(const float4*)(ep + cbase + 4);
            const float x[8] = {va.x, va.y, va.z, va.w, vb4.x, vb4.y, vb4.z, vb4.w};
            unsigned int uh[4], ul[4];
#pragma unroll
            for (int jj = 0; jj < 4; ++jj) {
                const int j = (cbase >> 1) + jj;
                const float theta = th_s[j];
                float sn, cs;
                sincosf(adj * theta, &sn, &cs);
                const float x1 = x[2*jj], x2 = x[2*jj+1];
                const float r1 = x1 * cs - x2 * sn;
                const float r2 = x1 * sn + x2 * cs;
                const unsigned int h1 = f2bf(r1), h2 = f2bf(r2);
                uh[jj] = h1 | (h2 << 16);
                ul[jj] = f2bf(r1 - bf2f(h1)) | (f2bf(r2 - bf2f(h2)) << 16);
            }
            uint4 wh, wl;
            wh.x = uh[0]; wh.y = uh[1]; wh.z = uh[2]; wh.w = uh[3];
            wl.x = ul[0]; wl.y = ul[1]; wl.z = ul[2]; wl.w = ul[3];
            *(uint4*)&Th[r * FF_LDA + cbase] = wh;
            *(uint4*)&Tl[r * FF_LDA + cbase] = wl;
        }
    }
    __syncthreads();

    const int rowA  = wave * 16 + m16;
    const int strow = tid >> 4;           // staging: row 0..15
    const int stks  = (tid & 15) * 8;     // staging: k-segment

    // ---- GEMM1: H[64x256] = T @ W1 (3-pass split, LDS-staged B, reg-dbuf) ----
    f32x4 acc1[16];
#pragma unroll
    for (int nt = 0; nt < 16; ++nt)
#pragma unroll
        for (int e = 0; e < 4; ++e) acc1[nt][e] = 0.f;

    uint4 pfh, pfl;
    {
        const size_t gi = (size_t)strow * 256 + stks;   // nt=0, kh=0
        pfh = *(const uint4*)(w1th + gi);
        pfl = *(const uint4*)(w1tl + gi);
    }
    for (int kh = 0; kh < 2; ++kh) {
        short8 a1h[4], a1l[4];
#pragma unroll
        for (int c4 = 0; c4 < 4; ++c4) {
            const int ar = rowA * FF_LDA + kh * 128 + c4 * 32 + quad * 8;
            a1h[c4] = *(const short8*)&Th[ar];
            a1l[c4] = *(const short8*)&Tl[ar];
        }
#pragma unroll
        for (int nt = 0; nt < 16; ++nt) {
            __syncthreads();   // previous tile's consumers done
            *(uint4*)&Bsh[strow * FF_LDB + stks] = pfh;
            *(uint4*)&Bsl[strow * FF_LDB + stks] = pfl;
            if (!(kh == 1 && nt == 15)) {
                const int nt2 = (nt + 1) & 15;
                const int kh2 = kh + (nt == 15);
                const size_t gi = (size_t)(nt2 * 16 + strow) * 256 + kh2 * 128 + stks;
                pfh = *(const uint4*)(w1th + gi);
                pfl = *(const uint4*)(w1tl + gi);
            }
            __syncthreads();   // tile ready
#pragma unroll
            for (int c4 = 0; c4 < 4; ++c4) {
                const int br = m16 * FF_LDB + c4 * 32 + quad * 8;
                const short8 bh = *(const short8*)&Bsh[br];
                const short8 bl = *(const short8*)&Bsl[br];
                acc1[nt] = __builtin_amdgcn_mfma_f32_16x16x32_bf16(a1h[c4], bh, acc1[nt], 0, 0, 0);
                acc1[nt] = __builtin_amdgcn_mfma_f32_16x16x32_bf16(a1h[c4], bl, acc1[nt], 0, 0, 0);
                acc1[nt] = __builtin_amdgcn_mfma_f32_16x16x32_bf16(a1l[c4], bh, acc1[nt], 0, 0, 0);
            }
        }
    }

    // ---- +b1, LayerNorm stats (in-register, shfl over m16 group) ----
    float sume[4] = {0.f, 0.f, 0.f, 0.f}, sumq[4] = {0.f, 0.f, 0.f, 0.f};
#pragma unroll
    for (int nt = 0; nt < 16; ++nt) {
        const float bb = b1[nt * 16 + m16];
#pragma unroll
        for (int e = 0; e < 4; ++e) {
            const float v = acc1[nt][e] + bb;
            acc1[nt][e] = v;
            sume[e] += v;
            sumq[e] += v * v;
        }
    }
#pragma unroll
    for (int e = 0; e < 4; ++e) {
#pragma unroll
        for (int off = 1; off < 16; off <<= 1) {
            sume[e] += __shfl_xor(sume[e], off, 64);
            sumq[e] += __shfl_xor(sumq[e], off, 64);
        }
    }
    float mu[4], rs[4];
#pragma unroll
    for (int e = 0; e < 4; ++e) {
        mu[e] = sume[e] * (1.f / 256.f);
        const float var = sumq[e] * (1.f / 256.f) - mu[e] * mu[e];
        rs[e] = rsqrtf(var + 1e-5f);
    }

    // preload GEMM2 tile (0,0) while LN finishes
    {
        const size_t gi = (size_t)strow * 256 + stks;
        pfh = *(const uint4*)(w2th + gi);
        pfl = *(const uint4*)(w2tl + gi);
    }

    // ---- LN + GELU + split, write H back into Th/Tl ----
    __syncthreads();   // all waves done reading T / Bs
#pragma unroll
    for (int nt = 0; nt < 16; ++nt) {
        const int col = nt * 16 + m16;
        const float g  = lng[col];
        const float be = lnb[col];
#pragma unroll
        for (int e = 0; e < 4; ++e) {
            const float h  = (acc1[nt][e] - mu[e]) * rs[e] * g + be;
            const float hg = 0.5f * h * (1.f + erff(h * 0.7071067811865475f));
            const unsigned int hb = f2bf(hg);
            const int li = (wave * 16 + quad * 4 + e) * FF_LDA + col;
            Th[li] = (unsigned short)hb;
            Tl[li] = (unsigned short)f2bf(hg - bf2f(hb));
        }
    }
    __syncthreads();

    // ---- GEMM2: A[64x512] = Hg @ W2 (3-pass split, LDS-staged B, reg-dbuf) ----
    f32x4 acc2[32];
#pragma unroll
    for (int nt = 0; nt < 32; ++nt)
#pragma unroll
        for (int e = 0; e < 4; ++e) acc2[nt][e] = 0.f;

    for (int kh = 0; kh < 2; ++kh) {
        short8 a2h[4], a2l[4];
#pragma unroll
        for (int c4 = 0; c4 < 4; ++c4) {
            const int ar = rowA * FF_LDA + kh * 128 + c4 * 32 + quad * 8;
            a2h[c4] = *(const short8*)&Th[ar];
            a2l[c4] = *(const short8*)&Tl[ar];
        }
#pragma unroll
        for (int nt = 0; nt < 32; ++nt) {
            __syncthreads();
            *(uint4*)&Bsh[strow * FF_LDB + stks] = pfh;
            *(uint4*)&Bsl[strow * FF_LDB + stks] = pfl;
            if (!(kh == 1 && nt == 31)) {
                const int nt2 = (nt + 1) & 31;
                const int kh2 = kh + (nt == 31);
                const size_t gi = (size_t)(nt2 * 16 + strow) * 256 + kh2 * 128 + stks;
                pfh = *(const uint4*)(w2th + gi);
                pfl = *(const uint4*)(w2tl + gi);
            }
            __syncthreads();
#pragma unroll
            for (int c4 = 0; c4 < 4; ++c4) {
                const int br = m16 * FF_LDB + c4 * 32 + quad * 8;
                const short8 bh = *(const short8*)&Bsh[br];
                const short8 bl = *(const short8*)&Bsl[br];
                acc2[nt] = __builtin_amdgcn_mfma_f32_16x16x32_bf16(a2h[c4], bh, acc2[nt], 0, 0, 0);
                acc2[nt] = __builtin_amdgcn_mfma_f32_16x16x32_bf16(a2h[c4], bl, acc2[nt], 0, 0, 0);
                acc2[nt] = __builtin_amdgcn_mfma_f32_16x16x32_bf16(a2l[c4], bh, acc2[nt], 0, 0, 0);
            }
        }
    }

    // ---- (a+b2)*ffs, L1-norm per (row, half), store hh[b][i][d][s] ----
    float sm[2][4] = {{0.f,0.f,0.f,0.f},{0.f,0.f,0.f,0.f}};
#pragma unroll
    for (int nt = 0; nt < 32; ++nt) {
        const int col = nt * 16 + m16;
        const float bb = b2[col];
        const float fs = ffs[col];
#pragma unroll
        for (int e = 0; e < 4; ++e) {
            const float v = (acc2[nt][e] + bb) * fs;
            acc2[nt][e] = v;
            sm[nt >> 4][e] += fabsf(v);
        }
    }
#pragma unroll
    for (int i = 0; i < 2; ++i)
#pragma unroll
        for (int e = 0; e < 4; ++e) {
#pragma unroll
            for (int off = 1; off < 16; off <<= 1)
                sm[i][e] += __shfl_xor(sm[i][e], off, 64);
        }
#pragma unroll
    for (int nt = 0; nt < 32; ++nt) {
        const int i = nt >> 4;
        const int d = (nt & 15) * 16 + m16;
        float4 o4;
        o4.x = acc2[nt][0] / (sm[i][0] + 1e-8f);
        o4.y = acc2[nt][1] / (sm[i][1] + 1e-8f);
        o4.z = acc2[nt][2] / (sm[i][2] + 1e-8f);
        o4.w = acc2[nt][3] / (sm[i][3] + 1e-8f);
        *(float4*)(hh + ((size_t)((b * 2 + i) * 256 + d)) * S_LEN + s0 + wave * 16 + quad * 4) = o4;
    }
}

// ---------------- MFMA blocked-Toeplitz causal long conv (unchanged) ----------------
#define XS_PAD   960
#define XS_ELEMS 5056
#define FRX_WORDS 4160
__device__ __forceinline__ int xsw(int blk) { return blk ^ ((blk >> 3) & 7); }

__global__ __launch_bounds__(64) void k_conv_mfma(
    const float* __restrict__ xbuf, const int xC, const int xoff,
    const float* __restrict__ hh, const int iord,
    const float* __restrict__ cbuf, float* __restrict__ outb)
{
    const int d = blockIdx.x;
    const int b = blockIdx.y;
    const int lane = threadIdx.x;
    const float* xp = xbuf + ((size_t)(b * xC + xoff + d)) * S_LEN;
    const float* fp = hh   + ((size_t)((b * 2 + iord) * 256 + d)) * S_LEN;
    const float* zp = cbuf + ((size_t)(b * 768 + iord * 256 + d)) * S_LEN;
    float* op = outb + ((size_t)(b * 256 + d)) * S_LEN;

    __shared__ unsigned short xs[XS_ELEMS];
    __shared__ unsigned int   frx[FRX_WORDS];

    {
        for (int blk = lane; blk < 120; blk += 64) {
            int4 z; z.x = 0; z.y = 0; z.z = 0; z.w = 0;
            *(int4*)(xs + xsw(blk) * 8) = z;
        }
#pragma unroll
        for (int it = 0; it < 8; ++it) {
            const int idx = it * 64 + lane;
            const int j = idx * 8;
            const float4 v0 = *(const float4*)(xp + j);
            const float4 v1 = *(const float4*)(xp + j + 4);
            int4 w;
            w.x = (int)(f2bf(v0.x) | (f2bf(v0.y) << 16));
            w.y = (int)(f2bf(v0.z) | (f2bf(v0.w) << 16));
            w.z = (int)(f2bf(v1.x) | (f2bf(v1.y) << 16));
            w.w = (int)(f2bf(v1.z) | (f2bf(v1.w) << 16));
            *(int4*)(xs + xsw(120 + idx) * 8) = w;
        }
    }
    {
        frx[4096 + lane] = 0u;
        if (lane == 0) frx[4095] = f2bf(fp[0]);
#pragma unroll
        for (int it = 0; it < 16; ++it) {
            const int j = (it * 64 + lane) * 4;
            const float4 v = *(const float4*)(fp + j);
            const float f4 = (j + 4 < S_LEN) ? fp[j + 4] : 0.f;
            frx[4094 - j] = f2bf(v.y) | (f2bf(v.x) << 16);
            frx[4093 - j] = f2bf(v.z) | (f2bf(v.y) << 16);
            frx[4092 - j] = f2bf(v.w) | (f2bf(v.z) << 16);
            if (j < 4092) frx[4091 - j] = f2bf(f4) | (f2bf(v.w) << 16);
        }
    }
    __syncthreads();

    const int m    = lane & 15;
    const int quad = lane >> 4;

    f32x4 acc[4][4];
#pragma unroll
    for (int mt = 0; mt < 4; ++mt)
#pragma unroll
        for (int pt = 0; pt < 4; ++pt)
#pragma unroll
            for (int e = 0; e < 4; ++e) acc[mt][pt][e] = 0.f;

    const int eA_base = 4095 - m + quad * 8;
    const int oB_base = XS_PAD + 64 * m + quad * 8;

    for (int r = 0; r < 64; ++r) {
        const int ea_r = eA_base - 64 * r;
        short8 afr[4][2];
#pragma unroll
        for (int mt = 0; mt < 4; ++mt)
#pragma unroll
            for (int kc = 0; kc < 2; ++kc) {
                const int e = ea_r - 16 * mt + 32 * kc;
                union { unsigned int u[4]; short8 s; } cvt;
                cvt.u[0] = frx[e];
                cvt.u[1] = frx[e + 2];
                cvt.u[2] = frx[e + 4];
                cvt.u[3] = frx[e + 6];
                afr[mt][kc] = cvt.s;
            }
        const int ptmin = r >> 4;
        const int ob_r = oB_base - 64 * r;
#pragma unroll
        for (int pt = 0; pt < 4; ++pt) {
            if (pt >= ptmin) {
                const int o0 = ob_r + 1024 * pt;
                const short8 bfr0 = *(const short8*)(xs + xsw(o0 >> 3) * 8);
                const short8 bfr1 = *(const short8*)(xs + xsw((o0 + 32) >> 3) * 8);
#pragma unroll
                for (int mt = 0; mt < 4; ++mt) {
                    acc[mt][pt] = __builtin_amdgcn_mfma_f32_16x16x32_bf16(afr[mt][0], bfr0, acc[mt][pt], 0, 0, 0);
                    acc[mt][pt] = __builtin_amdgcn_mfma_f32_16x16x32_bf16(afr[mt][1], bfr1, acc[mt][pt], 0, 0, 0);
                }
            }
        }
    }

    const float inv = 1.f / 8192.f;
#pragma unroll
    for (int mt = 0; mt < 4; ++mt)
#pragma unroll
        for (int pt = 0; pt < 4; ++pt) {
            const int p  = 16 * pt + m;
            const int s0 = 64 * p + 16 * mt + quad * 4;
            const float4 z4 = *(const float4*)(zp + s0);
            float4 o4;
            o4.x = z4.x * acc[mt][pt][0] * inv;
            o4.y = z4.y * acc[mt][pt][1] * inv;
            o4.z = z4.z * acc[mt][pt][2] * inv;
            o4.w = z4.w * acc[mt][pt][3] * inv;
            *(float4*)(op + s0) = o4;
        }
}

// ---------------- out[b][s][e] = mask * (sum_d v[b][d][s] * W_out[d][e] + b_out[e]) ----------------
__global__ __launch_bounds__(256) void k_out(
    const float* __restrict__ v, const float* __restrict__ Wo,
    const float* __restrict__ bo, const int* __restrict__ pos,
    float* __restrict__ out)
{
    const int b   = blockIdx.y;
    const int s0  = blockIdx.x * 32;
    const int tid = threadIdx.x;
    __shared__ float vs[256 * 36];
    {
        const float4* src = (const float4*)(v + ((size_t)(b*256 + tid)) * S_LEN + s0);
#pragma unroll
        for (int q = 0; q < 8; ++q) {
            *(float4*)&vs[tid*36 + q*4] = src[q];
        }
    }
    __syncthreads();
    float acc[32];
#pragma unroll
    for (int r = 0; r < 32; ++r) acc[r] = 0.f;
    for (int dd = 0; dd < 256; ++dd) {
        const float w = Wo[(size_t)dd * 256 + tid];
        const float* vr = &vs[dd * 36];
#pragma unroll
        for (int q = 0; q < 8; ++q) {
            const float4 x4 = *(const float4*)&vr[q*4];
            acc[q*4+0] += x4.x * w;
            acc[q*4+1] += x4.y * w;
            acc[q*4+2] += x4.z * w;
            acc[q*4+3] += x4.w * w;
        }
    }
    const float bb = bo[tid];
#pragma unroll
    for (int r = 0; r < 32; ++r) {
        const int s = s0 + r;
        const float m = (pos[(size_t)b * S_LEN + s] != -1) ? 1.f : 0.f;
        out[((size_t)b * S_LEN + s) * 256 + tid] = (acc[r] + bb) * m;
    }
}

extern "C" void kernel_launch(void* const* d_in, const int* in_sizes, int n_in,
                              void* d_out, int out_size, void* d_ws, size_t ws_size,
                              hipStream_t stream) {
    const float* emb = (const float*)d_in[0];
    const int*   pos = (const int*)  d_in[1];
    const float* Wp  = (const float*)d_in[2];
    const float* cw  = (const float*)d_in[3];
    const float* cb  = (const float*)d_in[4];
    const float* W1  = (const float*)d_in[5];
    const float* b1  = (const float*)d_in[6];
    const float* lg  = (const float*)d_in[7];
    const float* lb  = (const float*)d_in[8];
    const float* W2  = (const float*)d_in[9];
    const float* b2  = (const float*)d_in[10];
    const float* ffs = (const float*)d_in[11];
    const float* Wo  = (const float*)d_in[12];
    const float* bo  = (const float*)d_in[13];

    float* ws   = (float*)d_ws;
    float* minp = ws + OFF_MINP;
    float* wpt  = ws + OFF_WPT;
    unsigned short* wth = (unsigned short*)(ws + OFF_WTH);
    unsigned short* wtl = (unsigned short*)(ws + OFF_WTL);
    float* c    = ws + OFF_C;
    float* hh   = ws + OFF_HH;
    float* vb   = ws + OFF_V;
    float* ub   = ws + OFF_U;

    // FF weight splits carved from the head of vb (consumed by k_ff before conv#1 writes vb)
    unsigned short* w1th = (unsigned short*)vb;
    unsigned short* w1tl = w1th + 256 * 256;
    unsigned short* w2th = w1tl + 256 * 256;
    unsigned short* w2tl = w2th + 512 * 256;

    k_minpos<<<dim3(8), dim3(256), 0, stream>>>(pos, minp);
    k_wpt<<<dim3(24, 8), dim3(256), 0, stream>>>(Wp, wpt);
    k_weff<<<dim3(768), dim3(256), 0, stream>>>(wpt, cw, wth, wtl);
    k_tsplit<<<dim3(8, 8), dim3(256), 0, stream>>>(W1, 256, 256, w1th, w1tl);
    k_tsplit<<<dim3(16, 8), dim3(256), 0, stream>>>(W2, 256, 512, w2th, w2tl);
    k_convgemm<<<dim3(16, 6, 8), dim3(256), 0, stream>>>(emb, pos, wth, wtl, cb, c);
    k_ff<<<dim3(64, 8), dim3(256), 0, stream>>>(emb, pos, minp, w1th, w1tl, b1, lg, lb, w2th, w2tl, b2, ffs, hh);
    // v = zs[2]; v = zs[0] * longconv(v, hh[:,0]); v = zs[1] * longconv(v, hh[:,1])
    k_conv_mfma<<<dim3(256, 8), dim3(64), 0, stream>>>(c, 768, 512, hh, 0, c, vb);
    k_conv_mfma<<<dim3(256, 8), dim3(64), 0, stream>>>(vb, 256, 0, hh, 1, c, ub);
    k_out<<<dim3(128, 8), dim3(256), 0, stream>>>(ub, Wo, bo, pos, (float*)d_out);
}

// Round 6
// 534.916 us; speedup vs baseline: 1.2069x; 1.2069x over previous
//
#include <hip/hip_runtime.h>
#include <cstdint>

#define S_LEN 4096
#define D_DIM 256

// workspace layout (float offsets)
#define OFF_MINP 0
#define OFF_WPT  16
#define OFF_WTH  (OFF_WPT + 768*256)     // WeffT hi, 768x768 ushort = 294912 floats
#define OFF_WTL  (OFF_WTH + 294912)      // WeffT lo
#define OFF_C    (OFF_WTL + 294912)      // == old OFF_C, downstream unchanged
#define OFF_HH   (OFF_C + 8*768*4096)
#define OFF_V    (OFF_HH + 8*2*256*4096)
#define OFF_U    (OFF_V + 8*256*4096)

// FF weight splits live at the head of the V region (vb is only written by
// k_conv_mfma #1, which runs AFTER k_ff has consumed these — stream-order safe).

typedef __attribute__((ext_vector_type(8))) short short8;
typedef __attribute__((ext_vector_type(4))) float f32x4;

__device__ __forceinline__ unsigned int f2bf(float x) {
    union { float f; unsigned int u; } v; v.f = x;
    unsigned int r = v.u + 0x7fffu + ((v.u >> 16) & 1u);   // RNE
    return r >> 16;
}
__device__ __forceinline__ float bf2f(unsigned int h) {
    union { unsigned int u; float f; } v; v.u = h << 16; return v.f;
}

// ---------------- min valid position per batch ----------------
__global__ __launch_bounds__(256) void k_minpos(const int* __restrict__ pos, float* __restrict__ minp)
{
    const int b = blockIdx.x;
    const int tid = threadIdx.x;
    int mn = 0x7fffffff;
    const int* p = pos + (size_t)b * S_LEN;
    for (int s = tid; s < S_LEN; s += 256) {
        const int v = p[s];
        if (v != -1) mn = min(mn, v);
    }
    __shared__ int red[256];
    red[tid] = mn;
    __syncthreads();
    for (int st = 128; st > 0; st >>= 1) {
        if (tid < st) red[tid] = min(red[tid], red[tid + st]);
        __syncthreads();
    }
    if (tid == 0) minp[b] = (float)red[0];
}

// ---------------- transpose W_proj (256x768) -> WpT (768x256) ----------------
__global__ __launch_bounds__(256) void k_wpt(const float* __restrict__ Wp, float* __restrict__ WpT)
{
    __shared__ float t[32][33];
    const int e0 = blockIdx.x * 32;   // 0..767
    const int d0 = blockIdx.y * 32;   // 0..255
    const int lx = threadIdx.x & 31, ly = threadIdx.x >> 5; // 32x8
#pragma unroll
    for (int q = 0; q < 4; ++q)
        t[ly + 8*q][lx] = Wp[(size_t)(d0 + ly + 8*q) * 768 + e0 + lx];
    __syncthreads();
#pragma unroll
    for (int q = 0; q < 4; ++q)
        WpT[(size_t)(e0 + ly + 8*q) * 256 + d0 + lx] = t[lx][ly + 8*q];
}

// ---------------- generic transpose + bf16 hi/lo split: W[K][N] -> out[N][K] ----------------
__global__ __launch_bounds__(256) void k_tsplit(const float* __restrict__ W, const int K, const int N,
                                                unsigned short* __restrict__ oh, unsigned short* __restrict__ ol)
{
    __shared__ float t[32][33];
    const int n0 = blockIdx.x * 32;
    const int k0 = blockIdx.y * 32;
    const int lx = threadIdx.x & 31, ly = threadIdx.x >> 5;
#pragma unroll
    for (int q = 0; q < 4; ++q)
        t[ly + 8*q][lx] = W[(size_t)(k0 + ly + 8*q) * N + n0 + lx];
    __syncthreads();
#pragma unroll
    for (int q = 0; q < 4; ++q) {
        const float v = t[lx][ly + 8*q];
        const unsigned int h = f2bf(v);
        oh[(size_t)(n0 + ly + 8*q) * K + k0 + lx] = (unsigned short)h;
        ol[(size_t)(n0 + ly + 8*q) * K + k0 + lx] = (unsigned short)f2bf(v - bf2f(h));
    }
}

// ---------------- WeffT[o][t*256+d] = sum_i WpT[g*256+i][d] * conv_w[o][i][t], split hi/lo bf16 ----------------
__global__ __launch_bounds__(256) void k_weff(const float* __restrict__ WpT, const float* __restrict__ cw,
                                              unsigned short* __restrict__ wth, unsigned short* __restrict__ wtl)
{
    const int o = blockIdx.x;       // 768
    const int d = threadIdx.x;      // 256
    const int g = o >> 8;
    __shared__ float cwrow[768];
    for (int i = threadIdx.x; i < 768; i += 256) cwrow[i] = cw[(size_t)o * 768 + i];
    __syncthreads();
    float a0 = 0.f, a1 = 0.f, a2 = 0.f;
    const float* wb = WpT + (size_t)(g * 256) * 256 + d;
#pragma unroll 4
    for (int i = 0; i < 256; ++i) {
        const float wv = wb[(size_t)i * 256];
        a0 += wv * cwrow[i*3+0];
        a1 += wv * cwrow[i*3+1];
        a2 += wv * cwrow[i*3+2];
    }
    const float av[3] = {a0, a1, a2};
#pragma unroll
    for (int t = 0; t < 3; ++t) {
        const unsigned int hb = f2bf(av[t]);
        const unsigned int lb = f2bf(av[t] - bf2f(hb));
        wth[(size_t)o * 768 + t * 256 + d] = (unsigned short)hb;
        wtl[(size_t)o * 768 + t * 256 + d] = (unsigned short)lb;
    }
}

// ---------------- MFMA conv-GEMM (Round-4 verified version: 128s x 128o, mt=2, 2-pass) ----------------
#define CG_LDA 40   // 32 + 8 pad (16B frag alignment preserved: 80B rows)
__global__ __launch_bounds__(256, 3) void k_convgemm(
    const float* __restrict__ emb, const int* __restrict__ pos,
    const unsigned short* __restrict__ wth, const unsigned short* __restrict__ wtl,
    const float* __restrict__ convb, float* __restrict__ c)
{
    const int b  = blockIdx.z;
    const int o0 = blockIdx.y * 128;
    const int s0 = blockIdx.x * 128;
    const int tid  = threadIdx.x;
    const int wave = tid >> 6, lane = tid & 63;
    const int m16  = lane & 15, quad = lane >> 4;

    __shared__ __align__(16) unsigned short As[130 * CG_LDA];
    __shared__ __align__(16) unsigned short Bh[128 * CG_LDA];
    __shared__ __align__(16) unsigned short Bl[128 * CG_LDA];

    // A staging: thread -> row rA = tid>>1 (0..127), 16 consecutive k-cols at cA
    const int rA = tid >> 1;
    const int cA = (tid & 1) * 16;
    const int srowA = s0 + rA - 1;
    const bool vA = (srowA >= 0 && srowA < S_LEN);
    const float* embA = emb + ((size_t)b * S_LEN + (vA ? srowA : 0)) * D_DIM + cA;
    // A tail rows 128..129: threads 0..15, 4 k-cols each
    const int rT = 128 + (tid >> 3);
    const int cT = (tid & 7) * 4;
    const int srowT = s0 + rT - 1;
    const bool vT = (tid < 16) && (srowT >= 0 && srowT < S_LEN);
    const float* embT = emb + ((size_t)b * S_LEN + ((tid < 16 && vT) ? srowT : 0)) * D_DIM + cT;

    // B staging: tasks {tid, tid+256}: row task>>2, 8 k-cols at (task&3)*8
    const int rB0 = tid >> 2,        gB0 = (tid & 3) * 8;
    const int rB1 = 64 + (tid >> 2), gB1 = gB0;

    float4 apf[4]; float4 apfT;
    uint4 bph0, bpl0, bph1, bpl1;

    // preload A(c8=0) and B(seg 0: t=0,c8=0)
#pragma unroll
    for (int q = 0; q < 4; ++q) apf[q] = vA ? *(const float4*)(embA + q * 4) : make_float4(0.f,0.f,0.f,0.f);
    apfT = vT ? *(const float4*)(embT) : make_float4(0.f,0.f,0.f,0.f);
    {
        const size_t gi0 = (size_t)(o0 + rB0) * 768 + gB0;
        const size_t gi1 = (size_t)(o0 + rB1) * 768 + gB1;
        bph0 = *(const uint4*)(wth + gi0); bpl0 = *(const uint4*)(wtl + gi0);
        bph1 = *(const uint4*)(wth + gi1); bpl1 = *(const uint4*)(wtl + gi1);
    }

    f32x4 acc[2][8];
#pragma unroll
    for (int mt = 0; mt < 2; ++mt)
#pragma unroll
        for (int nt = 0; nt < 8; ++nt)
#pragma unroll
            for (int e = 0; e < 4; ++e) acc[mt][nt][e] = 0.f;

    for (int c8 = 0; c8 < 8; ++c8) {
        for (int t = 0; t < 3; ++t) {
            __syncthreads();   // consumers of previous tiles done
            if (t == 0) {
                // write A (bf16 RNE) from prefetch regs
#pragma unroll
                for (int q = 0; q < 4; ++q) {
                    const float4 v = apf[q];
                    uint2 hp;
                    hp.x = f2bf(v.x) | (f2bf(v.y) << 16);
                    hp.y = f2bf(v.z) | (f2bf(v.w) << 16);
                    *(uint2*)&As[rA * CG_LDA + cA + q * 4] = hp;
                }
                if (tid < 16) {
                    const float4 v = apfT;
                    uint2 hp;
                    hp.x = f2bf(v.x) | (f2bf(v.y) << 16);
                    hp.y = f2bf(v.z) | (f2bf(v.w) << 16);
                    *(uint2*)&As[rT * CG_LDA + cT] = hp;
                }
                if (c8 < 7) {
                    const int base = (c8 + 1) * 32;
#pragma unroll
                    for (int q = 0; q < 4; ++q) apf[q] = vA ? *(const float4*)(embA + base + q * 4) : make_float4(0.f,0.f,0.f,0.f);
                    apfT = vT ? *(const float4*)(embT + base) : make_float4(0.f,0.f,0.f,0.f);
                }
            }
            // write B from prefetch regs
            *(uint4*)&Bh[rB0 * CG_LDA + gB0] = bph0;
            *(uint4*)&Bl[rB0 * CG_LDA + gB0] = bpl0;
            *(uint4*)&Bh[rB1 * CG_LDA + gB1] = bph1;
            *(uint4*)&Bl[rB1 * CG_LDA + gB1] = bpl1;
            // prefetch next segment's B
            if (!(c8 == 7 && t == 2)) {
                const int t2  = (t == 2) ? 0 : (t + 1);
                const int c82 = c8 + (t == 2);
                const int kbase = t2 * 256 + c82 * 32;
                const size_t gi0 = (size_t)(o0 + rB0) * 768 + kbase + gB0;
                const size_t gi1 = (size_t)(o0 + rB1) * 768 + kbase + gB1;
                bph0 = *(const uint4*)(wth + gi0); bpl0 = *(const uint4*)(wtl + gi0);
                bph1 = *(const uint4*)(wth + gi1); bpl1 = *(const uint4*)(wtl + gi1);
            }
            __syncthreads();   // tiles ready
            // MFMA segment (2-pass)
            short8 ah[2];
#pragma unroll
            for (int mt = 0; mt < 2; ++mt) {
                const int ar = (wave * 32 + mt * 16 + m16 + t) * CG_LDA + quad * 8;
                ah[mt] = *(const short8*)&As[ar];
            }
#pragma unroll
            for (int nt = 0; nt < 8; ++nt) {
                const int br = (nt * 16 + m16) * CG_LDA + quad * 8;
                const short8 bh = *(const short8*)&Bh[br];
                const short8 bl = *(const short8*)&Bl[br];
#pragma unroll
                for (int mt = 0; mt < 2; ++mt) {
                    acc[mt][nt] = __builtin_amdgcn_mfma_f32_16x16x32_bf16(ah[mt], bh, acc[mt][nt], 0, 0, 0);
                    acc[mt][nt] = __builtin_amdgcn_mfma_f32_16x16x32_bf16(ah[mt], bl, acc[mt][nt], 0, 0, 0);
                }
            }
        }
    }
    __syncthreads();

    // epilogue: +bias, *mask, store c[b][o][s] (float4 over s)
    float msk[2][4];
#pragma unroll
    for (int mt = 0; mt < 2; ++mt) {
        const int s = s0 + wave * 32 + mt * 16 + quad * 4;
        const int4 p4 = *(const int4*)(pos + (size_t)b * S_LEN + s);
        msk[mt][0] = (p4.x != -1) ? 1.f : 0.f;
        msk[mt][1] = (p4.y != -1) ? 1.f : 0.f;
        msk[mt][2] = (p4.z != -1) ? 1.f : 0.f;
        msk[mt][3] = (p4.w != -1) ? 1.f : 0.f;
    }
#pragma unroll
    for (int nt = 0; nt < 8; ++nt) {
        const int o = o0 + nt * 16 + m16;
        const float cb = convb[o];
#pragma unroll
        for (int mt = 0; mt < 2; ++mt) {
            const int s = s0 + wave * 32 + mt * 16 + quad * 4;
            float4 r;
            r.x = (acc[mt][nt][0] + cb) * msk[mt][0];
            r.y = (acc[mt][nt][1] + cb) * msk[mt][1];
            r.z = (acc[mt][nt][2] + cb) * msk[mt][2];
            r.w = (acc[mt][nt][3] + cb) * msk[mt][3];
            *(float4*)(c + ((size_t)(b * 768 + o)) * S_LEN + s) = r;
        }
    }
}

// ---------------- RoPE + FF (MFMA, LDS-staged B, 2-pass split: T/H plain bf16, W hi/lo) ----------------
#define FF_LDA 264   // 256 + 8 ushort pad: rows 528B apart (33*16B, 2-way banks = free)
#define FF_LDB 136   // 128 + 8 pad: rows 272B apart (17*16B)
__global__ __launch_bounds__(256, 2) void k_ff(
    const float* __restrict__ emb, const int* __restrict__ pos, const float* __restrict__ minp,
    const unsigned short* __restrict__ w1th, const unsigned short* __restrict__ w1tl,
    const float* __restrict__ b1,
    const float* __restrict__ lng, const float* __restrict__ lnb,
    const unsigned short* __restrict__ w2th, const unsigned short* __restrict__ w2tl,
    const float* __restrict__ b2, const float* __restrict__ ffs, float* __restrict__ hh)
{
    const int b   = blockIdx.y;
    const int s0  = blockIdx.x * 64;
    const int tid = threadIdx.x;
    const int wave = tid >> 6, lane = tid & 63;
    const int m16  = lane & 15, quad = lane >> 4;

    __shared__ __align__(16) unsigned short Th[64 * FF_LDA];
    __shared__ __align__(16) unsigned short Bsh[16 * FF_LDB];
    __shared__ __align__(16) unsigned short Bsl[16 * FF_LDB];
    __shared__ float th_s[128];

    if (tid < 128) th_s[tid] = expf(-(float)tid * 0.07195578415606394f);
    __syncthreads();

    // ---- RoPE -> Th (bf16 RNE; each thread: 1/4 of one row = 64 cols = 32 pairs) ----
    {
        const int r    = tid >> 2;            // 0..63
        const int col0 = (tid & 3) * 64;
        const int s    = s0 + r;
        const int p    = pos[(size_t)b * S_LEN + s];
        const float adj = (p == -1) ? -1.f : ((float)p - minp[b]);
        const float* ep = emb + ((size_t)b * S_LEN + s) * D_DIM;
#pragma unroll
        for (int p8 = 0; p8 < 8; ++p8) {
            const int cbase = col0 + p8 * 8;
            const float4 va = *(const float4*)(ep + cbase);
            const float4 vb4 = *(const float4*)(ep + cbase + 4);
            const float x[8] = {va.x, va.y, va.z, va.w, vb4.x, vb4.y, vb4.z, vb4.w};
            unsigned int uh[4];
#pragma unroll
            for (int jj = 0; jj < 4; ++jj) {
                const int j = (cbase >> 1) + jj;
                const float theta = th_s[j];
                float sn, cs;
                sincosf(adj * theta, &sn, &cs);
                const float x1 = x[2*jj], x2 = x[2*jj+1];
                const float r1 = x1 * cs - x2 * sn;
                const float r2 = x1 * sn + x2 * cs;
                uh[jj] = f2bf(r1) | (f2bf(r2) << 16);
            }
            uint4 wh;
            wh.x = uh[0]; wh.y = uh[1]; wh.z = uh[2]; wh.w = uh[3];
            *(uint4*)&Th[r * FF_LDA + cbase] = wh;
        }
    }
    __syncthreads();

    const int rowA  = wave * 16 + m16;
    const int strow = tid >> 4;           // staging: row 0..15
    const int stks  = (tid & 15) * 8;     // staging: k-segment

    // ---- GEMM1: H[64x256] = T @ W1 (2-pass split, LDS-staged B, reg-dbuf) ----
    f32x4 acc1[16];
#pragma unroll
    for (int nt = 0; nt < 16; ++nt)
#pragma unroll
        for (int e = 0; e < 4; ++e) acc1[nt][e] = 0.f;

    uint4 pfh, pfl;
    {
        const size_t gi = (size_t)strow * 256 + stks;   // nt=0, kh=0
        pfh = *(const uint4*)(w1th + gi);
        pfl = *(const uint4*)(w1tl + gi);
    }
    for (int kh = 0; kh < 2; ++kh) {
        short8 a1h[4];
#pragma unroll
        for (int c4 = 0; c4 < 4; ++c4) {
            const int ar = rowA * FF_LDA + kh * 128 + c4 * 32 + quad * 8;
            a1h[c4] = *(const short8*)&Th[ar];
        }
#pragma unroll
        for (int nt = 0; nt < 16; ++nt) {
            __syncthreads();   // previous tile's consumers done
            *(uint4*)&Bsh[strow * FF_LDB + stks] = pfh;
            *(uint4*)&Bsl[strow * FF_LDB + stks] = pfl;
            if (!(kh == 1 && nt == 15)) {
                const int nt2 = (nt + 1) & 15;
                const int kh2 = kh + (nt == 15);
                const size_t gi = (size_t)(nt2 * 16 + strow) * 256 + kh2 * 128 + stks;
                pfh = *(const uint4*)(w1th + gi);
                pfl = *(const uint4*)(w1tl + gi);
            }
            __syncthreads();   // tile ready
#pragma unroll
            for (int c4 = 0; c4 < 4; ++c4) {
                const int br = m16 * FF_LDB + c4 * 32 + quad * 8;
                const short8 bh = *(const short8*)&Bsh[br];
                const short8 bl = *(const short8*)&Bsl[br];
                acc1[nt] = __builtin_amdgcn_mfma_f32_16x16x32_bf16(a1h[c4], bh, acc1[nt], 0, 0, 0);
                acc1[nt] = __builtin_amdgcn_mfma_f32_16x16x32_bf16(a1h[c4], bl, acc1[nt], 0, 0, 0);
            }
        }
    }

    // ---- +b1, LayerNorm stats (in-register, shfl over m16 group) ----
    float sume[4] = {0.f, 0.f, 0.f, 0.f}, sumq[4] = {0.f, 0.f, 0.f, 0.f};
#pragma unroll
    for (int nt = 0; nt < 16; ++nt) {
        const float bb = b1[nt * 16 + m16];
#pragma unroll
        for (int e = 0; e < 4; ++e) {
            const float v = acc1[nt][e] + bb;
            acc1[nt][e] = v;
            sume[e] += v;
            sumq[e] += v * v;
        }
    }
#pragma unroll
    for (int e = 0; e < 4; ++e) {
#pragma unroll
        for (int off = 1; off < 16; off <<= 1) {
            sume[e] += __shfl_xor(sume[e], off, 64);
            sumq[e] += __shfl_xor(sumq[e], off, 64);
        }
    }
    float mu[4], rs[4];
#pragma unroll
    for (int e = 0; e < 4; ++e) {
        mu[e] = sume[e] * (1.f / 256.f);
        const float var = sumq[e] * (1.f / 256.f) - mu[e] * mu[e];
        rs[e] = rsqrtf(var + 1e-5f);
    }

    // preload GEMM2 tile (0,0) while LN finishes
    {
        const size_t gi = (size_t)strow * 256 + stks;
        pfh = *(const uint4*)(w2th + gi);
        pfl = *(const uint4*)(w2tl + gi);
    }

    // ---- LN + GELU, write H (bf16) back into Th ----
    __syncthreads();   // all waves done reading T / Bs
#pragma unroll
    for (int nt = 0; nt < 16; ++nt) {
        const int col = nt * 16 + m16;
        const float g  = lng[col];
        const float be = lnb[col];
#pragma unroll
        for (int e = 0; e < 4; ++e) {
            const float h  = (acc1[nt][e] - mu[e]) * rs[e] * g + be;
            const float hg = 0.5f * h * (1.f + erff(h * 0.7071067811865475f));
            const int li = (wave * 16 + quad * 4 + e) * FF_LDA + col;
            Th[li] = (unsigned short)f2bf(hg);
        }
    }
    __syncthreads();

    // ---- GEMM2: A[64x512] = Hg @ W2 (2-pass split, LDS-staged B, reg-dbuf) ----
    f32x4 acc2[32];
#pragma unroll
    for (int nt = 0; nt < 32; ++nt)
#pragma unroll
        for (int e = 0; e < 4; ++e) acc2[nt][e] = 0.f;

    for (int kh = 0; kh < 2; ++kh) {
        short8 a2h[4];
#pragma unroll
        for (int c4 = 0; c4 < 4; ++c4) {
            const int ar = rowA * FF_LDA + kh * 128 + c4 * 32 + quad * 8;
            a2h[c4] = *(const short8*)&Th[ar];
        }
#pragma unroll
        for (int nt = 0; nt < 32; ++nt) {
            __syncthreads();
            *(uint4*)&Bsh[strow * FF_LDB + stks] = pfh;
            *(uint4*)&Bsl[strow * FF_LDB + stks] = pfl;
            if (!(kh == 1 && nt == 31)) {
                const int nt2 = (nt + 1) & 31;
                const int kh2 = kh + (nt == 31);
                const size_t gi = (size_t)(nt2 * 16 + strow) * 256 + kh2 * 128 + stks;
                pfh = *(const uint4*)(w2th + gi);
                pfl = *(const uint4*)(w2tl + gi);
            }
            __syncthreads();
#pragma unroll
            for (int c4 = 0; c4 < 4; ++c4) {
                const int br = m16 * FF_LDB + c4 * 32 + quad * 8;
                const short8 bh = *(const short8*)&Bsh[br];
                const short8 bl = *(const short8*)&Bsl[br];
                acc2[nt] = __builtin_amdgcn_mfma_f32_16x16x32_bf16(a2h[c4], bh, acc2[nt], 0, 0, 0);
                acc2[nt] = __builtin_amdgcn_mfma_f32_16x16x32_bf16(a2h[c4], bl, acc2[nt], 0, 0, 0);
            }
        }
    }

    // ---- (a+b2)*ffs, L1-norm per (row, half), store hh[b][i][d][s] ----
    float sm[2][4] = {{0.f,0.f,0.f,0.f},{0.f,0.f,0.f,0.f}};
#pragma unroll
    for (int nt = 0; nt < 32; ++nt) {
        const int col = nt * 16 + m16;
        const float bb = b2[col];
        const float fs = ffs[col];
#pragma unroll
        for (int e = 0; e < 4; ++e) {
            const float v = (acc2[nt][e] + bb) * fs;
            acc2[nt][e] = v;
            sm[nt >> 4][e] += fabsf(v);
        }
    }
#pragma unroll
    for (int i = 0; i < 2; ++i)
#pragma unroll
        for (int e = 0; e < 4; ++e) {
#pragma unroll
            for (int off = 1; off < 16; off <<= 1)
                sm[i][e] += __shfl_xor(sm[i][e], off, 64);
        }
#pragma unroll
    for (int nt = 0; nt < 32; ++nt) {
        const int i = nt >> 4;
        const int d = (nt & 15) * 16 + m16;
        float4 o4;
        o4.x = acc2[nt][0] / (sm[i][0] + 1e-8f);
        o4.y = acc2[nt][1] / (sm[i][1] + 1e-8f);
        o4.z = acc2[nt][2] / (sm[i][2] + 1e-8f);
        o4.w = acc2[nt][3] / (sm[i][3] + 1e-8f);
        *(float4*)(hh + ((size_t)((b * 2 + i) * 256 + d)) * S_LEN + s0 + wave * 16 + quad * 4) = o4;
    }
}

// ---------------- MFMA blocked-Toeplitz causal long conv (unchanged) ----------------
#define XS_PAD   960
#define XS_ELEMS 5056
#define FRX_WORDS 4160
__device__ __forceinline__ int xsw(int blk) { return blk ^ ((blk >> 3) & 7); }

__global__ __launch_bounds__(64) void k_conv_mfma(
    const float* __restrict__ xbuf, const int xC, const int xoff,
    const float* __restrict__ hh, const int iord,
    const float* __restrict__ cbuf, float* __restrict__ outb)
{
    const int d = blockIdx.x;
    const int b = blockIdx.y;
    const int lane = threadIdx.x;
    const float* xp = xbuf + ((size_t)(b * xC + xoff + d)) * S_LEN;
    const float* fp = hh   + ((size_t)((b * 2 + iord) * 256 + d)) * S_LEN;
    const float* zp = cbuf + ((size_t)(b * 768 + iord * 256 + d)) * S_LEN;
    float* op = outb + ((size_t)(b * 256 + d)) * S_LEN;

    __shared__ unsigned short xs[XS_ELEMS];
    __shared__ unsigned int   frx[FRX_WORDS];

    {
        for (int blk = lane; blk < 120; blk += 64) {
            int4 z; z.x = 0; z.y = 0; z.z = 0; z.w = 0;
            *(int4*)(xs + xsw(blk) * 8) = z;
        }
#pragma unroll
        for (int it = 0; it < 8; ++it) {
            const int idx = it * 64 + lane;
            const int j = idx * 8;
            const float4 v0 = *(const float4*)(xp + j);
            const float4 v1 = *(const float4*)(xp + j + 4);
            int4 w;
            w.x = (int)(f2bf(v0.x) | (f2bf(v0.y) << 16));
            w.y = (int)(f2bf(v0.z) | (f2bf(v0.w) << 16));
            w.z = (int)(f2bf(v1.x) | (f2bf(v1.y) << 16));
            w.w = (int)(f2bf(v1.z) | (f2bf(v1.w) << 16));
            *(int4*)(xs + xsw(120 + idx) * 8) = w;
        }
    }
    {
        frx[4096 + lane] = 0u;
        if (lane == 0) frx[4095] = f2bf(fp[0]);
#pragma unroll
        for (int it = 0; it < 16; ++it) {
            const int j = (it * 64 + lane) * 4;
            const float4 v = *(const float4*)(fp + j);
            const float f4 = (j + 4 < S_LEN) ? fp[j + 4] : 0.f;
            frx[4094 - j] = f2bf(v.y) | (f2bf(v.x) << 16);
            frx[4093 - j] = f2bf(v.z) | (f2bf(v.y) << 16);
            frx[4092 - j] = f2bf(v.w) | (f2bf(v.z) << 16);
            if (j < 4092) frx[4091 - j] = f2bf(f4) | (f2bf(v.w) << 16);
        }
    }
    __syncthreads();

    const int m    = lane & 15;
    const int quad = lane >> 4;

    f32x4 acc[4][4];
#pragma unroll
    for (int mt = 0; mt < 4; ++mt)
#pragma unroll
        for (int pt = 0; pt < 4; ++pt)
#pragma unroll
            for (int e = 0; e < 4; ++e) acc[mt][pt][e] = 0.f;

    const int eA_base = 4095 - m + quad * 8;
    const int oB_base = XS_PAD + 64 * m + quad * 8;

    for (int r = 0; r < 64; ++r) {
        const int ea_r = eA_base - 64 * r;
        short8 afr[4][2];
#pragma unroll
        for (int mt = 0; mt < 4; ++mt)
#pragma unroll
            for (int kc = 0; kc < 2; ++kc) {
                const int e = ea_r - 16 * mt + 32 * kc;
                union { unsigned int u[4]; short8 s; } cvt;
                cvt.u[0] = frx[e];
                cvt.u[1] = frx[e + 2];
                cvt.u[2] = frx[e + 4];
                cvt.u[3] = frx[e + 6];
                afr[mt][kc] = cvt.s;
            }
        const int ptmin = r >> 4;
        const int ob_r = oB_base - 64 * r;
#pragma unroll
        for (int pt = 0; pt < 4; ++pt) {
            if (pt >= ptmin) {
                const int o0 = ob_r + 1024 * pt;
                const short8 bfr0 = *(const short8*)(xs + xsw(o0 >> 3) * 8);
                const short8 bfr1 = *(const short8*)(xs + xsw((o0 + 32) >> 3) * 8);
#pragma unroll
                for (int mt = 0; mt < 4; ++mt) {
                    acc[mt][pt] = __builtin_amdgcn_mfma_f32_16x16x32_bf16(afr[mt][0], bfr0, acc[mt][pt], 0, 0, 0);
                    acc[mt][pt] = __builtin_amdgcn_mfma_f32_16x16x32_bf16(afr[mt][1], bfr1, acc[mt][pt], 0, 0, 0);
                }
            }
        }
    }

    const float inv = 1.f / 8192.f;
#pragma unroll
    for (int mt = 0; mt < 4; ++mt)
#pragma unroll
        for (int pt = 0; pt < 4; ++pt) {
            const int p  = 16 * pt + m;
            const int s0 = 64 * p + 16 * mt + quad * 4;
            const float4 z4 = *(const float4*)(zp + s0);
            float4 o4;
            o4.x = z4.x * acc[mt][pt][0] * inv;
            o4.y = z4.y * acc[mt][pt][1] * inv;
            o4.z = z4.z * acc[mt][pt][2] * inv;
            o4.w = z4.w * acc[mt][pt][3] * inv;
            *(float4*)(op + s0) = o4;
        }
}

// ---------------- out[b][s][e] = mask * (sum_d v[b][d][s] * W_out[d][e] + b_out[e]) ----------------
__global__ __launch_bounds__(256) void k_out(
    const float* __restrict__ v, const float* __restrict__ Wo,
    const float* __restrict__ bo, const int* __restrict__ pos,
    float* __restrict__ out)
{
    const int b   = blockIdx.y;
    const int s0  = blockIdx.x * 32;
    const int tid = threadIdx.x;
    __shared__ float vs[256 * 36];
    {
        const float4* src = (const float4*)(v + ((size_t)(b*256 + tid)) * S_LEN + s0);
#pragma unroll
        for (int q = 0; q < 8; ++q) {
            *(float4*)&vs[tid*36 + q*4] = src[q];
        }
    }
    __syncthreads();
    float acc[32];
#pragma unroll
    for (int r = 0; r < 32; ++r) acc[r] = 0.f;
    for (int dd = 0; dd < 256; ++dd) {
        const float w = Wo[(size_t)dd * 256 + tid];
        const float* vr = &vs[dd * 36];
#pragma unroll
        for (int q = 0; q < 8; ++q) {
            const float4 x4 = *(const float4*)&vr[q*4];
            acc[q*4+0] += x4.x * w;
            acc[q*4+1] += x4.y * w;
            acc[q*4+2] += x4.z * w;
            acc[q*4+3] += x4.w * w;
        }
    }
    const float bb = bo[tid];
#pragma unroll
    for (int r = 0; r < 32; ++r) {
        const int s = s0 + r;
        const float m = (pos[(size_t)b * S_LEN + s] != -1) ? 1.f : 0.f;
        out[((size_t)b * S_LEN + s) * 256 + tid] = (acc[r] + bb) * m;
    }
}

extern "C" void kernel_launch(void* const* d_in, const int* in_sizes, int n_in,
                              void* d_out, int out_size, void* d_ws, size_t ws_size,
                              hipStream_t stream) {
    const float* emb = (const float*)d_in[0];
    const int*   pos = (const int*)  d_in[1];
    const float* Wp  = (const float*)d_in[2];
    const float* cw  = (const float*)d_in[3];
    const float* cb  = (const float*)d_in[4];
    const float* W1  = (const float*)d_in[5];
    const float* b1  = (const float*)d_in[6];
    const float* lg  = (const float*)d_in[7];
    const float* lb  = (const float*)d_in[8];
    const float* W2  = (const float*)d_in[9];
    const float* b2  = (const float*)d_in[10];
    const float* ffs = (const float*)d_in[11];
    const float* Wo  = (const float*)d_in[12];
    const float* bo  = (const float*)d_in[13];

    float* ws   = (float*)d_ws;
    float* minp = ws + OFF_MINP;
    float* wpt  = ws + OFF_WPT;
    unsigned short* wth = (unsigned short*)(ws + OFF_WTH);
    unsigned short* wtl = (unsigned short*)(ws + OFF_WTL);
    float* c    = ws + OFF_C;
    float* hh   = ws + OFF_HH;
    float* vb   = ws + OFF_V;
    float* ub   = ws + OFF_U;

    // FF weight splits carved from the head of vb (consumed by k_ff before conv#1 writes vb)
    unsigned short* w1th = (unsigned short*)vb;
    unsigned short* w1tl = w1th + 256 * 256;
    unsigned short* w2th = w1tl + 256 * 256;
    unsigned short* w2tl = w2th + 512 * 256;

    k_minpos<<<dim3(8), dim3(256), 0, stream>>>(pos, minp);
    k_wpt<<<dim3(24, 8), dim3(256), 0, stream>>>(Wp, wpt);
    k_weff<<<dim3(768), dim3(256), 0, stream>>>(wpt, cw, wth, wtl);
    k_tsplit<<<dim3(8, 8), dim3(256), 0, stream>>>(W1, 256, 256, w1th, w1tl);
    k_tsplit<<<dim3(16, 8), dim3(256), 0, stream>>>(W2, 256, 512, w2th, w2tl);
    k_convgemm<<<dim3(32, 6, 8), dim3(256), 0, stream>>>(emb, pos, wth, wtl, cb, c);
    k_ff<<<dim3(64, 8), dim3(256), 0, stream>>>(emb, pos, minp, w1th, w1tl, b1, lg, lb, w2th, w2tl, b2, ffs, hh);
    // v = zs[2]; v = zs[0] * longconv(v, hh[:,0]); v = zs[1] * longconv(v, hh[:,1])
    k_conv_mfma<<<dim3(256, 8), dim3(64), 0, stream>>>(c, 768, 512, hh, 0, c, vb);
    k_conv_mfma<<<dim3(256, 8), dim3(64), 0, stream>>>(vb, 256, 0, hh, 1, c, ub);
    k_out<<<dim3(128, 8), dim3(256), 0, stream>>>(ub, Wo, bo, pos, (float*)d_out);
}

// Round 7
// 511.866 us; speedup vs baseline: 1.2612x; 1.0450x over previous
//
#include <hip/hip_runtime.h>
#include <cstdint>

#define S_LEN 4096
#define D_DIM 256

// workspace layout (float offsets)
#define OFF_MINP 0
#define OFF_WPT  16
#define OFF_WTH  (OFF_WPT + 768*256)     // WeffT hi, 768x768 ushort = 294912 floats
#define OFF_WTL  (OFF_WTH + 294912)      // WeffT lo
#define OFF_C    (OFF_WTL + 294912)      // == old OFF_C, downstream unchanged
#define OFF_HH   (OFF_C + 8*768*4096)
#define OFF_V    (OFF_HH + 8*2*256*4096)
#define OFF_U    (OFF_V + 8*256*4096)

// FF weight splits live at the head of the V region (vb is only written by
// k_conv_mfma #1, which runs AFTER k_ff has consumed these — stream-order safe).

typedef __attribute__((ext_vector_type(8))) short short8;
typedef __attribute__((ext_vector_type(4))) float f32x4;

__device__ __forceinline__ unsigned int f2bf(float x) {
    union { float f; unsigned int u; } v; v.f = x;
    unsigned int r = v.u + 0x7fffu + ((v.u >> 16) & 1u);   // RNE
    return r >> 16;
}
__device__ __forceinline__ float bf2f(unsigned int h) {
    union { unsigned int u; float f; } v; v.u = h << 16; return v.f;
}

// ---------------- min valid position per batch ----------------
__global__ __launch_bounds__(256) void k_minpos(const int* __restrict__ pos, float* __restrict__ minp)
{
    const int b = blockIdx.x;
    const int tid = threadIdx.x;
    int mn = 0x7fffffff;
    const int* p = pos + (size_t)b * S_LEN;
    for (int s = tid; s < S_LEN; s += 256) {
        const int v = p[s];
        if (v != -1) mn = min(mn, v);
    }
    __shared__ int red[256];
    red[tid] = mn;
    __syncthreads();
    for (int st = 128; st > 0; st >>= 1) {
        if (tid < st) red[tid] = min(red[tid], red[tid + st]);
        __syncthreads();
    }
    if (tid == 0) minp[b] = (float)red[0];
}

// ---------------- transpose W_proj (256x768) -> WpT (768x256) ----------------
__global__ __launch_bounds__(256) void k_wpt(const float* __restrict__ Wp, float* __restrict__ WpT)
{
    __shared__ float t[32][33];
    const int e0 = blockIdx.x * 32;   // 0..767
    const int d0 = blockIdx.y * 32;   // 0..255
    const int lx = threadIdx.x & 31, ly = threadIdx.x >> 5; // 32x8
#pragma unroll
    for (int q = 0; q < 4; ++q)
        t[ly + 8*q][lx] = Wp[(size_t)(d0 + ly + 8*q) * 768 + e0 + lx];
    __syncthreads();
#pragma unroll
    for (int q = 0; q < 4; ++q)
        WpT[(size_t)(e0 + ly + 8*q) * 256 + d0 + lx] = t[lx][ly + 8*q];
}

// ---------------- generic transpose + bf16 hi/lo split: W[K][N] -> out[N][K] ----------------
__global__ __launch_bounds__(256) void k_tsplit(const float* __restrict__ W, const int K, const int N,
                                                unsigned short* __restrict__ oh, unsigned short* __restrict__ ol)
{
    __shared__ float t[32][33];
    const int n0 = blockIdx.x * 32;
    const int k0 = blockIdx.y * 32;
    const int lx = threadIdx.x & 31, ly = threadIdx.x >> 5;
#pragma unroll
    for (int q = 0; q < 4; ++q)
        t[ly + 8*q][lx] = W[(size_t)(k0 + ly + 8*q) * N + n0 + lx];
    __syncthreads();
#pragma unroll
    for (int q = 0; q < 4; ++q) {
        const float v = t[lx][ly + 8*q];
        const unsigned int h = f2bf(v);
        oh[(size_t)(n0 + ly + 8*q) * K + k0 + lx] = (unsigned short)h;
        ol[(size_t)(n0 + ly + 8*q) * K + k0 + lx] = (unsigned short)f2bf(v - bf2f(h));
    }
}

// ---------------- WeffT[o][t*256+d] = sum_i WpT[g*256+i][d] * conv_w[o][i][t], split hi/lo bf16 ----------------
__global__ __launch_bounds__(256) void k_weff(const float* __restrict__ WpT, const float* __restrict__ cw,
                                              unsigned short* __restrict__ wth, unsigned short* __restrict__ wtl)
{
    const int o = blockIdx.x;       // 768
    const int d = threadIdx.x;      // 256
    const int g = o >> 8;
    __shared__ float cwrow[768];
    for (int i = threadIdx.x; i < 768; i += 256) cwrow[i] = cw[(size_t)o * 768 + i];
    __syncthreads();
    float a0 = 0.f, a1 = 0.f, a2 = 0.f;
    const float* wb = WpT + (size_t)(g * 256) * 256 + d;
#pragma unroll 4
    for (int i = 0; i < 256; ++i) {
        const float wv = wb[(size_t)i * 256];
        a0 += wv * cwrow[i*3+0];
        a1 += wv * cwrow[i*3+1];
        a2 += wv * cwrow[i*3+2];
    }
    const float av[3] = {a0, a1, a2};
#pragma unroll
    for (int t = 0; t < 3; ++t) {
        const unsigned int hb = f2bf(av[t]);
        const unsigned int lb = f2bf(av[t] - bf2f(hb));
        wth[(size_t)o * 768 + t * 256 + d] = (unsigned short)hb;
        wtl[(size_t)o * 768 + t * 256 + d] = (unsigned short)lb;
    }
}

// ---------------- MFMA conv-GEMM (verified: 128s x 128o, mt=2, 2-pass, reg-prefetch) ----------------
#define CG_LDA 40   // 32 + 8 pad (16B frag alignment preserved: 80B rows)
__global__ __launch_bounds__(256, 3) void k_convgemm(
    const float* __restrict__ emb, const int* __restrict__ pos,
    const unsigned short* __restrict__ wth, const unsigned short* __restrict__ wtl,
    const float* __restrict__ convb, float* __restrict__ c)
{
    const int b  = blockIdx.z;
    const int o0 = blockIdx.y * 128;
    const int s0 = blockIdx.x * 128;
    const int tid  = threadIdx.x;
    const int wave = tid >> 6, lane = tid & 63;
    const int m16  = lane & 15, quad = lane >> 4;

    __shared__ __align__(16) unsigned short As[130 * CG_LDA];
    __shared__ __align__(16) unsigned short Bh[128 * CG_LDA];
    __shared__ __align__(16) unsigned short Bl[128 * CG_LDA];

    // A staging: thread -> row rA = tid>>1 (0..127), 16 consecutive k-cols at cA
    const int rA = tid >> 1;
    const int cA = (tid & 1) * 16;
    const int srowA = s0 + rA - 1;
    const bool vA = (srowA >= 0 && srowA < S_LEN);
    const float* embA = emb + ((size_t)b * S_LEN + (vA ? srowA : 0)) * D_DIM + cA;
    // A tail rows 128..129: threads 0..15, 4 k-cols each
    const int rT = 128 + (tid >> 3);
    const int cT = (tid & 7) * 4;
    const int srowT = s0 + rT - 1;
    const bool vT = (tid < 16) && (srowT >= 0 && srowT < S_LEN);
    const float* embT = emb + ((size_t)b * S_LEN + ((tid < 16 && vT) ? srowT : 0)) * D_DIM + cT;

    // B staging: tasks {tid, tid+256}: row task>>2, 8 k-cols at (task&3)*8
    const int rB0 = tid >> 2,        gB0 = (tid & 3) * 8;
    const int rB1 = 64 + (tid >> 2), gB1 = gB0;

    float4 apf[4]; float4 apfT;
    uint4 bph0, bpl0, bph1, bpl1;

    // preload A(c8=0) and B(seg 0: t=0,c8=0)
#pragma unroll
    for (int q = 0; q < 4; ++q) apf[q] = vA ? *(const float4*)(embA + q * 4) : make_float4(0.f,0.f,0.f,0.f);
    apfT = vT ? *(const float4*)(embT) : make_float4(0.f,0.f,0.f,0.f);
    {
        const size_t gi0 = (size_t)(o0 + rB0) * 768 + gB0;
        const size_t gi1 = (size_t)(o0 + rB1) * 768 + gB1;
        bph0 = *(const uint4*)(wth + gi0); bpl0 = *(const uint4*)(wtl + gi0);
        bph1 = *(const uint4*)(wth + gi1); bpl1 = *(const uint4*)(wtl + gi1);
    }

    f32x4 acc[2][8];
#pragma unroll
    for (int mt = 0; mt < 2; ++mt)
#pragma unroll
        for (int nt = 0; nt < 8; ++nt)
#pragma unroll
            for (int e = 0; e < 4; ++e) acc[mt][nt][e] = 0.f;

    for (int c8 = 0; c8 < 8; ++c8) {
        for (int t = 0; t < 3; ++t) {
            __syncthreads();   // consumers of previous tiles done
            if (t == 0) {
                // write A (bf16 RNE) from prefetch regs
#pragma unroll
                for (int q = 0; q < 4; ++q) {
                    const float4 v = apf[q];
                    uint2 hp;
                    hp.x = f2bf(v.x) | (f2bf(v.y) << 16);
                    hp.y = f2bf(v.z) | (f2bf(v.w) << 16);
                    *(uint2*)&As[rA * CG_LDA + cA + q * 4] = hp;
                }
                if (tid < 16) {
                    const float4 v = apfT;
                    uint2 hp;
                    hp.x = f2bf(v.x) | (f2bf(v.y) << 16);
                    hp.y = f2bf(v.z) | (f2bf(v.w) << 16);
                    *(uint2*)&As[rT * CG_LDA + cT] = hp;
                }
                if (c8 < 7) {
                    const int base = (c8 + 1) * 32;
#pragma unroll
                    for (int q = 0; q < 4; ++q) apf[q] = vA ? *(const float4*)(embA + base + q * 4) : make_float4(0.f,0.f,0.f,0.f);
                    apfT = vT ? *(const float4*)(embT + base) : make_float4(0.f,0.f,0.f,0.f);
                }
            }
            // write B from prefetch regs
            *(uint4*)&Bh[rB0 * CG_LDA + gB0] = bph0;
            *(uint4*)&Bl[rB0 * CG_LDA + gB0] = bpl0;
            *(uint4*)&Bh[rB1 * CG_LDA + gB1] = bph1;
            *(uint4*)&Bl[rB1 * CG_LDA + gB1] = bpl1;
            // prefetch next segment's B
            if (!(c8 == 7 && t == 2)) {
                const int t2  = (t == 2) ? 0 : (t + 1);
                const int c82 = c8 + (t == 2);
                const int kbase = t2 * 256 + c82 * 32;
                const size_t gi0 = (size_t)(o0 + rB0) * 768 + kbase + gB0;
                const size_t gi1 = (size_t)(o0 + rB1) * 768 + kbase + gB1;
                bph0 = *(const uint4*)(wth + gi0); bpl0 = *(const uint4*)(wtl + gi0);
                bph1 = *(const uint4*)(wth + gi1); bpl1 = *(const uint4*)(wtl + gi1);
            }
            __syncthreads();   // tiles ready
            // MFMA segment (2-pass)
            short8 ah[2];
#pragma unroll
            for (int mt = 0; mt < 2; ++mt) {
                const int ar = (wave * 32 + mt * 16 + m16 + t) * CG_LDA + quad * 8;
                ah[mt] = *(const short8*)&As[ar];
            }
#pragma unroll
            for (int nt = 0; nt < 8; ++nt) {
                const int br = (nt * 16 + m16) * CG_LDA + quad * 8;
                const short8 bh = *(const short8*)&Bh[br];
                const short8 bl = *(const short8*)&Bl[br];
#pragma unroll
                for (int mt = 0; mt < 2; ++mt) {
                    acc[mt][nt] = __builtin_amdgcn_mfma_f32_16x16x32_bf16(ah[mt], bh, acc[mt][nt], 0, 0, 0);
                    acc[mt][nt] = __builtin_amdgcn_mfma_f32_16x16x32_bf16(ah[mt], bl, acc[mt][nt], 0, 0, 0);
                }
            }
        }
    }
    __syncthreads();

    // epilogue: +bias, *mask, store c[b][o][s] (float4 over s)
    float msk[2][4];
#pragma unroll
    for (int mt = 0; mt < 2; ++mt) {
        const int s = s0 + wave * 32 + mt * 16 + quad * 4;
        const int4 p4 = *(const int4*)(pos + (size_t)b * S_LEN + s);
        msk[mt][0] = (p4.x != -1) ? 1.f : 0.f;
        msk[mt][1] = (p4.y != -1) ? 1.f : 0.f;
        msk[mt][2] = (p4.z != -1) ? 1.f : 0.f;
        msk[mt][3] = (p4.w != -1) ? 1.f : 0.f;
    }
#pragma unroll
    for (int nt = 0; nt < 8; ++nt) {
        const int o = o0 + nt * 16 + m16;
        const float cb = convb[o];
#pragma unroll
        for (int mt = 0; mt < 2; ++mt) {
            const int s = s0 + wave * 32 + mt * 16 + quad * 4;
            float4 r;
            r.x = (acc[mt][nt][0] + cb) * msk[mt][0];
            r.y = (acc[mt][nt][1] + cb) * msk[mt][1];
            r.z = (acc[mt][nt][2] + cb) * msk[mt][2];
            r.w = (acc[mt][nt][3] + cb) * msk[mt][3];
            *(float4*)(c + ((size_t)(b * 768 + o)) * S_LEN + s) = r;
        }
    }
}

// ---------------- RoPE + FF (MFMA, LDS-staged B, 2-pass split: T/H plain bf16, W hi/lo) ----------------
#define FF_LDA 264   // 256 + 8 ushort pad: rows 528B apart (33*16B, 2-way banks = free)
#define FF_LDB 136   // 128 + 8 pad: rows 272B apart (17*16B)
__global__ __launch_bounds__(256, 2) void k_ff(
    const float* __restrict__ emb, const int* __restrict__ pos, const float* __restrict__ minp,
    const unsigned short* __restrict__ w1th, const unsigned short* __restrict__ w1tl,
    const float* __restrict__ b1,
    const float* __restrict__ lng, const float* __restrict__ lnb,
    const unsigned short* __restrict__ w2th, const unsigned short* __restrict__ w2tl,
    const float* __restrict__ b2, const float* __restrict__ ffs, float* __restrict__ hh)
{
    const int b   = blockIdx.y;
    const int s0  = blockIdx.x * 64;
    const int tid = threadIdx.x;
    const int wave = tid >> 6, lane = tid & 63;
    const int m16  = lane & 15, quad = lane >> 4;

    __shared__ __align__(16) unsigned short Th[64 * FF_LDA];
    __shared__ __align__(16) unsigned short Bsh[16 * FF_LDB];
    __shared__ __align__(16) unsigned short Bsl[16 * FF_LDB];
    __shared__ float th_s[128];

    if (tid < 128) th_s[tid] = expf(-(float)tid * 0.07195578415606394f);
    __syncthreads();

    // ---- RoPE -> Th (bf16 RNE; each thread: 1/4 of one row = 64 cols = 32 pairs) ----
    {
        const int r    = tid >> 2;            // 0..63
        const int col0 = (tid & 3) * 64;
        const int s    = s0 + r;
        const int p    = pos[(size_t)b * S_LEN + s];
        const float adj = (p == -1) ? -1.f : ((float)p - minp[b]);
        const float* ep = emb + ((size_t)b * S_LEN + s) * D_DIM;
#pragma unroll
        for (int p8 = 0; p8 < 8; ++p8) {
            const int cbase = col0 + p8 * 8;
            const float4 va = *(const float4*)(ep + cbase);
            const float4 vb4 = *(const float4*)(ep + cbase + 4);
            const float x[8] = {va.x, va.y, va.z, va.w, vb4.x, vb4.y, vb4.z, vb4.w};
            unsigned int uh[4];
#pragma unroll
            for (int jj = 0; jj < 4; ++jj) {
                const int j = (cbase >> 1) + jj;
                const float theta = th_s[j];
                float sn, cs;
                sincosf(adj * theta, &sn, &cs);
                const float x1 = x[2*jj], x2 = x[2*jj+1];
                const float r1 = x1 * cs - x2 * sn;
                const float r2 = x1 * sn + x2 * cs;
                uh[jj] = f2bf(r1) | (f2bf(r2) << 16);
            }
            uint4 wh;
            wh.x = uh[0]; wh.y = uh[1]; wh.z = uh[2]; wh.w = uh[3];
            *(uint4*)&Th[r * FF_LDA + cbase] = wh;
        }
    }
    __syncthreads();

    const int rowA  = wave * 16 + m16;
    const int strow = tid >> 4;           // staging: row 0..15
    const int stks  = (tid & 15) * 8;     // staging: k-segment

    // ---- GEMM1: H[64x256] = T @ W1 (2-pass split, LDS-staged B, reg-dbuf) ----
    f32x4 acc1[16];
#pragma unroll
    for (int nt = 0; nt < 16; ++nt)
#pragma unroll
        for (int e = 0; e < 4; ++e) acc1[nt][e] = 0.f;

    uint4 pfh, pfl;
    {
        const size_t gi = (size_t)strow * 256 + stks;   // nt=0, kh=0
        pfh = *(const uint4*)(w1th + gi);
        pfl = *(const uint4*)(w1tl + gi);
    }
    for (int kh = 0; kh < 2; ++kh) {
        short8 a1h[4];
#pragma unroll
        for (int c4 = 0; c4 < 4; ++c4) {
            const int ar = rowA * FF_LDA + kh * 128 + c4 * 32 + quad * 8;
            a1h[c4] = *(const short8*)&Th[ar];
        }
#pragma unroll
        for (int nt = 0; nt < 16; ++nt) {
            __syncthreads();   // previous tile's consumers done
            *(uint4*)&Bsh[strow * FF_LDB + stks] = pfh;
            *(uint4*)&Bsl[strow * FF_LDB + stks] = pfl;
            if (!(kh == 1 && nt == 15)) {
                const int nt2 = (nt + 1) & 15;
                const int kh2 = kh + (nt == 15);
                const size_t gi = (size_t)(nt2 * 16 + strow) * 256 + kh2 * 128 + stks;
                pfh = *(const uint4*)(w1th + gi);
                pfl = *(const uint4*)(w1tl + gi);
            }
            __syncthreads();   // tile ready
#pragma unroll
            for (int c4 = 0; c4 < 4; ++c4) {
                const int br = m16 * FF_LDB + c4 * 32 + quad * 8;
                const short8 bh = *(const short8*)&Bsh[br];
                const short8 bl = *(const short8*)&Bsl[br];
                acc1[nt] = __builtin_amdgcn_mfma_f32_16x16x32_bf16(a1h[c4], bh, acc1[nt], 0, 0, 0);
                acc1[nt] = __builtin_amdgcn_mfma_f32_16x16x32_bf16(a1h[c4], bl, acc1[nt], 0, 0, 0);
            }
        }
    }

    // ---- +b1, LayerNorm stats (in-register, shfl over m16 group) ----
    float sume[4] = {0.f, 0.f, 0.f, 0.f}, sumq[4] = {0.f, 0.f, 0.f, 0.f};
#pragma unroll
    for (int nt = 0; nt < 16; ++nt) {
        const float bb = b1[nt * 16 + m16];
#pragma unroll
        for (int e = 0; e < 4; ++e) {
            const float v = acc1[nt][e] + bb;
            acc1[nt][e] = v;
            sume[e] += v;
            sumq[e] += v * v;
        }
    }
#pragma unroll
    for (int e = 0; e < 4; ++e) {
#pragma unroll
        for (int off = 1; off < 16; off <<= 1) {
            sume[e] += __shfl_xor(sume[e], off, 64);
            sumq[e] += __shfl_xor(sumq[e], off, 64);
        }
    }
    float mu[4], rs[4];
#pragma unroll
    for (int e = 0; e < 4; ++e) {
        mu[e] = sume[e] * (1.f / 256.f);
        const float var = sumq[e] * (1.f / 256.f) - mu[e] * mu[e];
        rs[e] = rsqrtf(var + 1e-5f);
    }

    // preload GEMM2 tile (0,0) while LN finishes
    {
        const size_t gi = (size_t)strow * 256 + stks;
        pfh = *(const uint4*)(w2th + gi);
        pfl = *(const uint4*)(w2tl + gi);
    }

    // ---- LN + GELU, write H (bf16) back into Th ----
    __syncthreads();   // all waves done reading T / Bs
#pragma unroll
    for (int nt = 0; nt < 16; ++nt) {
        const int col = nt * 16 + m16;
        const float g  = lng[col];
        const float be = lnb[col];
#pragma unroll
        for (int e = 0; e < 4; ++e) {
            const float h  = (acc1[nt][e] - mu[e]) * rs[e] * g + be;
            const float hg = 0.5f * h * (1.f + erff(h * 0.7071067811865475f));
            const int li = (wave * 16 + quad * 4 + e) * FF_LDA + col;
            Th[li] = (unsigned short)f2bf(hg);
        }
    }
    __syncthreads();

    // ---- GEMM2: A[64x512] = Hg @ W2 (2-pass split, LDS-staged B, reg-dbuf) ----
    f32x4 acc2[32];
#pragma unroll
    for (int nt = 0; nt < 32; ++nt)
#pragma unroll
        for (int e = 0; e < 4; ++e) acc2[nt][e] = 0.f;

    for (int kh = 0; kh < 2; ++kh) {
        short8 a2h[4];
#pragma unroll
        for (int c4 = 0; c4 < 4; ++c4) {
            const int ar = rowA * FF_LDA + kh * 128 + c4 * 32 + quad * 8;
            a2h[c4] = *(const short8*)&Th[ar];
        }
#pragma unroll
        for (int nt = 0; nt < 32; ++nt) {
            __syncthreads();
            *(uint4*)&Bsh[strow * FF_LDB + stks] = pfh;
            *(uint4*)&Bsl[strow * FF_LDB + stks] = pfl;
            if (!(kh == 1 && nt == 31)) {
                const int nt2 = (nt + 1) & 31;
                const int kh2 = kh + (nt == 31);
                const size_t gi = (size_t)(nt2 * 16 + strow) * 256 + kh2 * 128 + stks;
                pfh = *(const uint4*)(w2th + gi);
                pfl = *(const uint4*)(w2tl + gi);
            }
            __syncthreads();
#pragma unroll
            for (int c4 = 0; c4 < 4; ++c4) {
                const int br = m16 * FF_LDB + c4 * 32 + quad * 8;
                const short8 bh = *(const short8*)&Bsh[br];
                const short8 bl = *(const short8*)&Bsl[br];
                acc2[nt] = __builtin_amdgcn_mfma_f32_16x16x32_bf16(a2h[c4], bh, acc2[nt], 0, 0, 0);
                acc2[nt] = __builtin_amdgcn_mfma_f32_16x16x32_bf16(a2h[c4], bl, acc2[nt], 0, 0, 0);
            }
        }
    }

    // ---- (a+b2)*ffs, L1-norm per (row, half), store hh[b][i][d][s] ----
    float sm[2][4] = {{0.f,0.f,0.f,0.f},{0.f,0.f,0.f,0.f}};
#pragma unroll
    for (int nt = 0; nt < 32; ++nt) {
        const int col = nt * 16 + m16;
        const float bb = b2[col];
        const float fs = ffs[col];
#pragma unroll
        for (int e = 0; e < 4; ++e) {
            const float v = (acc2[nt][e] + bb) * fs;
            acc2[nt][e] = v;
            sm[nt >> 4][e] += fabsf(v);
        }
    }
#pragma unroll
    for (int i = 0; i < 2; ++i)
#pragma unroll
        for (int e = 0; e < 4; ++e) {
#pragma unroll
            for (int off = 1; off < 16; off <<= 1)
                sm[i][e] += __shfl_xor(sm[i][e], off, 64);
        }
#pragma unroll
    for (int nt = 0; nt < 32; ++nt) {
        const int i = nt >> 4;
        const int d = (nt & 15) * 16 + m16;
        float4 o4;
        o4.x = acc2[nt][0] / (sm[i][0] + 1e-8f);
        o4.y = acc2[nt][1] / (sm[i][1] + 1e-8f);
        o4.z = acc2[nt][2] / (sm[i][2] + 1e-8f);
        o4.w = acc2[nt][3] / (sm[i][3] + 1e-8f);
        *(float4*)(hh + ((size_t)((b * 2 + i) * 256 + d)) * S_LEN + s0 + wave * 16 + quad * 4) = o4;
    }
}

// ---------------- MFMA blocked-Toeplitz causal long conv (2-wave r-split) ----------------
// 128 threads: wave w accumulates partial sums over r = 2i+w (interleaved so the causal
// pt>=ptmin skip stays balanced), then wave1 dumps acc to LDS (reusing frx) and wave0
// adds + runs the unchanged epilogue. Frag addressing & MFMA sequence byte-identical.
#define XS_PAD   960
#define XS_ELEMS 5056
#define FRX_WORDS 4160
__device__ __forceinline__ int xsw(int blk) { return blk ^ ((blk >> 3) & 7); }

__global__ __launch_bounds__(128) void k_conv_mfma(
    const float* __restrict__ xbuf, const int xC, const int xoff,
    const float* __restrict__ hh, const int iord,
    const float* __restrict__ cbuf, float* __restrict__ outb)
{
    const int d = blockIdx.x;
    const int b = blockIdx.y;
    const int tid  = threadIdx.x;
    const int lane = tid & 63;
    const int wid  = tid >> 6;
    const float* xp = xbuf + ((size_t)(b * xC + xoff + d)) * S_LEN;
    const float* fp = hh   + ((size_t)((b * 2 + iord) * 256 + d)) * S_LEN;
    const float* zp = cbuf + ((size_t)(b * 768 + iord * 256 + d)) * S_LEN;
    float* op = outb + ((size_t)(b * 256 + d)) * S_LEN;

    __shared__ __align__(16) unsigned short xs[XS_ELEMS];
    __shared__ __align__(16) unsigned int   frx[FRX_WORDS];

    {
        for (int blk = tid; blk < 120; blk += 128) {
            int4 z; z.x = 0; z.y = 0; z.z = 0; z.w = 0;
            *(int4*)(xs + xsw(blk) * 8) = z;
        }
#pragma unroll
        for (int it = 0; it < 4; ++it) {
            const int idx = it * 128 + tid;
            const int j = idx * 8;
            const float4 v0 = *(const float4*)(xp + j);
            const float4 v1 = *(const float4*)(xp + j + 4);
            int4 w;
            w.x = (int)(f2bf(v0.x) | (f2bf(v0.y) << 16));
            w.y = (int)(f2bf(v0.z) | (f2bf(v0.w) << 16));
            w.z = (int)(f2bf(v1.x) | (f2bf(v1.y) << 16));
            w.w = (int)(f2bf(v1.z) | (f2bf(v1.w) << 16));
            *(int4*)(xs + xsw(120 + idx) * 8) = w;
        }
    }
    {
        if (tid < 64) frx[4096 + tid] = 0u;
        if (tid == 0) frx[4095] = f2bf(fp[0]);
#pragma unroll
        for (int it = 0; it < 8; ++it) {
            const int j = (it * 128 + tid) * 4;
            const float4 v = *(const float4*)(fp + j);
            const float f4 = (j + 4 < S_LEN) ? fp[j + 4] : 0.f;
            frx[4094 - j] = f2bf(v.y) | (f2bf(v.x) << 16);
            frx[4093 - j] = f2bf(v.z) | (f2bf(v.y) << 16);
            frx[4092 - j] = f2bf(v.w) | (f2bf(v.z) << 16);
            if (j < 4092) frx[4091 - j] = f2bf(f4) | (f2bf(v.w) << 16);
        }
    }
    __syncthreads();

    const int m    = lane & 15;
    const int quad = lane >> 4;

    f32x4 acc[4][4];
#pragma unroll
    for (int mt = 0; mt < 4; ++mt)
#pragma unroll
        for (int pt = 0; pt < 4; ++pt)
#pragma unroll
            for (int e = 0; e < 4; ++e) acc[mt][pt][e] = 0.f;

    const int eA_base = 4095 - m + quad * 8;
    const int oB_base = XS_PAD + 64 * m + quad * 8;

    for (int i = 0; i < 32; ++i) {
        const int r = 2 * i + wid;
        const int ea_r = eA_base - 64 * r;
        short8 afr[4][2];
#pragma unroll
        for (int mt = 0; mt < 4; ++mt)
#pragma unroll
            for (int kc = 0; kc < 2; ++kc) {
                const int e = ea_r - 16 * mt + 32 * kc;
                union { unsigned int u[4]; short8 s; } cvt;
                cvt.u[0] = frx[e];
                cvt.u[1] = frx[e + 2];
                cvt.u[2] = frx[e + 4];
                cvt.u[3] = frx[e + 6];
                afr[mt][kc] = cvt.s;
            }
        const int ptmin = r >> 4;
        const int ob_r = oB_base - 64 * r;
#pragma unroll
        for (int pt = 0; pt < 4; ++pt) {
            if (pt >= ptmin) {
                const int o0 = ob_r + 1024 * pt;
                const short8 bfr0 = *(const short8*)(xs + xsw(o0 >> 3) * 8);
                const short8 bfr1 = *(const short8*)(xs + xsw((o0 + 32) >> 3) * 8);
#pragma unroll
                for (int mt = 0; mt < 4; ++mt) {
                    acc[mt][pt] = __builtin_amdgcn_mfma_f32_16x16x32_bf16(afr[mt][0], bfr0, acc[mt][pt], 0, 0, 0);
                    acc[mt][pt] = __builtin_amdgcn_mfma_f32_16x16x32_bf16(afr[mt][1], bfr1, acc[mt][pt], 0, 0, 0);
                }
            }
        }
    }

    // cross-wave reduction: wave1 dumps partials into LDS (frx reused), wave0 adds + epilogue
    __syncthreads();
    float* red = (float*)frx;   // need 16 slots * 64 lanes * 16B = 16384B <= 16640B
    if (wid == 1) {
#pragma unroll
        for (int mt = 0; mt < 4; ++mt)
#pragma unroll
            for (int pt = 0; pt < 4; ++pt)
                *(f32x4*)&red[((mt * 4 + pt) * 64 + lane) * 4] = acc[mt][pt];
    }
    __syncthreads();
    if (wid == 0) {
        const float inv = 1.f / 8192.f;
#pragma unroll
        for (int mt = 0; mt < 4; ++mt)
#pragma unroll
            for (int pt = 0; pt < 4; ++pt) {
                const f32x4 po = *(const f32x4*)&red[((mt * 4 + pt) * 64 + lane) * 4];
                const int p  = 16 * pt + m;
                const int s0 = 64 * p + 16 * mt + quad * 4;
                const float4 z4 = *(const float4*)(zp + s0);
                float4 o4;
                o4.x = z4.x * (acc[mt][pt][0] + po[0]) * inv;
                o4.y = z4.y * (acc[mt][pt][1] + po[1]) * inv;
                o4.z = z4.z * (acc[mt][pt][2] + po[2]) * inv;
                o4.w = z4.w * (acc[mt][pt][3] + po[3]) * inv;
                *(float4*)(op + s0) = o4;
            }
    }
}

// ---------------- out[b][s][e] = mask * (sum_d v[b][d][s] * W_out[d][e] + b_out[e]) ----------------
__global__ __launch_bounds__(256) void k_out(
    const float* __restrict__ v, const float* __restrict__ Wo,
    const float* __restrict__ bo, const int* __restrict__ pos,
    float* __restrict__ out)
{
    const int b   = blockIdx.y;
    const int s0  = blockIdx.x * 32;
    const int tid = threadIdx.x;
    __shared__ float vs[256 * 36];
    {
        const float4* src = (const float4*)(v + ((size_t)(b*256 + tid)) * S_LEN + s0);
#pragma unroll
        for (int q = 0; q < 8; ++q) {
            *(float4*)&vs[tid*36 + q*4] = src[q];
        }
    }
    __syncthreads();
    float acc[32];
#pragma unroll
    for (int r = 0; r < 32; ++r) acc[r] = 0.f;
    for (int dd = 0; dd < 256; ++dd) {
        const float w = Wo[(size_t)dd * 256 + tid];
        const float* vr = &vs[dd * 36];
#pragma unroll
        for (int q = 0; q < 8; ++q) {
            const float4 x4 = *(const float4*)&vr[q*4];
            acc[q*4+0] += x4.x * w;
            acc[q*4+1] += x4.y * w;
            acc[q*4+2] += x4.z * w;
            acc[q*4+3] += x4.w * w;
        }
    }
    const float bb = bo[tid];
#pragma unroll
    for (int r = 0; r < 32; ++r) {
        const int s = s0 + r;
        const float m = (pos[(size_t)b * S_LEN + s] != -1) ? 1.f : 0.f;
        out[((size_t)b * S_LEN + s) * 256 + tid] = (acc[r] + bb) * m;
    }
}

extern "C" void kernel_launch(void* const* d_in, const int* in_sizes, int n_in,
                              void* d_out, int out_size, void* d_ws, size_t ws_size,
                              hipStream_t stream) {
    const float* emb = (const float*)d_in[0];
    const int*   pos = (const int*)  d_in[1];
    const float* Wp  = (const float*)d_in[2];
    const float* cw  = (const float*)d_in[3];
    const float* cb  = (const float*)d_in[4];
    const float* W1  = (const float*)d_in[5];
    const float* b1  = (const float*)d_in[6];
    const float* lg  = (const float*)d_in[7];
    const float* lb  = (const float*)d_in[8];
    const float* W2  = (const float*)d_in[9];
    const float* b2  = (const float*)d_in[10];
    const float* ffs = (const float*)d_in[11];
    const float* Wo  = (const float*)d_in[12];
    const float* bo  = (const float*)d_in[13];

    float* ws   = (float*)d_ws;
    float* minp = ws + OFF_MINP;
    float* wpt  = ws + OFF_WPT;
    unsigned short* wth = (unsigned short*)(ws + OFF_WTH);
    unsigned short* wtl = (unsigned short*)(ws + OFF_WTL);
    float* c    = ws + OFF_C;
    float* hh   = ws + OFF_HH;
    float* vb   = ws + OFF_V;
    float* ub   = ws + OFF_U;

    // FF weight splits carved from the head of vb (consumed by k_ff before conv#1 writes vb)
    unsigned short* w1th = (unsigned short*)vb;
    unsigned short* w1tl = w1th + 256 * 256;
    unsigned short* w2th = w1tl + 256 * 256;
    unsigned short* w2tl = w2th + 512 * 256;

    k_minpos<<<dim3(8), dim3(256), 0, stream>>>(pos, minp);
    k_wpt<<<dim3(24, 8), dim3(256), 0, stream>>>(Wp, wpt);
    k_weff<<<dim3(768), dim3(256), 0, stream>>>(wpt, cw, wth, wtl);
    k_tsplit<<<dim3(8, 8), dim3(256), 0, stream>>>(W1, 256, 256, w1th, w1tl);
    k_tsplit<<<dim3(16, 8), dim3(256), 0, stream>>>(W2, 256, 512, w2th, w2tl);
    k_convgemm<<<dim3(32, 6, 8), dim3(256), 0, stream>>>(emb, pos, wth, wtl, cb, c);
    k_ff<<<dim3(64, 8), dim3(256), 0, stream>>>(emb, pos, minp, w1th, w1tl, b1, lg, lb, w2th, w2tl, b2, ffs, hh);
    // v = zs[2]; v = zs[0] * longconv(v, hh[:,0]); v = zs[1] * longconv(v, hh[:,1])
    k_conv_mfma<<<dim3(256, 8), dim3(128), 0, stream>>>(c, 768, 512, hh, 0, c, vb);
    k_conv_mfma<<<dim3(256, 8), dim3(128), 0, stream>>>(vb, 256, 0, hh, 1, c, ub);
    k_out<<<dim3(128, 8), dim3(256), 0, stream>>>(ub, Wo, bo, pos, (float*)d_out);
}

// Round 8
// 483.955 us; speedup vs baseline: 1.3340x; 1.0577x over previous
//
#include <hip/hip_runtime.h>
#include <cstdint>

#define S_LEN 4096
#define D_DIM 256

// workspace layout (float offsets)
#define OFF_MINP 0
#define OFF_WPT  16
#define OFF_WTH  (OFF_WPT + 768*256)     // WeffT hi, 768x768 ushort = 294912 floats
#define OFF_WTL  (OFF_WTH + 294912)      // WeffT lo
#define OFF_C    (OFF_WTL + 294912)      // == old OFF_C, downstream unchanged
#define OFF_HH   (OFF_C + 8*768*4096)
#define OFF_V    (OFF_HH + 8*2*256*4096)
#define OFF_U    (OFF_V + 8*256*4096)

// FF weight splits live at the head of the V region (consumed by k_ff; the V region
// is otherwise unused now that conv1+conv2 are fused and v never hits HBM).

typedef __attribute__((ext_vector_type(8))) short short8;
typedef __attribute__((ext_vector_type(4))) float f32x4;

__device__ __forceinline__ unsigned int f2bf(float x) {
    union { float f; unsigned int u; } v; v.f = x;
    unsigned int r = v.u + 0x7fffu + ((v.u >> 16) & 1u);   // RNE
    return r >> 16;
}
__device__ __forceinline__ float bf2f(unsigned int h) {
    union { unsigned int u; float f; } v; v.u = h << 16; return v.f;
}

// ---------------- min valid position per batch ----------------
__global__ __launch_bounds__(256) void k_minpos(const int* __restrict__ pos, float* __restrict__ minp)
{
    const int b = blockIdx.x;
    const int tid = threadIdx.x;
    int mn = 0x7fffffff;
    const int* p = pos + (size_t)b * S_LEN;
    for (int s = tid; s < S_LEN; s += 256) {
        const int v = p[s];
        if (v != -1) mn = min(mn, v);
    }
    __shared__ int red[256];
    red[tid] = mn;
    __syncthreads();
    for (int st = 128; st > 0; st >>= 1) {
        if (tid < st) red[tid] = min(red[tid], red[tid + st]);
        __syncthreads();
    }
    if (tid == 0) minp[b] = (float)red[0];
}

// ---------------- transpose W_proj (256x768) -> WpT (768x256) ----------------
__global__ __launch_bounds__(256) void k_wpt(const float* __restrict__ Wp, float* __restrict__ WpT)
{
    __shared__ float t[32][33];
    const int e0 = blockIdx.x * 32;   // 0..767
    const int d0 = blockIdx.y * 32;   // 0..255
    const int lx = threadIdx.x & 31, ly = threadIdx.x >> 5; // 32x8
#pragma unroll
    for (int q = 0; q < 4; ++q)
        t[ly + 8*q][lx] = Wp[(size_t)(d0 + ly + 8*q) * 768 + e0 + lx];
    __syncthreads();
#pragma unroll
    for (int q = 0; q < 4; ++q)
        WpT[(size_t)(e0 + ly + 8*q) * 256 + d0 + lx] = t[lx][ly + 8*q];
}

// ---------------- generic transpose + bf16 hi/lo split: W[K][N] -> out[N][K] ----------------
__global__ __launch_bounds__(256) void k_tsplit(const float* __restrict__ W, const int K, const int N,
                                                unsigned short* __restrict__ oh, unsigned short* __restrict__ ol)
{
    __shared__ float t[32][33];
    const int n0 = blockIdx.x * 32;
    const int k0 = blockIdx.y * 32;
    const int lx = threadIdx.x & 31, ly = threadIdx.x >> 5;
#pragma unroll
    for (int q = 0; q < 4; ++q)
        t[ly + 8*q][lx] = W[(size_t)(k0 + ly + 8*q) * N + n0 + lx];
    __syncthreads();
#pragma unroll
    for (int q = 0; q < 4; ++q) {
        const float v = t[lx][ly + 8*q];
        const unsigned int h = f2bf(v);
        oh[(size_t)(n0 + ly + 8*q) * K + k0 + lx] = (unsigned short)h;
        ol[(size_t)(n0 + ly + 8*q) * K + k0 + lx] = (unsigned short)f2bf(v - bf2f(h));
    }
}

// ---------------- WeffT[o][t*256+d] = sum_i WpT[g*256+i][d] * conv_w[o][i][t], split hi/lo bf16 ----------------
__global__ __launch_bounds__(256) void k_weff(const float* __restrict__ WpT, const float* __restrict__ cw,
                                              unsigned short* __restrict__ wth, unsigned short* __restrict__ wtl)
{
    const int o = blockIdx.x;       // 768
    const int d = threadIdx.x;      // 256
    const int g = o >> 8;
    __shared__ float cwrow[768];
    for (int i = threadIdx.x; i < 768; i += 256) cwrow[i] = cw[(size_t)o * 768 + i];
    __syncthreads();
    float a0 = 0.f, a1 = 0.f, a2 = 0.f;
    const float* wb = WpT + (size_t)(g * 256) * 256 + d;
#pragma unroll 4
    for (int i = 0; i < 256; ++i) {
        const float wv = wb[(size_t)i * 256];
        a0 += wv * cwrow[i*3+0];
        a1 += wv * cwrow[i*3+1];
        a2 += wv * cwrow[i*3+2];
    }
    const float av[3] = {a0, a1, a2};
#pragma unroll
    for (int t = 0; t < 3; ++t) {
        const unsigned int hb = f2bf(av[t]);
        const unsigned int lb = f2bf(av[t] - bf2f(hb));
        wth[(size_t)o * 768 + t * 256 + d] = (unsigned short)hb;
        wtl[(size_t)o * 768 + t * 256 + d] = (unsigned short)lb;
    }
}

// ---------------- MFMA conv-GEMM (verified: 128s x 128o, mt=2, 2-pass, reg-prefetch) ----------------
#define CG_LDA 40   // 32 + 8 pad (16B frag alignment preserved: 80B rows)
__global__ __launch_bounds__(256, 3) void k_convgemm(
    const float* __restrict__ emb, const int* __restrict__ pos,
    const unsigned short* __restrict__ wth, const unsigned short* __restrict__ wtl,
    const float* __restrict__ convb, float* __restrict__ c)
{
    const int b  = blockIdx.z;
    const int o0 = blockIdx.y * 128;
    const int s0 = blockIdx.x * 128;
    const int tid  = threadIdx.x;
    const int wave = tid >> 6, lane = tid & 63;
    const int m16  = lane & 15, quad = lane >> 4;

    __shared__ __align__(16) unsigned short As[130 * CG_LDA];
    __shared__ __align__(16) unsigned short Bh[128 * CG_LDA];
    __shared__ __align__(16) unsigned short Bl[128 * CG_LDA];

    // A staging: thread -> row rA = tid>>1 (0..127), 16 consecutive k-cols at cA
    const int rA = tid >> 1;
    const int cA = (tid & 1) * 16;
    const int srowA = s0 + rA - 1;
    const bool vA = (srowA >= 0 && srowA < S_LEN);
    const float* embA = emb + ((size_t)b * S_LEN + (vA ? srowA : 0)) * D_DIM + cA;
    // A tail rows 128..129: threads 0..15, 4 k-cols each
    const int rT = 128 + (tid >> 3);
    const int cT = (tid & 7) * 4;
    const int srowT = s0 + rT - 1;
    const bool vT = (tid < 16) && (srowT >= 0 && srowT < S_LEN);
    const float* embT = emb + ((size_t)b * S_LEN + ((tid < 16 && vT) ? srowT : 0)) * D_DIM + cT;

    // B staging: tasks {tid, tid+256}: row task>>2, 8 k-cols at (task&3)*8
    const int rB0 = tid >> 2,        gB0 = (tid & 3) * 8;
    const int rB1 = 64 + (tid >> 2), gB1 = gB0;

    float4 apf[4]; float4 apfT;
    uint4 bph0, bpl0, bph1, bpl1;

    // preload A(c8=0) and B(seg 0: t=0,c8=0)
#pragma unroll
    for (int q = 0; q < 4; ++q) apf[q] = vA ? *(const float4*)(embA + q * 4) : make_float4(0.f,0.f,0.f,0.f);
    apfT = vT ? *(const float4*)(embT) : make_float4(0.f,0.f,0.f,0.f);
    {
        const size_t gi0 = (size_t)(o0 + rB0) * 768 + gB0;
        const size_t gi1 = (size_t)(o0 + rB1) * 768 + gB1;
        bph0 = *(const uint4*)(wth + gi0); bpl0 = *(const uint4*)(wtl + gi0);
        bph1 = *(const uint4*)(wth + gi1); bpl1 = *(const uint4*)(wtl + gi1);
    }

    f32x4 acc[2][8];
#pragma unroll
    for (int mt = 0; mt < 2; ++mt)
#pragma unroll
        for (int nt = 0; nt < 8; ++nt)
#pragma unroll
            for (int e = 0; e < 4; ++e) acc[mt][nt][e] = 0.f;

    for (int c8 = 0; c8 < 8; ++c8) {
        for (int t = 0; t < 3; ++t) {
            __syncthreads();   // consumers of previous tiles done
            if (t == 0) {
                // write A (bf16 RNE) from prefetch regs
#pragma unroll
                for (int q = 0; q < 4; ++q) {
                    const float4 v = apf[q];
                    uint2 hp;
                    hp.x = f2bf(v.x) | (f2bf(v.y) << 16);
                    hp.y = f2bf(v.z) | (f2bf(v.w) << 16);
                    *(uint2*)&As[rA * CG_LDA + cA + q * 4] = hp;
                }
                if (tid < 16) {
                    const float4 v = apfT;
                    uint2 hp;
                    hp.x = f2bf(v.x) | (f2bf(v.y) << 16);
                    hp.y = f2bf(v.z) | (f2bf(v.w) << 16);
                    *(uint2*)&As[rT * CG_LDA + cT] = hp;
                }
                if (c8 < 7) {
                    const int base = (c8 + 1) * 32;
#pragma unroll
                    for (int q = 0; q < 4; ++q) apf[q] = vA ? *(const float4*)(embA + base + q * 4) : make_float4(0.f,0.f,0.f,0.f);
                    apfT = vT ? *(const float4*)(embT + base) : make_float4(0.f,0.f,0.f,0.f);
                }
            }
            // write B from prefetch regs
            *(uint4*)&Bh[rB0 * CG_LDA + gB0] = bph0;
            *(uint4*)&Bl[rB0 * CG_LDA + gB0] = bpl0;
            *(uint4*)&Bh[rB1 * CG_LDA + gB1] = bph1;
            *(uint4*)&Bl[rB1 * CG_LDA + gB1] = bpl1;
            // prefetch next segment's B
            if (!(c8 == 7 && t == 2)) {
                const int t2  = (t == 2) ? 0 : (t + 1);
                const int c82 = c8 + (t == 2);
                const int kbase = t2 * 256 + c82 * 32;
                const size_t gi0 = (size_t)(o0 + rB0) * 768 + kbase + gB0;
                const size_t gi1 = (size_t)(o0 + rB1) * 768 + kbase + gB1;
                bph0 = *(const uint4*)(wth + gi0); bpl0 = *(const uint4*)(wtl + gi0);
                bph1 = *(const uint4*)(wth + gi1); bpl1 = *(const uint4*)(wtl + gi1);
            }
            __syncthreads();   // tiles ready
            // MFMA segment (2-pass)
            short8 ah[2];
#pragma unroll
            for (int mt = 0; mt < 2; ++mt) {
                const int ar = (wave * 32 + mt * 16 + m16 + t) * CG_LDA + quad * 8;
                ah[mt] = *(const short8*)&As[ar];
            }
#pragma unroll
            for (int nt = 0; nt < 8; ++nt) {
                const int br = (nt * 16 + m16) * CG_LDA + quad * 8;
                const short8 bh = *(const short8*)&Bh[br];
                const short8 bl = *(const short8*)&Bl[br];
#pragma unroll
                for (int mt = 0; mt < 2; ++mt) {
                    acc[mt][nt] = __builtin_amdgcn_mfma_f32_16x16x32_bf16(ah[mt], bh, acc[mt][nt], 0, 0, 0);
                    acc[mt][nt] = __builtin_amdgcn_mfma_f32_16x16x32_bf16(ah[mt], bl, acc[mt][nt], 0, 0, 0);
                }
            }
        }
    }
    __syncthreads();

    // epilogue: +bias, *mask, store c[b][o][s] (float4 over s)
    float msk[2][4];
#pragma unroll
    for (int mt = 0; mt < 2; ++mt) {
        const int s = s0 + wave * 32 + mt * 16 + quad * 4;
        const int4 p4 = *(const int4*)(pos + (size_t)b * S_LEN + s);
        msk[mt][0] = (p4.x != -1) ? 1.f : 0.f;
        msk[mt][1] = (p4.y != -1) ? 1.f : 0.f;
        msk[mt][2] = (p4.z != -1) ? 1.f : 0.f;
        msk[mt][3] = (p4.w != -1) ? 1.f : 0.f;
    }
#pragma unroll
    for (int nt = 0; nt < 8; ++nt) {
        const int o = o0 + nt * 16 + m16;
        const float cb = convb[o];
#pragma unroll
        for (int mt = 0; mt < 2; ++mt) {
            const int s = s0 + wave * 32 + mt * 16 + quad * 4;
            float4 r;
            r.x = (acc[mt][nt][0] + cb) * msk[mt][0];
            r.y = (acc[mt][nt][1] + cb) * msk[mt][1];
            r.z = (acc[mt][nt][2] + cb) * msk[mt][2];
            r.w = (acc[mt][nt][3] + cb) * msk[mt][3];
            *(float4*)(c + ((size_t)(b * 768 + o)) * S_LEN + s) = r;
        }
    }
}

// ---------------- RoPE + FF (MFMA, LDS-staged B, 2-pass split: T/H plain bf16, W hi/lo) ----------------
#define FF_LDA 264   // 256 + 8 ushort pad: rows 528B apart (33*16B, 2-way banks = free)
#define FF_LDB 136   // 128 + 8 pad: rows 272B apart (17*16B)
__global__ __launch_bounds__(256, 2) void k_ff(
    const float* __restrict__ emb, const int* __restrict__ pos, const float* __restrict__ minp,
    const unsigned short* __restrict__ w1th, const unsigned short* __restrict__ w1tl,
    const float* __restrict__ b1,
    const float* __restrict__ lng, const float* __restrict__ lnb,
    const unsigned short* __restrict__ w2th, const unsigned short* __restrict__ w2tl,
    const float* __restrict__ b2, const float* __restrict__ ffs, float* __restrict__ hh)
{
    const int b   = blockIdx.y;
    const int s0  = blockIdx.x * 64;
    const int tid = threadIdx.x;
    const int wave = tid >> 6, lane = tid & 63;
    const int m16  = lane & 15, quad = lane >> 4;

    __shared__ __align__(16) unsigned short Th[64 * FF_LDA];
    __shared__ __align__(16) unsigned short Bsh[16 * FF_LDB];
    __shared__ __align__(16) unsigned short Bsl[16 * FF_LDB];
    __shared__ float th_s[128];

    if (tid < 128) th_s[tid] = expf(-(float)tid * 0.07195578415606394f);
    __syncthreads();

    // ---- RoPE -> Th (bf16 RNE; each thread: 1/4 of one row = 64 cols = 32 pairs) ----
    {
        const int r    = tid >> 2;            // 0..63
        const int col0 = (tid & 3) * 64;
        const int s    = s0 + r;
        const int p    = pos[(size_t)b * S_LEN + s];
        const float adj = (p == -1) ? -1.f : ((float)p - minp[b]);
        const float* ep = emb + ((size_t)b * S_LEN + s) * D_DIM;
#pragma unroll
        for (int p8 = 0; p8 < 8; ++p8) {
            const int cbase = col0 + p8 * 8;
            const float4 va = *(const float4*)(ep + cbase);
            const float4 vb4 = *(const float4*)(ep + cbase + 4);
            const float x[8] = {va.x, va.y, va.z, va.w, vb4.x, vb4.y, vb4.z, vb4.w};
            unsigned int uh[4];
#pragma unroll
            for (int jj = 0; jj < 4; ++jj) {
                const int j = (cbase >> 1) + jj;
                const float theta = th_s[j];
                float sn, cs;
                sincosf(adj * theta, &sn, &cs);
                const float x1 = x[2*jj], x2 = x[2*jj+1];
                const float r1 = x1 * cs - x2 * sn;
                const float r2 = x1 * sn + x2 * cs;
                uh[jj] = f2bf(r1) | (f2bf(r2) << 16);
            }
            uint4 wh;
            wh.x = uh[0]; wh.y = uh[1]; wh.z = uh[2]; wh.w = uh[3];
            *(uint4*)&Th[r * FF_LDA + cbase] = wh;
        }
    }
    __syncthreads();

    const int rowA  = wave * 16 + m16;
    const int strow = tid >> 4;           // staging: row 0..15
    const int stks  = (tid & 15) * 8;     // staging: k-segment

    // ---- GEMM1: H[64x256] = T @ W1 (2-pass split, LDS-staged B, reg-dbuf) ----
    f32x4 acc1[16];
#pragma unroll
    for (int nt = 0; nt < 16; ++nt)
#pragma unroll
        for (int e = 0; e < 4; ++e) acc1[nt][e] = 0.f;

    uint4 pfh, pfl;
    {
        const size_t gi = (size_t)strow * 256 + stks;   // nt=0, kh=0
        pfh = *(const uint4*)(w1th + gi);
        pfl = *(const uint4*)(w1tl + gi);
    }
    for (int kh = 0; kh < 2; ++kh) {
        short8 a1h[4];
#pragma unroll
        for (int c4 = 0; c4 < 4; ++c4) {
            const int ar = rowA * FF_LDA + kh * 128 + c4 * 32 + quad * 8;
            a1h[c4] = *(const short8*)&Th[ar];
        }
#pragma unroll
        for (int nt = 0; nt < 16; ++nt) {
            __syncthreads();   // previous tile's consumers done
            *(uint4*)&Bsh[strow * FF_LDB + stks] = pfh;
            *(uint4*)&Bsl[strow * FF_LDB + stks] = pfl;
            if (!(kh == 1 && nt == 15)) {
                const int nt2 = (nt + 1) & 15;
                const int kh2 = kh + (nt == 15);
                const size_t gi = (size_t)(nt2 * 16 + strow) * 256 + kh2 * 128 + stks;
                pfh = *(const uint4*)(w1th + gi);
                pfl = *(const uint4*)(w1tl + gi);
            }
            __syncthreads();   // tile ready
#pragma unroll
            for (int c4 = 0; c4 < 4; ++c4) {
                const int br = m16 * FF_LDB + c4 * 32 + quad * 8;
                const short8 bh = *(const short8*)&Bsh[br];
                const short8 bl = *(const short8*)&Bsl[br];
                acc1[nt] = __builtin_amdgcn_mfma_f32_16x16x32_bf16(a1h[c4], bh, acc1[nt], 0, 0, 0);
                acc1[nt] = __builtin_amdgcn_mfma_f32_16x16x32_bf16(a1h[c4], bl, acc1[nt], 0, 0, 0);
            }
        }
    }

    // ---- +b1, LayerNorm stats (in-register, shfl over m16 group) ----
    float sume[4] = {0.f, 0.f, 0.f, 0.f}, sumq[4] = {0.f, 0.f, 0.f, 0.f};
#pragma unroll
    for (int nt = 0; nt < 16; ++nt) {
        const float bb = b1[nt * 16 + m16];
#pragma unroll
        for (int e = 0; e < 4; ++e) {
            const float v = acc1[nt][e] + bb;
            acc1[nt][e] = v;
            sume[e] += v;
            sumq[e] += v * v;
        }
    }
#pragma unroll
    for (int e = 0; e < 4; ++e) {
#pragma unroll
        for (int off = 1; off < 16; off <<= 1) {
            sume[e] += __shfl_xor(sume[e], off, 64);
            sumq[e] += __shfl_xor(sumq[e], off, 64);
        }
    }
    float mu[4], rs[4];
#pragma unroll
    for (int e = 0; e < 4; ++e) {
        mu[e] = sume[e] * (1.f / 256.f);
        const float var = sumq[e] * (1.f / 256.f) - mu[e] * mu[e];
        rs[e] = rsqrtf(var + 1e-5f);
    }

    // preload GEMM2 tile (0,0) while LN finishes
    {
        const size_t gi = (size_t)strow * 256 + stks;
        pfh = *(const uint4*)(w2th + gi);
        pfl = *(const uint4*)(w2tl + gi);
    }

    // ---- LN + GELU, write H (bf16) back into Th ----
    __syncthreads();   // all waves done reading T / Bs
#pragma unroll
    for (int nt = 0; nt < 16; ++nt) {
        const int col = nt * 16 + m16;
        const float g  = lng[col];
        const float be = lnb[col];
#pragma unroll
        for (int e = 0; e < 4; ++e) {
            const float h  = (acc1[nt][e] - mu[e]) * rs[e] * g + be;
            const float hg = 0.5f * h * (1.f + erff(h * 0.7071067811865475f));
            const int li = (wave * 16 + quad * 4 + e) * FF_LDA + col;
            Th[li] = (unsigned short)f2bf(hg);
        }
    }
    __syncthreads();

    // ---- GEMM2: A[64x512] = Hg @ W2 (2-pass split, LDS-staged B, reg-dbuf) ----
    f32x4 acc2[32];
#pragma unroll
    for (int nt = 0; nt < 32; ++nt)
#pragma unroll
        for (int e = 0; e < 4; ++e) acc2[nt][e] = 0.f;

    for (int kh = 0; kh < 2; ++kh) {
        short8 a2h[4];
#pragma unroll
        for (int c4 = 0; c4 < 4; ++c4) {
            const int ar = rowA * FF_LDA + kh * 128 + c4 * 32 + quad * 8;
            a2h[c4] = *(const short8*)&Th[ar];
        }
#pragma unroll
        for (int nt = 0; nt < 32; ++nt) {
            __syncthreads();
            *(uint4*)&Bsh[strow * FF_LDB + stks] = pfh;
            *(uint4*)&Bsl[strow * FF_LDB + stks] = pfl;
            if (!(kh == 1 && nt == 31)) {
                const int nt2 = (nt + 1) & 31;
                const int kh2 = kh + (nt == 31);
                const size_t gi = (size_t)(nt2 * 16 + strow) * 256 + kh2 * 128 + stks;
                pfh = *(const uint4*)(w2th + gi);
                pfl = *(const uint4*)(w2tl + gi);
            }
            __syncthreads();
#pragma unroll
            for (int c4 = 0; c4 < 4; ++c4) {
                const int br = m16 * FF_LDB + c4 * 32 + quad * 8;
                const short8 bh = *(const short8*)&Bsh[br];
                const short8 bl = *(const short8*)&Bsl[br];
                acc2[nt] = __builtin_amdgcn_mfma_f32_16x16x32_bf16(a2h[c4], bh, acc2[nt], 0, 0, 0);
                acc2[nt] = __builtin_amdgcn_mfma_f32_16x16x32_bf16(a2h[c4], bl, acc2[nt], 0, 0, 0);
            }
        }
    }

    // ---- (a+b2)*ffs, L1-norm per (row, half), store hh[b][i][d][s] ----
    float sm[2][4] = {{0.f,0.f,0.f,0.f},{0.f,0.f,0.f,0.f}};
#pragma unroll
    for (int nt = 0; nt < 32; ++nt) {
        const int col = nt * 16 + m16;
        const float bb = b2[col];
        const float fs = ffs[col];
#pragma unroll
        for (int e = 0; e < 4; ++e) {
            const float v = (acc2[nt][e] + bb) * fs;
            acc2[nt][e] = v;
            sm[nt >> 4][e] += fabsf(v);
        }
    }
#pragma unroll
    for (int i = 0; i < 2; ++i)
#pragma unroll
        for (int e = 0; e < 4; ++e) {
#pragma unroll
            for (int off = 1; off < 16; off <<= 1)
                sm[i][e] += __shfl_xor(sm[i][e], off, 64);
        }
#pragma unroll
    for (int nt = 0; nt < 32; ++nt) {
        const int i = nt >> 4;
        const int d = (nt & 15) * 16 + m16;
        float4 o4;
        o4.x = acc2[nt][0] / (sm[i][0] + 1e-8f);
        o4.y = acc2[nt][1] / (sm[i][1] + 1e-8f);
        o4.z = acc2[nt][2] / (sm[i][2] + 1e-8f);
        o4.w = acc2[nt][3] / (sm[i][3] + 1e-8f);
        *(float4*)(hh + ((size_t)((b * 2 + i) * 256 + d)) * S_LEN + s0 + wave * 16 + quad * 4) = o4;
    }
}

// ---------------- FUSED double blocked-Toeplitz causal long conv ----------------
// u = z1 * (F1 conv (z0 * (F0 conv x))) per (b,d), v kept on-chip: conv1's reduced
// result is multiplied by z0, rounded to bf16, and written straight into xs with the
// same xsw layout conv2's staging would have produced (bit-identical to the old
// vb-roundtrip: f2bf(fp32) either way). F1 prefetched to regs at start (latency
// hides under conv1 compute). 2-wave r-split per conv (verified R7 structure).
#define XS_PAD   960
#define XS_ELEMS 5056
#define FRX_WORDS 4160
__device__ __forceinline__ int xsw(int blk) { return blk ^ ((blk >> 3) & 7); }

#define CONV_ACCUM_LOOP(ACC)                                                         \
    for (int i = 0; i < 32; ++i) {                                                   \
        const int r = 2 * i + wid;                                                   \
        const int ea_r = eA_base - 64 * r;                                           \
        short8 afr[4][2];                                                            \
        _Pragma("unroll")                                                            \
        for (int mt = 0; mt < 4; ++mt)                                               \
            _Pragma("unroll")                                                        \
            for (int kc = 0; kc < 2; ++kc) {                                         \
                const int e = ea_r - 16 * mt + 32 * kc;                              \
                union { unsigned int u[4]; short8 s; } cvt;                          \
                cvt.u[0] = frx[e];                                                   \
                cvt.u[1] = frx[e + 2];                                               \
                cvt.u[2] = frx[e + 4];                                               \
                cvt.u[3] = frx[e + 6];                                               \
                afr[mt][kc] = cvt.s;                                                 \
            }                                                                        \
        const int ptmin = r >> 4;                                                    \
        const int ob_r = oB_base - 64 * r;                                           \
        _Pragma("unroll")                                                            \
        for (int pt = 0; pt < 4; ++pt) {                                             \
            if (pt >= ptmin) {                                                       \
                const int o0 = ob_r + 1024 * pt;                                     \
                const short8 bfr0 = *(const short8*)(xs + xsw(o0 >> 3) * 8);         \
                const short8 bfr1 = *(const short8*)(xs + xsw((o0 + 32) >> 3) * 8);  \
                _Pragma("unroll")                                                    \
                for (int mt = 0; mt < 4; ++mt) {                                     \
                    ACC[mt][pt] = __builtin_amdgcn_mfma_f32_16x16x32_bf16(afr[mt][0], bfr0, ACC[mt][pt], 0, 0, 0); \
                    ACC[mt][pt] = __builtin_amdgcn_mfma_f32_16x16x32_bf16(afr[mt][1], bfr1, ACC[mt][pt], 0, 0, 0); \
                }                                                                    \
            }                                                                        \
        }                                                                            \
    }

__global__ __launch_bounds__(128) void k_conv2x(
    const float* __restrict__ cbuf, const float* __restrict__ hh,
    float* __restrict__ outb)
{
    const int d = blockIdx.x;
    const int b = blockIdx.y;
    const int tid  = threadIdx.x;
    const int lane = tid & 63;
    const int wid  = tid >> 6;
    const float* xp  = cbuf + ((size_t)(b * 768 + 512 + d)) * S_LEN;   // zs[2]
    const float* fp0 = hh   + ((size_t)((b * 2 + 0) * 256 + d)) * S_LEN;
    const float* fp1 = hh   + ((size_t)((b * 2 + 1) * 256 + d)) * S_LEN;
    const float* zp0 = cbuf + ((size_t)(b * 768 +   0 + d)) * S_LEN;   // zs[0]
    const float* zp1 = cbuf + ((size_t)(b * 768 + 256 + d)) * S_LEN;   // zs[1]
    float* op = outb + ((size_t)(b * 256 + d)) * S_LEN;

    __shared__ __align__(16) unsigned short xs[XS_ELEMS];
    __shared__ __align__(16) unsigned int   frx[FRX_WORDS];

    // prefetch F1 into regs (consumed after conv1; latency hides under conv1 compute)
    float4 f1pf[8];
#pragma unroll
    for (int it = 0; it < 8; ++it)
        f1pf[it] = *(const float4*)(fp1 + (it * 128 + tid) * 4);

    // stage xs <- x (bf16), frx <- F0
    {
        for (int blk = tid; blk < 120; blk += 128) {
            int4 z; z.x = 0; z.y = 0; z.z = 0; z.w = 0;
            *(int4*)(xs + xsw(blk) * 8) = z;
        }
#pragma unroll
        for (int it = 0; it < 4; ++it) {
            const int idx = it * 128 + tid;
            const int j = idx * 8;
            const float4 v0 = *(const float4*)(xp + j);
            const float4 v1 = *(const float4*)(xp + j + 4);
            int4 w;
            w.x = (int)(f2bf(v0.x) | (f2bf(v0.y) << 16));
            w.y = (int)(f2bf(v0.z) | (f2bf(v0.w) << 16));
            w.z = (int)(f2bf(v1.x) | (f2bf(v1.y) << 16));
            w.w = (int)(f2bf(v1.z) | (f2bf(v1.w) << 16));
            *(int4*)(xs + xsw(120 + idx) * 8) = w;
        }
    }
    {
        if (tid < 64) frx[4096 + tid] = 0u;
        if (tid == 0) frx[4095] = f2bf(fp0[0]);
#pragma unroll
        for (int it = 0; it < 8; ++it) {
            const int j = (it * 128 + tid) * 4;
            const float4 v = *(const float4*)(fp0 + j);
            const float f4 = (j + 4 < S_LEN) ? fp0[j + 4] : 0.f;
            frx[4094 - j] = f2bf(v.y) | (f2bf(v.x) << 16);
            frx[4093 - j] = f2bf(v.z) | (f2bf(v.y) << 16);
            frx[4092 - j] = f2bf(v.w) | (f2bf(v.z) << 16);
            if (j < 4092) frx[4091 - j] = f2bf(f4) | (f2bf(v.w) << 16);
        }
    }
    __syncthreads();

    const int m    = lane & 15;
    const int quad = lane >> 4;
    const int eA_base = 4095 - m + quad * 8;
    const int oB_base = XS_PAD + 64 * m + quad * 8;
    const float inv = 1.f / 8192.f;
    float* red = (float*)frx;   // 16 slots * 64 lanes * 16B = 16384B <= frx[0..4095]

    f32x4 acc[4][4];
#pragma unroll
    for (int mt = 0; mt < 4; ++mt)
#pragma unroll
        for (int pt = 0; pt < 4; ++pt)
#pragma unroll
            for (int e = 0; e < 4; ++e) acc[mt][pt][e] = 0.f;

    // ---- conv1 ----
    CONV_ACCUM_LOOP(acc)

    __syncthreads();
    if (wid == 1) {
#pragma unroll
        for (int mt = 0; mt < 4; ++mt)
#pragma unroll
            for (int pt = 0; pt < 4; ++pt)
                *(f32x4*)&red[((mt * 4 + pt) * 64 + lane) * 4] = acc[mt][pt];
    }
    __syncthreads();
    // wave0: v = z0 * (acc+partial) * inv, round to bf16, write into xs payload
    if (wid == 0) {
#pragma unroll
        for (int mt = 0; mt < 4; ++mt)
#pragma unroll
            for (int pt = 0; pt < 4; ++pt) {
                const f32x4 po = *(const f32x4*)&red[((mt * 4 + pt) * 64 + lane) * 4];
                const int p  = 16 * pt + m;
                const int sv = 64 * p + 16 * mt + quad * 4;
                const float4 z4 = *(const float4*)(zp0 + sv);
                const float v0 = z4.x * (acc[mt][pt][0] + po[0]) * inv;
                const float v1 = z4.y * (acc[mt][pt][1] + po[1]) * inv;
                const float v2 = z4.z * (acc[mt][pt][2] + po[2]) * inv;
                const float v3 = z4.w * (acc[mt][pt][3] + po[3]) * inv;
                uint2 hp;
                hp.x = f2bf(v0) | (f2bf(v1) << 16);
                hp.y = f2bf(v2) | (f2bf(v3) << 16);
                *(uint2*)(xs + xsw(120 + (sv >> 3)) * 8 + (sv & 7)) = hp;
            }
    }
    __syncthreads();   // wave0's red-reads + xs-writes done; frx free for rebuild

    // ---- rebuild frx <- F1 (from prefetch regs; f4 scalar from global, L2-warm) ----
    {
        if (tid < 64) frx[4096 + tid] = 0u;
        if (tid == 0) frx[4095] = f2bf(fp1[0]);
#pragma unroll
        for (int it = 0; it < 8; ++it) {
            const int j = (it * 128 + tid) * 4;
            const float4 v = f1pf[it];
            const float f4 = (j + 4 < S_LEN) ? fp1[j + 4] : 0.f;
            frx[4094 - j] = f2bf(v.y) | (f2bf(v.x) << 16);
            frx[4093 - j] = f2bf(v.z) | (f2bf(v.y) << 16);
            frx[4092 - j] = f2bf(v.w) | (f2bf(v.z) << 16);
            if (j < 4092) frx[4091 - j] = f2bf(f4) | (f2bf(v.w) << 16);
        }
    }
#pragma unroll
    for (int mt = 0; mt < 4; ++mt)
#pragma unroll
        for (int pt = 0; pt < 4; ++pt)
#pragma unroll
            for (int e = 0; e < 4; ++e) acc[mt][pt][e] = 0.f;
    __syncthreads();

    // ---- conv2 ----
    CONV_ACCUM_LOOP(acc)

    __syncthreads();
    if (wid == 1) {
#pragma unroll
        for (int mt = 0; mt < 4; ++mt)
#pragma unroll
            for (int pt = 0; pt < 4; ++pt)
                *(f32x4*)&red[((mt * 4 + pt) * 64 + lane) * 4] = acc[mt][pt];
    }
    __syncthreads();
    if (wid == 0) {
#pragma unroll
        for (int mt = 0; mt < 4; ++mt)
#pragma unroll
            for (int pt = 0; pt < 4; ++pt) {
                const f32x4 po = *(const f32x4*)&red[((mt * 4 + pt) * 64 + lane) * 4];
                const int p  = 16 * pt + m;
                const int sv = 64 * p + 16 * mt + quad * 4;
                const float4 z4 = *(const float4*)(zp1 + sv);
                float4 o4;
                o4.x = z4.x * (acc[mt][pt][0] + po[0]) * inv;
                o4.y = z4.y * (acc[mt][pt][1] + po[1]) * inv;
                o4.z = z4.z * (acc[mt][pt][2] + po[2]) * inv;
                o4.w = z4.w * (acc[mt][pt][3] + po[3]) * inv;
                *(float4*)(op + sv) = o4;
            }
    }
}

// ---------------- out[b][s][e] = mask * (sum_d v[b][d][s] * W_out[d][e] + b_out[e]) ----------------
__global__ __launch_bounds__(256) void k_out(
    const float* __restrict__ v, const float* __restrict__ Wo,
    const float* __restrict__ bo, const int* __restrict__ pos,
    float* __restrict__ out)
{
    const int b   = blockIdx.y;
    const int s0  = blockIdx.x * 32;
    const int tid = threadIdx.x;
    __shared__ float vs[256 * 36];
    {
        const float4* src = (const float4*)(v + ((size_t)(b*256 + tid)) * S_LEN + s0);
#pragma unroll
        for (int q = 0; q < 8; ++q) {
            *(float4*)&vs[tid*36 + q*4] = src[q];
        }
    }
    __syncthreads();
    float acc[32];
#pragma unroll
    for (int r = 0; r < 32; ++r) acc[r] = 0.f;
    for (int dd = 0; dd < 256; ++dd) {
        const float w = Wo[(size_t)dd * 256 + tid];
        const float* vr = &vs[dd * 36];
#pragma unroll
        for (int q = 0; q < 8; ++q) {
            const float4 x4 = *(const float4*)&vr[q*4];
            acc[q*4+0] += x4.x * w;
            acc[q*4+1] += x4.y * w;
            acc[q*4+2] += x4.z * w;
            acc[q*4+3] += x4.w * w;
        }
    }
    const float bb = bo[tid];
#pragma unroll
    for (int r = 0; r < 32; ++r) {
        const int s = s0 + r;
        const float m = (pos[(size_t)b * S_LEN + s] != -1) ? 1.f : 0.f;
        out[((size_t)b * S_LEN + s) * 256 + tid] = (acc[r] + bb) * m;
    }
}

extern "C" void kernel_launch(void* const* d_in, const int* in_sizes, int n_in,
                              void* d_out, int out_size, void* d_ws, size_t ws_size,
                              hipStream_t stream) {
    const float* emb = (const float*)d_in[0];
    const int*   pos = (const int*)  d_in[1];
    const float* Wp  = (const float*)d_in[2];
    const float* cw  = (const float*)d_in[3];
    const float* cb  = (const float*)d_in[4];
    const float* W1  = (const float*)d_in[5];
    const float* b1  = (const float*)d_in[6];
    const float* lg  = (const float*)d_in[7];
    const float* lb  = (const float*)d_in[8];
    const float* W2  = (const float*)d_in[9];
    const float* b2  = (const float*)d_in[10];
    const float* ffs = (const float*)d_in[11];
    const float* Wo  = (const float*)d_in[12];
    const float* bo  = (const float*)d_in[13];

    float* ws   = (float*)d_ws;
    float* minp = ws + OFF_MINP;
    float* wpt  = ws + OFF_WPT;
    unsigned short* wth = (unsigned short*)(ws + OFF_WTH);
    unsigned short* wtl = (unsigned short*)(ws + OFF_WTL);
    float* c    = ws + OFF_C;
    float* hh   = ws + OFF_HH;
    float* vb   = ws + OFF_V;
    float* ub   = ws + OFF_U;

    // FF weight splits carved from the head of vb (consumed by k_ff; V region otherwise unused)
    unsigned short* w1th = (unsigned short*)vb;
    unsigned short* w1tl = w1th + 256 * 256;
    unsigned short* w2th = w1tl + 256 * 256;
    unsigned short* w2tl = w2th + 512 * 256;

    k_minpos<<<dim3(8), dim3(256), 0, stream>>>(pos, minp);
    k_wpt<<<dim3(24, 8), dim3(256), 0, stream>>>(Wp, wpt);
    k_weff<<<dim3(768), dim3(256), 0, stream>>>(wpt, cw, wth, wtl);
    k_tsplit<<<dim3(8, 8), dim3(256), 0, stream>>>(W1, 256, 256, w1th, w1tl);
    k_tsplit<<<dim3(16, 8), dim3(256), 0, stream>>>(W2, 256, 512, w2th, w2tl);
    k_convgemm<<<dim3(32, 6, 8), dim3(256), 0, stream>>>(emb, pos, wth, wtl, cb, c);
    k_ff<<<dim3(64, 8), dim3(256), 0, stream>>>(emb, pos, minp, w1th, w1tl, b1, lg, lb, w2th, w2tl, b2, ffs, hh);
    // u = z1 * (F1 conv (z0 * (F0 conv zs[2])))  — fused, v stays on-chip
    k_conv2x<<<dim3(256, 8), dim3(128), 0, stream>>>(c, hh, ub);
    k_out<<<dim3(128, 8), dim3(256), 0, stream>>>(ub, Wo, bo, pos, (float*)d_out);
}

// Round 10
// 466.730 us; speedup vs baseline: 1.3832x; 1.0369x over previous
//
#include <hip/hip_runtime.h>
#include <cstdint>

#define S_LEN 4096
#define D_DIM 256

// workspace layout (float offsets)
#define OFF_MINP 0
#define OFF_WPT  16
#define OFF_WTH  (OFF_WPT + 768*256)     // WeffT hi, 768x768 ushort = 294912 floats
#define OFF_WTL  (OFF_WTH + 294912)      // WeffT lo
#define OFF_C    (OFF_WTL + 294912)      // == old OFF_C, downstream unchanged
#define OFF_HH   (OFF_C + 8*768*4096)
#define OFF_V    (OFF_HH + 8*2*256*4096)
#define OFF_U    (OFF_V + 8*256*4096)

// Weight splits live at the head of the V region (consumed by k_ff / k_out; the V
// region is otherwise unused now that conv1+conv2 are fused and v never hits HBM).

typedef __attribute__((ext_vector_type(8))) short short8;
typedef __attribute__((ext_vector_type(4))) float f32x4;

__device__ __forceinline__ unsigned int f2bf(float x) {
    union { float f; unsigned int u; } v; v.f = x;
    unsigned int r = v.u + 0x7fffu + ((v.u >> 16) & 1u);   // RNE
    return r >> 16;
}
__device__ __forceinline__ float bf2f(unsigned int h) {
    union { unsigned int u; float f; } v; v.u = h << 16; return v.f;
}

// ---------------- min valid position per batch ----------------
__global__ __launch_bounds__(256) void k_minpos(const int* __restrict__ pos, float* __restrict__ minp)
{
    const int b = blockIdx.x;
    const int tid = threadIdx.x;
    int mn = 0x7fffffff;
    const int* p = pos + (size_t)b * S_LEN;
    for (int s = tid; s < S_LEN; s += 256) {
        const int v = p[s];
        if (v != -1) mn = min(mn, v);
    }
    __shared__ int red[256];
    red[tid] = mn;
    __syncthreads();
    for (int st = 128; st > 0; st >>= 1) {
        if (tid < st) red[tid] = min(red[tid], red[tid + st]);
        __syncthreads();
    }
    if (tid == 0) minp[b] = (float)red[0];
}

// ---------------- transpose W_proj (256x768) -> WpT (768x256) ----------------
__global__ __launch_bounds__(256) void k_wpt(const float* __restrict__ Wp, float* __restrict__ WpT)
{
    __shared__ float t[32][33];
    const int e0 = blockIdx.x * 32;   // 0..767
    const int d0 = blockIdx.y * 32;   // 0..255
    const int lx = threadIdx.x & 31, ly = threadIdx.x >> 5; // 32x8
#pragma unroll
    for (int q = 0; q < 4; ++q)
        t[ly + 8*q][lx] = Wp[(size_t)(d0 + ly + 8*q) * 768 + e0 + lx];
    __syncthreads();
#pragma unroll
    for (int q = 0; q < 4; ++q)
        WpT[(size_t)(e0 + ly + 8*q) * 256 + d0 + lx] = t[lx][ly + 8*q];
}

// ---------------- generic transpose + bf16 hi/lo split: W[K][N] -> out[N][K] ----------------
__global__ __launch_bounds__(256) void k_tsplit(const float* __restrict__ W, const int K, const int N,
                                                unsigned short* __restrict__ oh, unsigned short* __restrict__ ol)
{
    __shared__ float t[32][33];
    const int n0 = blockIdx.x * 32;
    const int k0 = blockIdx.y * 32;
    const int lx = threadIdx.x & 31, ly = threadIdx.x >> 5;
#pragma unroll
    for (int q = 0; q < 4; ++q)
        t[ly + 8*q][lx] = W[(size_t)(k0 + ly + 8*q) * N + n0 + lx];
    __syncthreads();
#pragma unroll
    for (int q = 0; q < 4; ++q) {
        const float v = t[lx][ly + 8*q];
        const unsigned int h = f2bf(v);
        oh[(size_t)(n0 + ly + 8*q) * K + k0 + lx] = (unsigned short)h;
        ol[(size_t)(n0 + ly + 8*q) * K + k0 + lx] = (unsigned short)f2bf(v - bf2f(h));
    }
}

// ---------------- WeffT[o][t*256+d] = sum_i WpT[g*256+i][d] * conv_w[o][i][t], split hi/lo bf16 ----------------
__global__ __launch_bounds__(256) void k_weff(const float* __restrict__ WpT, const float* __restrict__ cw,
                                              unsigned short* __restrict__ wth, unsigned short* __restrict__ wtl)
{
    const int o = blockIdx.x;       // 768
    const int d = threadIdx.x;      // 256
    const int g = o >> 8;
    __shared__ float cwrow[768];
    for (int i = threadIdx.x; i < 768; i += 256) cwrow[i] = cw[(size_t)o * 768 + i];
    __syncthreads();
    float a0 = 0.f, a1 = 0.f, a2 = 0.f;
    const float* wb = WpT + (size_t)(g * 256) * 256 + d;
#pragma unroll 4
    for (int i = 0; i < 256; ++i) {
        const float wv = wb[(size_t)i * 256];
        a0 += wv * cwrow[i*3+0];
        a1 += wv * cwrow[i*3+1];
        a2 += wv * cwrow[i*3+2];
    }
    const float av[3] = {a0, a1, a2};
#pragma unroll
    for (int t = 0; t < 3; ++t) {
        const unsigned int hb = f2bf(av[t]);
        const unsigned int lb = f2bf(av[t] - bf2f(hb));
        wth[(size_t)o * 768 + t * 256 + d] = (unsigned short)hb;
        wtl[(size_t)o * 768 + t * 256 + d] = (unsigned short)lb;
    }
}

// ---------------- MFMA conv-GEMM (verified: 128s x 128o, mt=2, 2-pass, reg-prefetch) ----------------
#define CG_LDA 40   // 32 + 8 pad (16B frag alignment preserved: 80B rows)
__global__ __launch_bounds__(256, 3) void k_convgemm(
    const float* __restrict__ emb, const int* __restrict__ pos,
    const unsigned short* __restrict__ wth, const unsigned short* __restrict__ wtl,
    const float* __restrict__ convb, float* __restrict__ c)
{
    const int b  = blockIdx.z;
    const int o0 = blockIdx.y * 128;
    const int s0 = blockIdx.x * 128;
    const int tid  = threadIdx.x;
    const int wave = tid >> 6, lane = tid & 63;
    const int m16  = lane & 15, quad = lane >> 4;

    __shared__ __align__(16) unsigned short As[130 * CG_LDA];
    __shared__ __align__(16) unsigned short Bh[128 * CG_LDA];
    __shared__ __align__(16) unsigned short Bl[128 * CG_LDA];

    const int rA = tid >> 1;
    const int cA = (tid & 1) * 16;
    const int srowA = s0 + rA - 1;
    const bool vA = (srowA >= 0 && srowA < S_LEN);
    const float* embA = emb + ((size_t)b * S_LEN + (vA ? srowA : 0)) * D_DIM + cA;
    const int rT = 128 + (tid >> 3);
    const int cT = (tid & 7) * 4;
    const int srowT = s0 + rT - 1;
    const bool vT = (tid < 16) && (srowT >= 0 && srowT < S_LEN);
    const float* embT = emb + ((size_t)b * S_LEN + ((tid < 16 && vT) ? srowT : 0)) * D_DIM + cT;

    const int rB0 = tid >> 2,        gB0 = (tid & 3) * 8;
    const int rB1 = 64 + (tid >> 2), gB1 = gB0;

    float4 apf[4]; float4 apfT;
    uint4 bph0, bpl0, bph1, bpl1;

#pragma unroll
    for (int q = 0; q < 4; ++q) apf[q] = vA ? *(const float4*)(embA + q * 4) : make_float4(0.f,0.f,0.f,0.f);
    apfT = vT ? *(const float4*)(embT) : make_float4(0.f,0.f,0.f,0.f);
    {
        const size_t gi0 = (size_t)(o0 + rB0) * 768 + gB0;
        const size_t gi1 = (size_t)(o0 + rB1) * 768 + gB1;
        bph0 = *(const uint4*)(wth + gi0); bpl0 = *(const uint4*)(wtl + gi0);
        bph1 = *(const uint4*)(wth + gi1); bpl1 = *(const uint4*)(wtl + gi1);
    }

    f32x4 acc[2][8];
#pragma unroll
    for (int mt = 0; mt < 2; ++mt)
#pragma unroll
        for (int nt = 0; nt < 8; ++nt)
#pragma unroll
            for (int e = 0; e < 4; ++e) acc[mt][nt][e] = 0.f;

    for (int c8 = 0; c8 < 8; ++c8) {
        for (int t = 0; t < 3; ++t) {
            __syncthreads();
            if (t == 0) {
#pragma unroll
                for (int q = 0; q < 4; ++q) {
                    const float4 v = apf[q];
                    uint2 hp;
                    hp.x = f2bf(v.x) | (f2bf(v.y) << 16);
                    hp.y = f2bf(v.z) | (f2bf(v.w) << 16);
                    *(uint2*)&As[rA * CG_LDA + cA + q * 4] = hp;
                }
                if (tid < 16) {
                    const float4 v = apfT;
                    uint2 hp;
                    hp.x = f2bf(v.x) | (f2bf(v.y) << 16);
                    hp.y = f2bf(v.z) | (f2bf(v.w) << 16);
                    *(uint2*)&As[rT * CG_LDA + cT] = hp;
                }
                if (c8 < 7) {
                    const int base = (c8 + 1) * 32;
#pragma unroll
                    for (int q = 0; q < 4; ++q) apf[q] = vA ? *(const float4*)(embA + base + q * 4) : make_float4(0.f,0.f,0.f,0.f);
                    apfT = vT ? *(const float4*)(embT + base) : make_float4(0.f,0.f,0.f,0.f);
                }
            }
            *(uint4*)&Bh[rB0 * CG_LDA + gB0] = bph0;
            *(uint4*)&Bl[rB0 * CG_LDA + gB0] = bpl0;
            *(uint4*)&Bh[rB1 * CG_LDA + gB1] = bph1;
            *(uint4*)&Bl[rB1 * CG_LDA + gB1] = bpl1;
            if (!(c8 == 7 && t == 2)) {
                const int t2  = (t == 2) ? 0 : (t + 1);
                const int c82 = c8 + (t == 2);
                const int kbase = t2 * 256 + c82 * 32;
                const size_t gi0 = (size_t)(o0 + rB0) * 768 + kbase + gB0;
                const size_t gi1 = (size_t)(o0 + rB1) * 768 + kbase + gB1;
                bph0 = *(const uint4*)(wth + gi0); bpl0 = *(const uint4*)(wtl + gi0);
                bph1 = *(const uint4*)(wth + gi1); bpl1 = *(const uint4*)(wtl + gi1);
            }
            __syncthreads();
            short8 ah[2];
#pragma unroll
            for (int mt = 0; mt < 2; ++mt) {
                const int ar = (wave * 32 + mt * 16 + m16 + t) * CG_LDA + quad * 8;
                ah[mt] = *(const short8*)&As[ar];
            }
#pragma unroll
            for (int nt = 0; nt < 8; ++nt) {
                const int br = (nt * 16 + m16) * CG_LDA + quad * 8;
                const short8 bh = *(const short8*)&Bh[br];
                const short8 bl = *(const short8*)&Bl[br];
#pragma unroll
                for (int mt = 0; mt < 2; ++mt) {
                    acc[mt][nt] = __builtin_amdgcn_mfma_f32_16x16x32_bf16(ah[mt], bh, acc[mt][nt], 0, 0, 0);
                    acc[mt][nt] = __builtin_amdgcn_mfma_f32_16x16x32_bf16(ah[mt], bl, acc[mt][nt], 0, 0, 0);
                }
            }
        }
    }
    __syncthreads();

    float msk[2][4];
#pragma unroll
    for (int mt = 0; mt < 2; ++mt) {
        const int s = s0 + wave * 32 + mt * 16 + quad * 4;
        const int4 p4 = *(const int4*)(pos + (size_t)b * S_LEN + s);
        msk[mt][0] = (p4.x != -1) ? 1.f : 0.f;
        msk[mt][1] = (p4.y != -1) ? 1.f : 0.f;
        msk[mt][2] = (p4.z != -1) ? 1.f : 0.f;
        msk[mt][3] = (p4.w != -1) ? 1.f : 0.f;
    }
#pragma unroll
    for (int nt = 0; nt < 8; ++nt) {
        const int o = o0 + nt * 16 + m16;
        const float cb = convb[o];
#pragma unroll
        for (int mt = 0; mt < 2; ++mt) {
            const int s = s0 + wave * 32 + mt * 16 + quad * 4;
            float4 r;
            r.x = (acc[mt][nt][0] + cb) * msk[mt][0];
            r.y = (acc[mt][nt][1] + cb) * msk[mt][1];
            r.z = (acc[mt][nt][2] + cb) * msk[mt][2];
            r.w = (acc[mt][nt][3] + cb) * msk[mt][3];
            *(float4*)(c + ((size_t)(b * 768 + o)) * S_LEN + s) = r;
        }
    }
}

// ---------------- RoPE + FF (MFMA, LDS-staged B, 2-pass split: T/H plain bf16, W hi/lo) ----------------
#define FF_LDA 264   // 256 + 8 ushort pad
#define FF_LDB 136   // 128 + 8 pad
__global__ __launch_bounds__(256, 2) void k_ff(
    const float* __restrict__ emb, const int* __restrict__ pos, const float* __restrict__ minp,
    const unsigned short* __restrict__ w1th, const unsigned short* __restrict__ w1tl,
    const float* __restrict__ b1,
    const float* __restrict__ lng, const float* __restrict__ lnb,
    const unsigned short* __restrict__ w2th, const unsigned short* __restrict__ w2tl,
    const float* __restrict__ b2, const float* __restrict__ ffs, float* __restrict__ hh)
{
    const int b   = blockIdx.y;
    const int s0  = blockIdx.x * 64;
    const int tid = threadIdx.x;
    const int wave = tid >> 6, lane = tid & 63;
    const int m16  = lane & 15, quad = lane >> 4;

    __shared__ __align__(16) unsigned short Th[64 * FF_LDA];
    __shared__ __align__(16) unsigned short Bsh[16 * FF_LDB];
    __shared__ __align__(16) unsigned short Bsl[16 * FF_LDB];
    __shared__ float th_s[128];

    if (tid < 128) th_s[tid] = expf(-(float)tid * 0.07195578415606394f);
    __syncthreads();

    {
        const int r    = tid >> 2;            // 0..63
        const int col0 = (tid & 3) * 64;
        const int s    = s0 + r;
        const int p    = pos[(size_t)b * S_LEN + s];
        const float adj = (p == -1) ? -1.f : ((float)p - minp[b]);
        const float* ep = emb + ((size_t)b * S_LEN + s) * D_DIM;
#pragma unroll
        for (int p8 = 0; p8 < 8; ++p8) {
            const int cbase = col0 + p8 * 8;
            const float4 va = *(const float4*)(ep + cbase);
            const float4 vb4 = *(const float4*)(ep + cbase + 4);
            const float x[8] = {va.x, va.y, va.z, va.w, vb4.x, vb4.y, vb4.z, vb4.w};
            unsigned int uh[4];
#pragma unroll
            for (int jj = 0; jj < 4; ++jj) {
                const int j = (cbase >> 1) + jj;
                const float theta = th_s[j];
                float sn, cs;
                sincosf(adj * theta, &sn, &cs);
                const float x1 = x[2*jj], x2 = x[2*jj+1];
                const float r1 = x1 * cs - x2 * sn;
                const float r2 = x1 * sn + x2 * cs;
                uh[jj] = f2bf(r1) | (f2bf(r2) << 16);
            }
            uint4 wh;
            wh.x = uh[0]; wh.y = uh[1]; wh.z = uh[2]; wh.w = uh[3];
            *(uint4*)&Th[r * FF_LDA + cbase] = wh;
        }
    }
    __syncthreads();

    const int rowA  = wave * 16 + m16;
    const int strow = tid >> 4;
    const int stks  = (tid & 15) * 8;

    f32x4 acc1[16];
#pragma unroll
    for (int nt = 0; nt < 16; ++nt)
#pragma unroll
        for (int e = 0; e < 4; ++e) acc1[nt][e] = 0.f;

    uint4 pfh, pfl;
    {
        const size_t gi = (size_t)strow * 256 + stks;
        pfh = *(const uint4*)(w1th + gi);
        pfl = *(const uint4*)(w1tl + gi);
    }
    for (int kh = 0; kh < 2; ++kh) {
        short8 a1h[4];
#pragma unroll
        for (int c4 = 0; c4 < 4; ++c4) {
            const int ar = rowA * FF_LDA + kh * 128 + c4 * 32 + quad * 8;
            a1h[c4] = *(const short8*)&Th[ar];
        }
#pragma unroll
        for (int nt = 0; nt < 16; ++nt) {
            __syncthreads();
            *(uint4*)&Bsh[strow * FF_LDB + stks] = pfh;
            *(uint4*)&Bsl[strow * FF_LDB + stks] = pfl;
            if (!(kh == 1 && nt == 15)) {
                const int nt2 = (nt + 1) & 15;
                const int kh2 = kh + (nt == 15);
                const size_t gi = (size_t)(nt2 * 16 + strow) * 256 + kh2 * 128 + stks;
                pfh = *(const uint4*)(w1th + gi);
                pfl = *(const uint4*)(w1tl + gi);
            }
            __syncthreads();
#pragma unroll
            for (int c4 = 0; c4 < 4; ++c4) {
                const int br = m16 * FF_LDB + c4 * 32 + quad * 8;
                const short8 bh = *(const short8*)&Bsh[br];
                const short8 bl = *(const short8*)&Bsl[br];
                acc1[nt] = __builtin_amdgcn_mfma_f32_16x16x32_bf16(a1h[c4], bh, acc1[nt], 0, 0, 0);
                acc1[nt] = __builtin_amdgcn_mfma_f32_16x16x32_bf16(a1h[c4], bl, acc1[nt], 0, 0, 0);
            }
        }
    }

    float sume[4] = {0.f, 0.f, 0.f, 0.f}, sumq[4] = {0.f, 0.f, 0.f, 0.f};
#pragma unroll
    for (int nt = 0; nt < 16; ++nt) {
        const float bb = b1[nt * 16 + m16];
#pragma unroll
        for (int e = 0; e < 4; ++e) {
            const float v = acc1[nt][e] + bb;
            acc1[nt][e] = v;
            sume[e] += v;
            sumq[e] += v * v;
        }
    }
#pragma unroll
    for (int e = 0; e < 4; ++e) {
#pragma unroll
        for (int off = 1; off < 16; off <<= 1) {
            sume[e] += __shfl_xor(sume[e], off, 64);
            sumq[e] += __shfl_xor(sumq[e], off, 64);
        }
    }
    float mu[4], rs[4];
#pragma unroll
    for (int e = 0; e < 4; ++e) {
        mu[e] = sume[e] * (1.f / 256.f);
        const float var = sumq[e] * (1.f / 256.f) - mu[e] * mu[e];
        rs[e] = rsqrtf(var + 1e-5f);
    }

    {
        const size_t gi = (size_t)strow * 256 + stks;
        pfh = *(const uint4*)(w2th + gi);
        pfl = *(const uint4*)(w2tl + gi);
    }

    __syncthreads();
#pragma unroll
    for (int nt = 0; nt < 16; ++nt) {
        const int col = nt * 16 + m16;
        const float g  = lng[col];
        const float be = lnb[col];
#pragma unroll
        for (int e = 0; e < 4; ++e) {
            const float h  = (acc1[nt][e] - mu[e]) * rs[e] * g + be;
            const float hg = 0.5f * h * (1.f + erff(h * 0.7071067811865475f));
            const int li = (wave * 16 + quad * 4 + e) * FF_LDA + col;
            Th[li] = (unsigned short)f2bf(hg);
        }
    }
    __syncthreads();

    f32x4 acc2[32];
#pragma unroll
    for (int nt = 0; nt < 32; ++nt)
#pragma unroll
        for (int e = 0; e < 4; ++e) acc2[nt][e] = 0.f;

    for (int kh = 0; kh < 2; ++kh) {
        short8 a2h[4];
#pragma unroll
        for (int c4 = 0; c4 < 4; ++c4) {
            const int ar = rowA * FF_LDA + kh * 128 + c4 * 32 + quad * 8;
            a2h[c4] = *(const short8*)&Th[ar];
        }
#pragma unroll
        for (int nt = 0; nt < 32; ++nt) {
            __syncthreads();
            *(uint4*)&Bsh[strow * FF_LDB + stks] = pfh;
            *(uint4*)&Bsl[strow * FF_LDB + stks] = pfl;
            if (!(kh == 1 && nt == 31)) {
                const int nt2 = (nt + 1) & 31;
                const int kh2 = kh + (nt == 31);
                const size_t gi = (size_t)(nt2 * 16 + strow) * 256 + kh2 * 128 + stks;
                pfh = *(const uint4*)(w2th + gi);
                pfl = *(const uint4*)(w2tl + gi);
            }
            __syncthreads();
#pragma unroll
            for (int c4 = 0; c4 < 4; ++c4) {
                const int br = m16 * FF_LDB + c4 * 32 + quad * 8;
                const short8 bh = *(const short8*)&Bsh[br];
                const short8 bl = *(const short8*)&Bsl[br];
                acc2[nt] = __builtin_amdgcn_mfma_f32_16x16x32_bf16(a2h[c4], bh, acc2[nt], 0, 0, 0);
                acc2[nt] = __builtin_amdgcn_mfma_f32_16x16x32_bf16(a2h[c4], bl, acc2[nt], 0, 0, 0);
            }
        }
    }

    float sm[2][4] = {{0.f,0.f,0.f,0.f},{0.f,0.f,0.f,0.f}};
#pragma unroll
    for (int nt = 0; nt < 32; ++nt) {
        const int col = nt * 16 + m16;
        const float bb = b2[col];
        const float fs = ffs[col];
#pragma unroll
        for (int e = 0; e < 4; ++e) {
            const float v = (acc2[nt][e] + bb) * fs;
            acc2[nt][e] = v;
            sm[nt >> 4][e] += fabsf(v);
        }
    }
#pragma unroll
    for (int i = 0; i < 2; ++i)
#pragma unroll
        for (int e = 0; e < 4; ++e) {
#pragma unroll
            for (int off = 1; off < 16; off <<= 1)
                sm[i][e] += __shfl_xor(sm[i][e], off, 64);
        }
#pragma unroll
    for (int nt = 0; nt < 32; ++nt) {
        const int i = nt >> 4;
        const int d = (nt & 15) * 16 + m16;
        float4 o4;
        o4.x = acc2[nt][0] / (sm[i][0] + 1e-8f);
        o4.y = acc2[nt][1] / (sm[i][1] + 1e-8f);
        o4.z = acc2[nt][2] / (sm[i][2] + 1e-8f);
        o4.w = acc2[nt][3] / (sm[i][3] + 1e-8f);
        *(float4*)(hh + ((size_t)((b * 2 + i) * 256 + d)) * S_LEN + s0 + wave * 16 + quad * 4) = o4;
    }
}

// ---------------- FUSED double blocked-Toeplitz causal long conv ----------------
// Pair-dup filter layout: frxd[k] = {frx[k], frx[k-2]} (uint2, 8B-aligned). Each MFMA
// A-fragment = 2x ds_read_b64 (frxd[e+2], frxd[e+6]) instead of 4x stride-2 b32.
// Values are the identical f2bf words -> bit-identical conv results.
#define XS_PAD   960
#define XS_ELEMS 5056
#define FRX_WORDS 4160
__device__ __forceinline__ int xsw(int blk) { return blk ^ ((blk >> 3) & 7); }

#define CONV_ACCUM_LOOP(ACC)                                                         \
    for (int i = 0; i < 32; ++i) {                                                   \
        const int r = 2 * i + wid;                                                   \
        const int ea_r = eA_base - 64 * r;                                           \
        short8 afr[4][2];                                                            \
        _Pragma("unroll")                                                            \
        for (int mt = 0; mt < 4; ++mt)                                               \
            _Pragma("unroll")                                                        \
            for (int kc = 0; kc < 2; ++kc) {                                         \
                const int e = ea_r - 16 * mt + 32 * kc;                              \
                const uint2 d0 = frxd[e + 2];                                        \
                const uint2 d1 = frxd[e + 6];                                        \
                union { unsigned int u[4]; short8 s; } cvt;                          \
                cvt.u[0] = d0.y;                                                     \
                cvt.u[1] = d0.x;                                                     \
                cvt.u[2] = d1.y;                                                     \
                cvt.u[3] = d1.x;                                                     \
                afr[mt][kc] = cvt.s;                                                 \
            }                                                                        \
        const int ptmin = r >> 4;                                                    \
        const int ob_r = oB_base - 64 * r;                                           \
        _Pragma("unroll")                                                            \
        for (int pt = 0; pt < 4; ++pt) {                                             \
            if (pt >= ptmin) {                                                       \
                const int o0 = ob_r + 1024 * pt;                                     \
                const short8 bfr0 = *(const short8*)(xs + xsw(o0 >> 3) * 8);         \
                const short8 bfr1 = *(const short8*)(xs + xsw((o0 + 32) >> 3) * 8);  \
                _Pragma("unroll")                                                    \
                for (int mt = 0; mt < 4; ++mt) {                                     \
                    ACC[mt][pt] = __builtin_amdgcn_mfma_f32_16x16x32_bf16(afr[mt][0], bfr0, ACC[mt][pt], 0, 0, 0); \
                    ACC[mt][pt] = __builtin_amdgcn_mfma_f32_16x16x32_bf16(afr[mt][1], bfr1, ACC[mt][pt], 0, 0, 0); \
                }                                                                    \
            }                                                                        \
        }                                                                            \
    }

// build frxd from filter pointer fp (v supplied per-it by caller expression)
#define BUILD_FRXD(FPTR, VEXPR)                                                      \
    {                                                                                \
        _Pragma("unroll")                                                            \
        for (int it = 0; it < 8; ++it) {                                             \
            const int j = (it * 128 + tid) * 4;                                      \
            const float4 v = (VEXPR);                                                \
            const float4 g4 = (j + 4 < S_LEN) ? *(const float4*)((FPTR) + j + 4)     \
                                              : make_float4(0.f,0.f,0.f,0.f);       \
            const unsigned int w0 = f2bf(v.y)  | (f2bf(v.x)  << 16);                 \
            const unsigned int w1 = f2bf(v.z)  | (f2bf(v.y)  << 16);                 \
            const unsigned int w2 = f2bf(v.w)  | (f2bf(v.z)  << 16);                 \
            const unsigned int w3 = f2bf(g4.x) | (f2bf(v.w)  << 16);                 \
            const unsigned int w4 = f2bf(g4.y) | (f2bf(g4.x) << 16);                 \
            const unsigned int w5 = f2bf(g4.z) | (f2bf(g4.y) << 16);                 \
            frxd[4094 - j] = make_uint2(w0, w2);                                     \
            frxd[4093 - j] = make_uint2(w1, w3);                                     \
            frxd[4092 - j] = make_uint2(w2, w4);                                     \
            if (j < 4092) frxd[4091 - j] = make_uint2(w3, w5);                       \
        }                                                                            \
        if (tid == 0) {                                                              \
            const float4 v0 = *(const float4*)(FPTR);                                \
            const unsigned int a95 = f2bf(v0.x);                                     \
            const unsigned int w94 = f2bf(v0.y) | (f2bf(v0.x) << 16);                \
            const unsigned int w93 = f2bf(v0.z) | (f2bf(v0.y) << 16);                \
            frxd[4095] = make_uint2(a95, w93);                                       \
            frxd[4096] = make_uint2(0u, w94);                                        \
            frxd[4097] = make_uint2(0u, a95);                                        \
        }                                                                            \
        if (tid >= 2 && tid < 64) frxd[4096 + tid] = make_uint2(0u, 0u);             \
    }

__global__ __launch_bounds__(128) void k_conv2x(
    const float* __restrict__ cbuf, const float* __restrict__ hh,
    float* __restrict__ outb)
{
    const int d = blockIdx.x;
    const int b = blockIdx.y;
    const int tid  = threadIdx.x;
    const int lane = tid & 63;
    const int wid  = tid >> 6;
    const float* xp  = cbuf + ((size_t)(b * 768 + 512 + d)) * S_LEN;   // zs[2]
    const float* fp0 = hh   + ((size_t)((b * 2 + 0) * 256 + d)) * S_LEN;
    const float* fp1 = hh   + ((size_t)((b * 2 + 1) * 256 + d)) * S_LEN;
    const float* zp0 = cbuf + ((size_t)(b * 768 +   0 + d)) * S_LEN;   // zs[0]
    const float* zp1 = cbuf + ((size_t)(b * 768 + 256 + d)) * S_LEN;   // zs[1]
    float* op = outb + ((size_t)(b * 256 + d)) * S_LEN;

    __shared__ __align__(16) unsigned short xs[XS_ELEMS];
    __shared__ __align__(16) uint2 frxd[FRX_WORDS];

    // prefetch F1 into regs (consumed after conv1; latency hides under conv1 compute)
    float4 f1pf[8];
#pragma unroll
    for (int it = 0; it < 8; ++it)
        f1pf[it] = *(const float4*)(fp1 + (it * 128 + tid) * 4);

    // stage xs <- x (bf16)
    {
        for (int blk = tid; blk < 120; blk += 128) {
            int4 z; z.x = 0; z.y = 0; z.z = 0; z.w = 0;
            *(int4*)(xs + xsw(blk) * 8) = z;
        }
#pragma unroll
        for (int it = 0; it < 4; ++it) {
            const int idx = it * 128 + tid;
            const int j = idx * 8;
            const float4 v0 = *(const float4*)(xp + j);
            const float4 v1 = *(const float4*)(xp + j + 4);
            int4 w;
            w.x = (int)(f2bf(v0.x) | (f2bf(v0.y) << 16));
            w.y = (int)(f2bf(v0.z) | (f2bf(v0.w) << 16));
            w.z = (int)(f2bf(v1.x) | (f2bf(v1.y) << 16));
            w.w = (int)(f2bf(v1.z) | (f2bf(v1.w) << 16));
            *(int4*)(xs + xsw(120 + idx) * 8) = w;
        }
    }
    // frxd <- F0
    BUILD_FRXD(fp0, *(const float4*)(fp0 + j))
    __syncthreads();

    const int m    = lane & 15;
    const int quad = lane >> 4;
    const int eA_base = 4095 - m + quad * 8;
    const int oB_base = XS_PAD + 64 * m + quad * 8;
    const float inv = 1.f / 8192.f;
    float* red = (float*)frxd;   // 16 slots * 64 lanes * 16B = 16384B <= 33280B

    f32x4 acc[4][4];
#pragma unroll
    for (int mt = 0; mt < 4; ++mt)
#pragma unroll
        for (int pt = 0; pt < 4; ++pt)
#pragma unroll
            for (int e = 0; e < 4; ++e) acc[mt][pt][e] = 0.f;

    // ---- conv1 ----
    CONV_ACCUM_LOOP(acc)

    __syncthreads();
    if (wid == 1) {
#pragma unroll
        for (int mt = 0; mt < 4; ++mt)
#pragma unroll
            for (int pt = 0; pt < 4; ++pt)
                *(f32x4*)&red[((mt * 4 + pt) * 64 + lane) * 4] = acc[mt][pt];
    }
    __syncthreads();
    // wave0: v = z0 * (acc+partial) * inv, round to bf16, write into xs payload
    if (wid == 0) {
#pragma unroll
        for (int mt = 0; mt < 4; ++mt)
#pragma unroll
            for (int pt = 0; pt < 4; ++pt) {
                const f32x4 po = *(const f32x4*)&red[((mt * 4 + pt) * 64 + lane) * 4];
                const int p  = 16 * pt + m;
                const int sv = 64 * p + 16 * mt + quad * 4;
                const float4 z4 = *(const float4*)(zp0 + sv);
                const float v0 = z4.x * (acc[mt][pt][0] + po[0]) * inv;
                const float v1 = z4.y * (acc[mt][pt][1] + po[1]) * inv;
                const float v2 = z4.z * (acc[mt][pt][2] + po[2]) * inv;
                const float v3 = z4.w * (acc[mt][pt][3] + po[3]) * inv;
                uint2 hp;
                hp.x = f2bf(v0) | (f2bf(v1) << 16);
                hp.y = f2bf(v2) | (f2bf(v3) << 16);
                *(uint2*)(xs + xsw(120 + (sv >> 3)) * 8 + (sv & 7)) = hp;
            }
    }
    __syncthreads();   // wave0's red-reads + xs-writes done; frxd free for rebuild

    // ---- rebuild frxd <- F1 (v from prefetch regs) ----
    BUILD_FRXD(fp1, f1pf[it])
#pragma unroll
    for (int mt = 0; mt < 4; ++mt)
#pragma unroll
        for (int pt = 0; pt < 4; ++pt)
#pragma unroll
            for (int e = 0; e < 4; ++e) acc[mt][pt][e] = 0.f;
    __syncthreads();

    // ---- conv2 ----
    CONV_ACCUM_LOOP(acc)

    __syncthreads();
    if (wid == 1) {
#pragma unroll
        for (int mt = 0; mt < 4; ++mt)
#pragma unroll
            for (int pt = 0; pt < 4; ++pt)
                *(f32x4*)&red[((mt * 4 + pt) * 64 + lane) * 4] = acc[mt][pt];
    }
    __syncthreads();
    if (wid == 0) {
#pragma unroll
        for (int mt = 0; mt < 4; ++mt)
#pragma unroll
            for (int pt = 0; pt < 4; ++pt) {
                const f32x4 po = *(const f32x4*)&red[((mt * 4 + pt) * 64 + lane) * 4];
                const int p  = 16 * pt + m;
                const int sv = 64 * p + 16 * mt + quad * 4;
                const float4 z4 = *(const float4*)(zp1 + sv);
                float4 o4;
                o4.x = z4.x * (acc[mt][pt][0] + po[0]) * inv;
                o4.y = z4.y * (acc[mt][pt][1] + po[1]) * inv;
                o4.z = z4.z * (acc[mt][pt][2] + po[2]) * inv;
                o4.w = z4.w * (acc[mt][pt][3] + po[3]) * inv;
                *(float4*)(op + sv) = o4;
            }
    }
}

// ---------------- MFMA k_out: out[b][s][e] = mask*(sum_d u[b][d][s]*Wo[d][e] + bo[e]) ----------------
// 64 s-rows x 256 e per block, 4 waves (16 s each). A-frags gathered straight from
// global (per-lane d-strided scalars; 16-lane s-groups = full 64B lines, u read once).
// B = WoT hi/lo via the verified k_ff reg-dbuf LDS tile. 2-pass split.
__global__ __launch_bounds__(256, 2) void k_out(
    const float* __restrict__ u, const unsigned short* __restrict__ woth,
    const unsigned short* __restrict__ wotl, const float* __restrict__ bo,
    const int* __restrict__ pos, float* __restrict__ out)
{
    const int b   = blockIdx.y;
    const int s0  = blockIdx.x * 64;
    const int tid = threadIdx.x;
    const int wave = tid >> 6, lane = tid & 63;
    const int m16  = lane & 15, quad = lane >> 4;

    __shared__ __align__(16) unsigned short Bsh[16 * FF_LDB];
    __shared__ __align__(16) unsigned short Bsl[16 * FF_LDB];

    const int strow = tid >> 4;
    const int stks  = (tid & 15) * 8;

    const int sA = s0 + wave * 16 + m16;                 // this lane's A-row (s)
    const float* uA = u + (size_t)b * 256 * S_LEN + sA;  // index d via *S_LEN

    f32x4 acc[16];
#pragma unroll
    for (int nt = 0; nt < 16; ++nt)
#pragma unroll
        for (int e = 0; e < 4; ++e) acc[nt][e] = 0.f;

    uint4 pfh, pfl;
    {
        const size_t gi = (size_t)strow * 256 + stks;
        pfh = *(const uint4*)(woth + gi);
        pfl = *(const uint4*)(wotl + gi);
    }
    for (int kh = 0; kh < 2; ++kh) {
        short8 ah[4];
#pragma unroll
        for (int c4 = 0; c4 < 4; ++c4) {
            const int k0 = kh * 128 + c4 * 32 + quad * 8;
            float x[8];
#pragma unroll
            for (int j = 0; j < 8; ++j) x[j] = uA[(size_t)(k0 + j) * S_LEN];
            union { unsigned int w[4]; short8 s; } pk;
#pragma unroll
            for (int j = 0; j < 4; ++j)
                pk.w[j] = f2bf(x[2*j]) | (f2bf(x[2*j+1]) << 16);
            ah[c4] = pk.s;
        }
#pragma unroll
        for (int nt = 0; nt < 16; ++nt) {
            __syncthreads();
            *(uint4*)&Bsh[strow * FF_LDB + stks] = pfh;
            *(uint4*)&Bsl[strow * FF_LDB + stks] = pfl;
            if (!(kh == 1 && nt == 15)) {
                const int nt2 = (nt + 1) & 15;
                const int kh2 = kh + (nt == 15);
                const size_t gi = (size_t)(nt2 * 16 + strow) * 256 + kh2 * 128 + stks;
                pfh = *(const uint4*)(woth + gi);
                pfl = *(const uint4*)(wotl + gi);
            }
            __syncthreads();
#pragma unroll
            for (int c4 = 0; c4 < 4; ++c4) {
                const int br = m16 * FF_LDB + c4 * 32 + quad * 8;
                const short8 bh = *(const short8*)&Bsh[br];
                const short8 bl = *(const short8*)&Bsl[br];
                acc[nt] = __builtin_amdgcn_mfma_f32_16x16x32_bf16(ah[c4], bh, acc[nt], 0, 0, 0);
                acc[nt] = __builtin_amdgcn_mfma_f32_16x16x32_bf16(ah[c4], bl, acc[nt], 0, 0, 0);
            }
        }
    }

    // epilogue: +bo, *mask, store out[b][s][e]
    const int sBase = s0 + wave * 16 + quad * 4;
    const int4 p4 = *(const int4*)(pos + (size_t)b * S_LEN + sBase);
    float msk[4];
    msk[0] = (p4.x != -1) ? 1.f : 0.f;
    msk[1] = (p4.y != -1) ? 1.f : 0.f;
    msk[2] = (p4.z != -1) ? 1.f : 0.f;
    msk[3] = (p4.w != -1) ? 1.f : 0.f;
#pragma unroll
    for (int nt = 0; nt < 16; ++nt) {
        const int col = nt * 16 + m16;
        const float bb = bo[col];
#pragma unroll
        for (int e = 0; e < 4; ++e) {
            out[((size_t)b * S_LEN + sBase + e) * 256 + col] = (acc[nt][e] + bb) * msk[e];
        }
    }
}

extern "C" void kernel_launch(void* const* d_in, const int* in_sizes, int n_in,
                              void* d_out, int out_size, void* d_ws, size_t ws_size,
                              hipStream_t stream) {
    const float* emb = (const float*)d_in[0];
    const int*   pos = (const int*)  d_in[1];
    const float* Wp  = (const float*)d_in[2];
    const float* cw  = (const float*)d_in[3];
    const float* cb  = (const float*)d_in[4];
    const float* W1  = (const float*)d_in[5];
    const float* b1  = (const float*)d_in[6];
    const float* lg  = (const float*)d_in[7];
    const float* lb  = (const float*)d_in[8];
    const float* W2  = (const float*)d_in[9];
    const float* b2  = (const float*)d_in[10];
    const float* ffs = (const float*)d_in[11];
    const float* Wo  = (const float*)d_in[12];
    const float* bo  = (const float*)d_in[13];

    float* ws   = (float*)d_ws;
    float* minp = ws + OFF_MINP;
    float* wpt  = ws + OFF_WPT;
    unsigned short* wth = (unsigned short*)(ws + OFF_WTH);
    unsigned short* wtl = (unsigned short*)(ws + OFF_WTL);
    float* c    = ws + OFF_C;
    float* hh   = ws + OFF_HH;
    float* vb   = ws + OFF_V;
    float* ub   = ws + OFF_U;

    // weight splits carved from the head of vb (V region otherwise unused)
    unsigned short* w1th = (unsigned short*)vb;
    unsigned short* w1tl = w1th + 256 * 256;
    unsigned short* w2th = w1tl + 256 * 256;
    unsigned short* w2tl = w2th + 512 * 256;
    unsigned short* woth = w2tl + 512 * 256;
    unsigned short* wotl = woth + 256 * 256;

    k_minpos<<<dim3(8), dim3(256), 0, stream>>>(pos, minp);
    k_wpt<<<dim3(24, 8), dim3(256), 0, stream>>>(Wp, wpt);
    k_weff<<<dim3(768), dim3(256), 0, stream>>>(wpt, cw, wth, wtl);
    k_tsplit<<<dim3(8, 8), dim3(256), 0, stream>>>(W1, 256, 256, w1th, w1tl);
    k_tsplit<<<dim3(16, 8), dim3(256), 0, stream>>>(W2, 256, 512, w2th, w2tl);
    k_tsplit<<<dim3(8, 8), dim3(256), 0, stream>>>(Wo, 256, 256, woth, wotl);
    k_convgemm<<<dim3(32, 6, 8), dim3(256), 0, stream>>>(emb, pos, wth, wtl, cb, c);
    k_ff<<<dim3(64, 8), dim3(256), 0, stream>>>(emb, pos, minp, w1th, w1tl, b1, lg, lb, w2th, w2tl, b2, ffs, hh);
    // u = z1 * (F1 conv (z0 * (F0 conv zs[2])))  — fused, v stays on-chip
    k_conv2x<<<dim3(256, 8), dim3(128), 0, stream>>>(c, hh, ub);
    k_out<<<dim3(64, 8), dim3(256), 0, stream>>>(ub, woth, wotl, bo, pos, (float*)d_out);
}

// Round 11
// 430.968 us; speedup vs baseline: 1.4980x; 1.0830x over previous
//
#include <hip/hip_runtime.h>
#include <cstdint>

#define S_LEN 4096
#define D_DIM 256

// workspace layout (float offsets)
#define OFF_MINP 0
#define OFF_WPT  16
#define OFF_WTH  (OFF_WPT + 768*256)     // WeffT hi, 768x768 ushort = 294912 floats
#define OFF_WTL  (OFF_WTH + 294912)      // WeffT lo
#define OFF_C    (OFF_WTL + 294912)      // == old OFF_C, downstream unchanged
#define OFF_HH   (OFF_C + 8*768*4096)
#define OFF_V    (OFF_HH + 8*2*256*4096)
#define OFF_U    (OFF_V + 8*256*4096)

// Weight splits live at the head of the V region (consumed by k_ff / k_out; the V
// region is otherwise unused now that conv1+conv2 are fused and v never hits HBM).

typedef __attribute__((ext_vector_type(8))) short short8;
typedef __attribute__((ext_vector_type(4))) float f32x4;

__device__ __forceinline__ unsigned int f2bf(float x) {
    union { float f; unsigned int u; } v; v.f = x;
    unsigned int r = v.u + 0x7fffu + ((v.u >> 16) & 1u);   // RNE
    return r >> 16;
}
__device__ __forceinline__ float bf2f(unsigned int h) {
    union { unsigned int u; float f; } v; v.u = h << 16; return v.f;
}

// ---------------- min valid position per batch ----------------
__global__ __launch_bounds__(256) void k_minpos(const int* __restrict__ pos, float* __restrict__ minp)
{
    const int b = blockIdx.x;
    const int tid = threadIdx.x;
    int mn = 0x7fffffff;
    const int* p = pos + (size_t)b * S_LEN;
    for (int s = tid; s < S_LEN; s += 256) {
        const int v = p[s];
        if (v != -1) mn = min(mn, v);
    }
    __shared__ int red[256];
    red[tid] = mn;
    __syncthreads();
    for (int st = 128; st > 0; st >>= 1) {
        if (tid < st) red[tid] = min(red[tid], red[tid + st]);
        __syncthreads();
    }
    if (tid == 0) minp[b] = (float)red[0];
}

// ---------------- transpose W_proj (256x768) -> WpT (768x256) ----------------
__global__ __launch_bounds__(256) void k_wpt(const float* __restrict__ Wp, float* __restrict__ WpT)
{
    __shared__ float t[32][33];
    const int e0 = blockIdx.x * 32;   // 0..767
    const int d0 = blockIdx.y * 32;   // 0..255
    const int lx = threadIdx.x & 31, ly = threadIdx.x >> 5; // 32x8
#pragma unroll
    for (int q = 0; q < 4; ++q)
        t[ly + 8*q][lx] = Wp[(size_t)(d0 + ly + 8*q) * 768 + e0 + lx];
    __syncthreads();
#pragma unroll
    for (int q = 0; q < 4; ++q)
        WpT[(size_t)(e0 + ly + 8*q) * 256 + d0 + lx] = t[lx][ly + 8*q];
}

// ---------------- generic transpose + bf16 hi/lo split: W[K][N] -> out[N][K] ----------------
__global__ __launch_bounds__(256) void k_tsplit(const float* __restrict__ W, const int K, const int N,
                                                unsigned short* __restrict__ oh, unsigned short* __restrict__ ol)
{
    __shared__ float t[32][33];
    const int n0 = blockIdx.x * 32;
    const int k0 = blockIdx.y * 32;
    const int lx = threadIdx.x & 31, ly = threadIdx.x >> 5;
#pragma unroll
    for (int q = 0; q < 4; ++q)
        t[ly + 8*q][lx] = W[(size_t)(k0 + ly + 8*q) * N + n0 + lx];
    __syncthreads();
#pragma unroll
    for (int q = 0; q < 4; ++q) {
        const float v = t[lx][ly + 8*q];
        const unsigned int h = f2bf(v);
        oh[(size_t)(n0 + ly + 8*q) * K + k0 + lx] = (unsigned short)h;
        ol[(size_t)(n0 + ly + 8*q) * K + k0 + lx] = (unsigned short)f2bf(v - bf2f(h));
    }
}

// ---------------- WeffT[o][t*256+d] = sum_i WpT[g*256+i][d] * conv_w[o][i][t], split hi/lo bf16 ----------------
__global__ __launch_bounds__(256) void k_weff(const float* __restrict__ WpT, const float* __restrict__ cw,
                                              unsigned short* __restrict__ wth, unsigned short* __restrict__ wtl)
{
    const int o = blockIdx.x;       // 768
    const int d = threadIdx.x;      // 256
    const int g = o >> 8;
    __shared__ float cwrow[768];
    for (int i = threadIdx.x; i < 768; i += 256) cwrow[i] = cw[(size_t)o * 768 + i];
    __syncthreads();
    float a0 = 0.f, a1 = 0.f, a2 = 0.f;
    const float* wb = WpT + (size_t)(g * 256) * 256 + d;
#pragma unroll 4
    for (int i = 0; i < 256; ++i) {
        const float wv = wb[(size_t)i * 256];
        a0 += wv * cwrow[i*3+0];
        a1 += wv * cwrow[i*3+1];
        a2 += wv * cwrow[i*3+2];
    }
    const float av[3] = {a0, a1, a2};
#pragma unroll
    for (int t = 0; t < 3; ++t) {
        const unsigned int hb = f2bf(av[t]);
        const unsigned int lb = f2bf(av[t] - bf2f(hb));
        wth[(size_t)o * 768 + t * 256 + d] = (unsigned short)hb;
        wtl[(size_t)o * 768 + t * 256 + d] = (unsigned short)lb;
    }
}

// ---------------- MFMA conv-GEMM (verified: 128s x 128o, mt=2, 2-pass, reg-prefetch) ----------------
#define CG_LDA 40   // 32 + 8 pad (16B frag alignment preserved: 80B rows)
__global__ __launch_bounds__(256, 3) void k_convgemm(
    const float* __restrict__ emb, const int* __restrict__ pos,
    const unsigned short* __restrict__ wth, const unsigned short* __restrict__ wtl,
    const float* __restrict__ convb, float* __restrict__ c)
{
    const int b  = blockIdx.z;
    const int o0 = blockIdx.y * 128;
    const int s0 = blockIdx.x * 128;
    const int tid  = threadIdx.x;
    const int wave = tid >> 6, lane = tid & 63;
    const int m16  = lane & 15, quad = lane >> 4;

    __shared__ __align__(16) unsigned short As[130 * CG_LDA];
    __shared__ __align__(16) unsigned short Bh[128 * CG_LDA];
    __shared__ __align__(16) unsigned short Bl[128 * CG_LDA];

    const int rA = tid >> 1;
    const int cA = (tid & 1) * 16;
    const int srowA = s0 + rA - 1;
    const bool vA = (srowA >= 0 && srowA < S_LEN);
    const float* embA = emb + ((size_t)b * S_LEN + (vA ? srowA : 0)) * D_DIM + cA;
    const int rT = 128 + (tid >> 3);
    const int cT = (tid & 7) * 4;
    const int srowT = s0 + rT - 1;
    const bool vT = (tid < 16) && (srowT >= 0 && srowT < S_LEN);
    const float* embT = emb + ((size_t)b * S_LEN + ((tid < 16 && vT) ? srowT : 0)) * D_DIM + cT;

    const int rB0 = tid >> 2,        gB0 = (tid & 3) * 8;
    const int rB1 = 64 + (tid >> 2), gB1 = gB0;

    float4 apf[4]; float4 apfT;
    uint4 bph0, bpl0, bph1, bpl1;

#pragma unroll
    for (int q = 0; q < 4; ++q) apf[q] = vA ? *(const float4*)(embA + q * 4) : make_float4(0.f,0.f,0.f,0.f);
    apfT = vT ? *(const float4*)(embT) : make_float4(0.f,0.f,0.f,0.f);
    {
        const size_t gi0 = (size_t)(o0 + rB0) * 768 + gB0;
        const size_t gi1 = (size_t)(o0 + rB1) * 768 + gB1;
        bph0 = *(const uint4*)(wth + gi0); bpl0 = *(const uint4*)(wtl + gi0);
        bph1 = *(const uint4*)(wth + gi1); bpl1 = *(const uint4*)(wtl + gi1);
    }

    f32x4 acc[2][8];
#pragma unroll
    for (int mt = 0; mt < 2; ++mt)
#pragma unroll
        for (int nt = 0; nt < 8; ++nt)
#pragma unroll
            for (int e = 0; e < 4; ++e) acc[mt][nt][e] = 0.f;

    for (int c8 = 0; c8 < 8; ++c8) {
        for (int t = 0; t < 3; ++t) {
            __syncthreads();
            if (t == 0) {
#pragma unroll
                for (int q = 0; q < 4; ++q) {
                    const float4 v = apf[q];
                    uint2 hp;
                    hp.x = f2bf(v.x) | (f2bf(v.y) << 16);
                    hp.y = f2bf(v.z) | (f2bf(v.w) << 16);
                    *(uint2*)&As[rA * CG_LDA + cA + q * 4] = hp;
                }
                if (tid < 16) {
                    const float4 v = apfT;
                    uint2 hp;
                    hp.x = f2bf(v.x) | (f2bf(v.y) << 16);
                    hp.y = f2bf(v.z) | (f2bf(v.w) << 16);
                    *(uint2*)&As[rT * CG_LDA + cT] = hp;
                }
                if (c8 < 7) {
                    const int base = (c8 + 1) * 32;
#pragma unroll
                    for (int q = 0; q < 4; ++q) apf[q] = vA ? *(const float4*)(embA + base + q * 4) : make_float4(0.f,0.f,0.f,0.f);
                    apfT = vT ? *(const float4*)(embT + base) : make_float4(0.f,0.f,0.f,0.f);
                }
            }
            *(uint4*)&Bh[rB0 * CG_LDA + gB0] = bph0;
            *(uint4*)&Bl[rB0 * CG_LDA + gB0] = bpl0;
            *(uint4*)&Bh[rB1 * CG_LDA + gB1] = bph1;
            *(uint4*)&Bl[rB1 * CG_LDA + gB1] = bpl1;
            if (!(c8 == 7 && t == 2)) {
                const int t2  = (t == 2) ? 0 : (t + 1);
                const int c82 = c8 + (t == 2);
                const int kbase = t2 * 256 + c82 * 32;
                const size_t gi0 = (size_t)(o0 + rB0) * 768 + kbase + gB0;
                const size_t gi1 = (size_t)(o0 + rB1) * 768 + kbase + gB1;
                bph0 = *(const uint4*)(wth + gi0); bpl0 = *(const uint4*)(wtl + gi0);
                bph1 = *(const uint4*)(wth + gi1); bpl1 = *(const uint4*)(wtl + gi1);
            }
            __syncthreads();
            short8 ah[2];
#pragma unroll
            for (int mt = 0; mt < 2; ++mt) {
                const int ar = (wave * 32 + mt * 16 + m16 + t) * CG_LDA + quad * 8;
                ah[mt] = *(const short8*)&As[ar];
            }
#pragma unroll
            for (int nt = 0; nt < 8; ++nt) {
                const int br = (nt * 16 + m16) * CG_LDA + quad * 8;
                const short8 bh = *(const short8*)&Bh[br];
                const short8 bl = *(const short8*)&Bl[br];
#pragma unroll
                for (int mt = 0; mt < 2; ++mt) {
                    acc[mt][nt] = __builtin_amdgcn_mfma_f32_16x16x32_bf16(ah[mt], bh, acc[mt][nt], 0, 0, 0);
                    acc[mt][nt] = __builtin_amdgcn_mfma_f32_16x16x32_bf16(ah[mt], bl, acc[mt][nt], 0, 0, 0);
                }
            }
        }
    }
    __syncthreads();

    float msk[2][4];
#pragma unroll
    for (int mt = 0; mt < 2; ++mt) {
        const int s = s0 + wave * 32 + mt * 16 + quad * 4;
        const int4 p4 = *(const int4*)(pos + (size_t)b * S_LEN + s);
        msk[mt][0] = (p4.x != -1) ? 1.f : 0.f;
        msk[mt][1] = (p4.y != -1) ? 1.f : 0.f;
        msk[mt][2] = (p4.z != -1) ? 1.f : 0.f;
        msk[mt][3] = (p4.w != -1) ? 1.f : 0.f;
    }
#pragma unroll
    for (int nt = 0; nt < 8; ++nt) {
        const int o = o0 + nt * 16 + m16;
        const float cb = convb[o];
#pragma unroll
        for (int mt = 0; mt < 2; ++mt) {
            const int s = s0 + wave * 32 + mt * 16 + quad * 4;
            float4 r;
            r.x = (acc[mt][nt][0] + cb) * msk[mt][0];
            r.y = (acc[mt][nt][1] + cb) * msk[mt][1];
            r.z = (acc[mt][nt][2] + cb) * msk[mt][2];
            r.w = (acc[mt][nt][3] + cb) * msk[mt][3];
            *(float4*)(c + ((size_t)(b * 768 + o)) * S_LEN + s) = r;
        }
    }
}

// ---------------- RoPE + FF (MFMA, LDS-staged B, 2-pass split: T/H plain bf16, W hi/lo) ----------------
#define FF_LDA 264   // 256 + 8 ushort pad
#define FF_LDB 136   // 128 + 8 pad
__global__ __launch_bounds__(256, 2) void k_ff(
    const float* __restrict__ emb, const int* __restrict__ pos, const float* __restrict__ minp,
    const unsigned short* __restrict__ w1th, const unsigned short* __restrict__ w1tl,
    const float* __restrict__ b1,
    const float* __restrict__ lng, const float* __restrict__ lnb,
    const unsigned short* __restrict__ w2th, const unsigned short* __restrict__ w2tl,
    const float* __restrict__ b2, const float* __restrict__ ffs, float* __restrict__ hh)
{
    const int b   = blockIdx.y;
    const int s0  = blockIdx.x * 64;
    const int tid = threadIdx.x;
    const int wave = tid >> 6, lane = tid & 63;
    const int m16  = lane & 15, quad = lane >> 4;

    __shared__ __align__(16) unsigned short Th[64 * FF_LDA];
    __shared__ __align__(16) unsigned short Bsh[16 * FF_LDB];
    __shared__ __align__(16) unsigned short Bsl[16 * FF_LDB];
    __shared__ float th_s[128];

    if (tid < 128) th_s[tid] = expf(-(float)tid * 0.07195578415606394f);
    __syncthreads();

    {
        const int r    = tid >> 2;            // 0..63
        const int col0 = (tid & 3) * 64;
        const int s    = s0 + r;
        const int p    = pos[(size_t)b * S_LEN + s];
        const float adj = (p == -1) ? -1.f : ((float)p - minp[b]);
        const float* ep = emb + ((size_t)b * S_LEN + s) * D_DIM;
#pragma unroll
        for (int p8 = 0; p8 < 8; ++p8) {
            const int cbase = col0 + p8 * 8;
            const float4 va = *(const float4*)(ep + cbase);
            const float4 vb4 = *(const float4*)(ep + cbase + 4);
            const float x[8] = {va.x, va.y, va.z, va.w, vb4.x, vb4.y, vb4.z, vb4.w};
            unsigned int uh[4];
#pragma unroll
            for (int jj = 0; jj < 4; ++jj) {
                const int j = (cbase >> 1) + jj;
                const float theta = th_s[j];
                float sn, cs;
                sincosf(adj * theta, &sn, &cs);
                const float x1 = x[2*jj], x2 = x[2*jj+1];
                const float r1 = x1 * cs - x2 * sn;
                const float r2 = x1 * sn + x2 * cs;
                uh[jj] = f2bf(r1) | (f2bf(r2) << 16);
            }
            uint4 wh;
            wh.x = uh[0]; wh.y = uh[1]; wh.z = uh[2]; wh.w = uh[3];
            *(uint4*)&Th[r * FF_LDA + cbase] = wh;
        }
    }
    __syncthreads();

    const int rowA  = wave * 16 + m16;
    const int strow = tid >> 4;
    const int stks  = (tid & 15) * 8;

    f32x4 acc1[16];
#pragma unroll
    for (int nt = 0; nt < 16; ++nt)
#pragma unroll
        for (int e = 0; e < 4; ++e) acc1[nt][e] = 0.f;

    uint4 pfh, pfl;
    {
        const size_t gi = (size_t)strow * 256 + stks;
        pfh = *(const uint4*)(w1th + gi);
        pfl = *(const uint4*)(w1tl + gi);
    }
    for (int kh = 0; kh < 2; ++kh) {
        short8 a1h[4];
#pragma unroll
        for (int c4 = 0; c4 < 4; ++c4) {
            const int ar = rowA * FF_LDA + kh * 128 + c4 * 32 + quad * 8;
            a1h[c4] = *(const short8*)&Th[ar];
        }
#pragma unroll
        for (int nt = 0; nt < 16; ++nt) {
            __syncthreads();
            *(uint4*)&Bsh[strow * FF_LDB + stks] = pfh;
            *(uint4*)&Bsl[strow * FF_LDB + stks] = pfl;
            if (!(kh == 1 && nt == 15)) {
                const int nt2 = (nt + 1) & 15;
                const int kh2 = kh + (nt == 15);
                const size_t gi = (size_t)(nt2 * 16 + strow) * 256 + kh2 * 128 + stks;
                pfh = *(const uint4*)(w1th + gi);
                pfl = *(const uint4*)(w1tl + gi);
            }
            __syncthreads();
#pragma unroll
            for (int c4 = 0; c4 < 4; ++c4) {
                const int br = m16 * FF_LDB + c4 * 32 + quad * 8;
                const short8 bh = *(const short8*)&Bsh[br];
                const short8 bl = *(const short8*)&Bsl[br];
                acc1[nt] = __builtin_amdgcn_mfma_f32_16x16x32_bf16(a1h[c4], bh, acc1[nt], 0, 0, 0);
                acc1[nt] = __builtin_amdgcn_mfma_f32_16x16x32_bf16(a1h[c4], bl, acc1[nt], 0, 0, 0);
            }
        }
    }

    float sume[4] = {0.f, 0.f, 0.f, 0.f}, sumq[4] = {0.f, 0.f, 0.f, 0.f};
#pragma unroll
    for (int nt = 0; nt < 16; ++nt) {
        const float bb = b1[nt * 16 + m16];
#pragma unroll
        for (int e = 0; e < 4; ++e) {
            const float v = acc1[nt][e] + bb;
            acc1[nt][e] = v;
            sume[e] += v;
            sumq[e] += v * v;
        }
    }
#pragma unroll
    for (int e = 0; e < 4; ++e) {
#pragma unroll
        for (int off = 1; off < 16; off <<= 1) {
            sume[e] += __shfl_xor(sume[e], off, 64);
            sumq[e] += __shfl_xor(sumq[e], off, 64);
        }
    }
    float mu[4], rs[4];
#pragma unroll
    for (int e = 0; e < 4; ++e) {
        mu[e] = sume[e] * (1.f / 256.f);
        const float var = sumq[e] * (1.f / 256.f) - mu[e] * mu[e];
        rs[e] = rsqrtf(var + 1e-5f);
    }

    {
        const size_t gi = (size_t)strow * 256 + stks;
        pfh = *(const uint4*)(w2th + gi);
        pfl = *(const uint4*)(w2tl + gi);
    }

    __syncthreads();
#pragma unroll
    for (int nt = 0; nt < 16; ++nt) {
        const int col = nt * 16 + m16;
        const float g  = lng[col];
        const float be = lnb[col];
#pragma unroll
        for (int e = 0; e < 4; ++e) {
            const float h  = (acc1[nt][e] - mu[e]) * rs[e] * g + be;
            const float hg = 0.5f * h * (1.f + erff(h * 0.7071067811865475f));
            const int li = (wave * 16 + quad * 4 + e) * FF_LDA + col;
            Th[li] = (unsigned short)f2bf(hg);
        }
    }
    __syncthreads();

    f32x4 acc2[32];
#pragma unroll
    for (int nt = 0; nt < 32; ++nt)
#pragma unroll
        for (int e = 0; e < 4; ++e) acc2[nt][e] = 0.f;

    for (int kh = 0; kh < 2; ++kh) {
        short8 a2h[4];
#pragma unroll
        for (int c4 = 0; c4 < 4; ++c4) {
            const int ar = rowA * FF_LDA + kh * 128 + c4 * 32 + quad * 8;
            a2h[c4] = *(const short8*)&Th[ar];
        }
#pragma unroll
        for (int nt = 0; nt < 32; ++nt) {
            __syncthreads();
            *(uint4*)&Bsh[strow * FF_LDB + stks] = pfh;
            *(uint4*)&Bsl[strow * FF_LDB + stks] = pfl;
            if (!(kh == 1 && nt == 31)) {
                const int nt2 = (nt + 1) & 31;
                const int kh2 = kh + (nt == 31);
                const size_t gi = (size_t)(nt2 * 16 + strow) * 256 + kh2 * 128 + stks;
                pfh = *(const uint4*)(w2th + gi);
                pfl = *(const uint4*)(w2tl + gi);
            }
            __syncthreads();
#pragma unroll
            for (int c4 = 0; c4 < 4; ++c4) {
                const int br = m16 * FF_LDB + c4 * 32 + quad * 8;
                const short8 bh = *(const short8*)&Bsh[br];
                const short8 bl = *(const short8*)&Bsl[br];
                acc2[nt] = __builtin_amdgcn_mfma_f32_16x16x32_bf16(a2h[c4], bh, acc2[nt], 0, 0, 0);
                acc2[nt] = __builtin_amdgcn_mfma_f32_16x16x32_bf16(a2h[c4], bl, acc2[nt], 0, 0, 0);
            }
        }
    }

    float sm[2][4] = {{0.f,0.f,0.f,0.f},{0.f,0.f,0.f,0.f}};
#pragma unroll
    for (int nt = 0; nt < 32; ++nt) {
        const int col = nt * 16 + m16;
        const float bb = b2[col];
        const float fs = ffs[col];
#pragma unroll
        for (int e = 0; e < 4; ++e) {
            const float v = (acc2[nt][e] + bb) * fs;
            acc2[nt][e] = v;
            sm[nt >> 4][e] += fabsf(v);
        }
    }
#pragma unroll
    for (int i = 0; i < 2; ++i)
#pragma unroll
        for (int e = 0; e < 4; ++e) {
#pragma unroll
            for (int off = 1; off < 16; off <<= 1)
                sm[i][e] += __shfl_xor(sm[i][e], off, 64);
        }
#pragma unroll
    for (int nt = 0; nt < 32; ++nt) {
        const int i = nt >> 4;
        const int d = (nt & 15) * 16 + m16;
        float4 o4;
        o4.x = acc2[nt][0] / (sm[i][0] + 1e-8f);
        o4.y = acc2[nt][1] / (sm[i][1] + 1e-8f);
        o4.z = acc2[nt][2] / (sm[i][2] + 1e-8f);
        o4.w = acc2[nt][3] / (sm[i][3] + 1e-8f);
        *(float4*)(hh + ((size_t)((b * 2 + i) * 256 + d)) * S_LEN + s0 + wave * 16 + quad * 4) = o4;
    }
}

// ---------------- FUSED double blocked-Toeplitz causal long conv (R8-verified loop) ----------------
// v kept on-chip: conv1's reduced result is multiplied by z0, rounded to bf16, and
// written straight into xs (same xsw layout conv2's staging would have produced —
// bit-identical to the old vb-roundtrip). F1 prefetched to regs at start.
#define XS_PAD   960
#define XS_ELEMS 5056
#define FRX_WORDS 4160
__device__ __forceinline__ int xsw(int blk) { return blk ^ ((blk >> 3) & 7); }

#define CONV_ACCUM_LOOP(ACC)                                                         \
    for (int i = 0; i < 32; ++i) {                                                   \
        const int r = 2 * i + wid;                                                   \
        const int ea_r = eA_base - 64 * r;                                           \
        short8 afr[4][2];                                                            \
        _Pragma("unroll")                                                            \
        for (int mt = 0; mt < 4; ++mt)                                               \
            _Pragma("unroll")                                                        \
            for (int kc = 0; kc < 2; ++kc) {                                         \
                const int e = ea_r - 16 * mt + 32 * kc;                              \
                union { unsigned int u[4]; short8 s; } cvt;                          \
                cvt.u[0] = frx[e];                                                   \
                cvt.u[1] = frx[e + 2];                                               \
                cvt.u[2] = frx[e + 4];                                               \
                cvt.u[3] = frx[e + 6];                                               \
                afr[mt][kc] = cvt.s;                                                 \
            }                                                                        \
        const int ptmin = r >> 4;                                                    \
        const int ob_r = oB_base - 64 * r;                                           \
        _Pragma("unroll")                                                            \
        for (int pt = 0; pt < 4; ++pt) {                                             \
            if (pt >= ptmin) {                                                       \
                const int o0 = ob_r + 1024 * pt;                                     \
                const short8 bfr0 = *(const short8*)(xs + xsw(o0 >> 3) * 8);         \
                const short8 bfr1 = *(const short8*)(xs + xsw((o0 + 32) >> 3) * 8);  \
                _Pragma("unroll")                                                    \
                for (int mt = 0; mt < 4; ++mt) {                                     \
                    ACC[mt][pt] = __builtin_amdgcn_mfma_f32_16x16x32_bf16(afr[mt][0], bfr0, ACC[mt][pt], 0, 0, 0); \
                    ACC[mt][pt] = __builtin_amdgcn_mfma_f32_16x16x32_bf16(afr[mt][1], bfr1, ACC[mt][pt], 0, 0, 0); \
                }                                                                    \
            }                                                                        \
        }                                                                            \
    }

__global__ __launch_bounds__(128) void k_conv2x(
    const float* __restrict__ cbuf, const float* __restrict__ hh,
    float* __restrict__ outb)
{
    const int d = blockIdx.x;
    const int b = blockIdx.y;
    const int tid  = threadIdx.x;
    const int lane = tid & 63;
    const int wid  = tid >> 6;
    const float* xp  = cbuf + ((size_t)(b * 768 + 512 + d)) * S_LEN;   // zs[2]
    const float* fp0 = hh   + ((size_t)((b * 2 + 0) * 256 + d)) * S_LEN;
    const float* fp1 = hh   + ((size_t)((b * 2 + 1) * 256 + d)) * S_LEN;
    const float* zp0 = cbuf + ((size_t)(b * 768 +   0 + d)) * S_LEN;   // zs[0]
    const float* zp1 = cbuf + ((size_t)(b * 768 + 256 + d)) * S_LEN;   // zs[1]
    float* op = outb + ((size_t)(b * 256 + d)) * S_LEN;

    __shared__ __align__(16) unsigned short xs[XS_ELEMS];
    __shared__ __align__(16) unsigned int   frx[FRX_WORDS];

    // prefetch F1 into regs (consumed after conv1; latency hides under conv1 compute)
    float4 f1pf[8];
#pragma unroll
    for (int it = 0; it < 8; ++it)
        f1pf[it] = *(const float4*)(fp1 + (it * 128 + tid) * 4);

    // stage xs <- x (bf16), frx <- F0
    {
        for (int blk = tid; blk < 120; blk += 128) {
            int4 z; z.x = 0; z.y = 0; z.z = 0; z.w = 0;
            *(int4*)(xs + xsw(blk) * 8) = z;
        }
#pragma unroll
        for (int it = 0; it < 4; ++it) {
            const int idx = it * 128 + tid;
            const int j = idx * 8;
            const float4 v0 = *(const float4*)(xp + j);
            const float4 v1 = *(const float4*)(xp + j + 4);
            int4 w;
            w.x = (int)(f2bf(v0.x) | (f2bf(v0.y) << 16));
            w.y = (int)(f2bf(v0.z) | (f2bf(v0.w) << 16));
            w.z = (int)(f2bf(v1.x) | (f2bf(v1.y) << 16));
            w.w = (int)(f2bf(v1.z) | (f2bf(v1.w) << 16));
            *(int4*)(xs + xsw(120 + idx) * 8) = w;
        }
    }
    {
        if (tid < 64) frx[4096 + tid] = 0u;
        if (tid == 0) frx[4095] = f2bf(fp0[0]);
#pragma unroll
        for (int it = 0; it < 8; ++it) {
            const int j = (it * 128 + tid) * 4;
            const float4 v = *(const float4*)(fp0 + j);
            const float f4 = (j + 4 < S_LEN) ? fp0[j + 4] : 0.f;
            frx[4094 - j] = f2bf(v.y) | (f2bf(v.x) << 16);
            frx[4093 - j] = f2bf(v.z) | (f2bf(v.y) << 16);
            frx[4092 - j] = f2bf(v.w) | (f2bf(v.z) << 16);
            if (j < 4092) frx[4091 - j] = f2bf(f4) | (f2bf(v.w) << 16);
        }
    }
    __syncthreads();

    const int m    = lane & 15;
    const int quad = lane >> 4;
    const int eA_base = 4095 - m + quad * 8;
    const int oB_base = XS_PAD + 64 * m + quad * 8;
    const float inv = 1.f / 8192.f;
    float* red = (float*)frx;   // 16 slots * 64 lanes * 16B = 16384B <= 16640B

    f32x4 acc[4][4];
#pragma unroll
    for (int mt = 0; mt < 4; ++mt)
#pragma unroll
        for (int pt = 0; pt < 4; ++pt)
#pragma unroll
            for (int e = 0; e < 4; ++e) acc[mt][pt][e] = 0.f;

    // ---- conv1 ----
    CONV_ACCUM_LOOP(acc)

    __syncthreads();
    if (wid == 1) {
#pragma unroll
        for (int mt = 0; mt < 4; ++mt)
#pragma unroll
            for (int pt = 0; pt < 4; ++pt)
                *(f32x4*)&red[((mt * 4 + pt) * 64 + lane) * 4] = acc[mt][pt];
    }
    __syncthreads();
    // wave0: v = z0 * (acc+partial) * inv, round to bf16, write into xs payload
    if (wid == 0) {
#pragma unroll
        for (int mt = 0; mt < 4; ++mt)
#pragma unroll
            for (int pt = 0; pt < 4; ++pt) {
                const f32x4 po = *(const f32x4*)&red[((mt * 4 + pt) * 64 + lane) * 4];
                const int p  = 16 * pt + m;
                const int sv = 64 * p + 16 * mt + quad * 4;
                const float4 z4 = *(const float4*)(zp0 + sv);
                const float v0 = z4.x * (acc[mt][pt][0] + po[0]) * inv;
                const float v1 = z4.y * (acc[mt][pt][1] + po[1]) * inv;
                const float v2 = z4.z * (acc[mt][pt][2] + po[2]) * inv;
                const float v3 = z4.w * (acc[mt][pt][3] + po[3]) * inv;
                uint2 hp;
                hp.x = f2bf(v0) | (f2bf(v1) << 16);
                hp.y = f2bf(v2) | (f2bf(v3) << 16);
                *(uint2*)(xs + xsw(120 + (sv >> 3)) * 8 + (sv & 7)) = hp;
            }
    }
    __syncthreads();   // wave0's red-reads + xs-writes done; frx free for rebuild

    // ---- rebuild frx <- F1 (from prefetch regs; f4 scalar from global, L2-warm) ----
    {
        if (tid < 64) frx[4096 + tid] = 0u;
        if (tid == 0) frx[4095] = f2bf(fp1[0]);
#pragma unroll
        for (int it = 0; it < 8; ++it) {
            const int j = (it * 128 + tid) * 4;
            const float4 v = f1pf[it];
            const float f4 = (j + 4 < S_LEN) ? fp1[j + 4] : 0.f;
            frx[4094 - j] = f2bf(v.y) | (f2bf(v.x) << 16);
            frx[4093 - j] = f2bf(v.z) | (f2bf(v.y) << 16);
            frx[4092 - j] = f2bf(v.w) | (f2bf(v.z) << 16);
            if (j < 4092) frx[4091 - j] = f2bf(f4) | (f2bf(v.w) << 16);
        }
    }
#pragma unroll
    for (int mt = 0; mt < 4; ++mt)
#pragma unroll
        for (int pt = 0; pt < 4; ++pt)
#pragma unroll
            for (int e = 0; e < 4; ++e) acc[mt][pt][e] = 0.f;
    __syncthreads();

    // ---- conv2 ----
    CONV_ACCUM_LOOP(acc)

    __syncthreads();
    if (wid == 1) {
#pragma unroll
        for (int mt = 0; mt < 4; ++mt)
#pragma unroll
            for (int pt = 0; pt < 4; ++pt)
                *(f32x4*)&red[((mt * 4 + pt) * 64 + lane) * 4] = acc[mt][pt];
    }
    __syncthreads();
    if (wid == 0) {
#pragma unroll
        for (int mt = 0; mt < 4; ++mt)
#pragma unroll
            for (int pt = 0; pt < 4; ++pt) {
                const f32x4 po = *(const f32x4*)&red[((mt * 4 + pt) * 64 + lane) * 4];
                const int p  = 16 * pt + m;
                const int sv = 64 * p + 16 * mt + quad * 4;
                const float4 z4 = *(const float4*)(zp1 + sv);
                float4 o4;
                o4.x = z4.x * (acc[mt][pt][0] + po[0]) * inv;
                o4.y = z4.y * (acc[mt][pt][1] + po[1]) * inv;
                o4.z = z4.z * (acc[mt][pt][2] + po[2]) * inv;
                o4.w = z4.w * (acc[mt][pt][3] + po[3]) * inv;
                *(float4*)(op + sv) = o4;
            }
    }
}

// ---------------- MFMA k_out: out[b][s][e] = mask*(sum_d u[b][d][s]*Wo[d][e] + bo[e]) ----------------
__global__ __launch_bounds__(256, 2) void k_out(
    const float* __restrict__ u, const unsigned short* __restrict__ woth,
    const unsigned short* __restrict__ wotl, const float* __restrict__ bo,
    const int* __restrict__ pos, float* __restrict__ out)
{
    const int b   = blockIdx.y;
    const int s0  = blockIdx.x * 64;
    const int tid = threadIdx.x;
    const int wave = tid >> 6, lane = tid & 63;
    const int m16  = lane & 15, quad = lane >> 4;

    __shared__ __align__(16) unsigned short Bsh[16 * FF_LDB];
    __shared__ __align__(16) unsigned short Bsl[16 * FF_LDB];

    const int strow = tid >> 4;
    const int stks  = (tid & 15) * 8;

    const int sA = s0 + wave * 16 + m16;                 // this lane's A-row (s)
    const float* uA = u + (size_t)b * 256 * S_LEN + sA;  // index d via *S_LEN

    f32x4 acc[16];
#pragma unroll
    for (int nt = 0; nt < 16; ++nt)
#pragma unroll
        for (int e = 0; e < 4; ++e) acc[nt][e] = 0.f;

    uint4 pfh, pfl;
    {
        const size_t gi = (size_t)strow * 256 + stks;
        pfh = *(const uint4*)(woth + gi);
        pfl = *(const uint4*)(wotl + gi);
    }
    for (int kh = 0; kh < 2; ++kh) {
        short8 ah[4];
#pragma unroll
        for (int c4 = 0; c4 < 4; ++c4) {
            const int k0 = kh * 128 + c4 * 32 + quad * 8;
            float x[8];
#pragma unroll
            for (int j = 0; j < 8; ++j) x[j] = uA[(size_t)(k0 + j) * S_LEN];
            union { unsigned int w[4]; short8 s; } pk;
#pragma unroll
            for (int j = 0; j < 4; ++j)
                pk.w[j] = f2bf(x[2*j]) | (f2bf(x[2*j+1]) << 16);
            ah[c4] = pk.s;
        }
#pragma unroll
        for (int nt = 0; nt < 16; ++nt) {
            __syncthreads();
            *(uint4*)&Bsh[strow * FF_LDB + stks] = pfh;
            *(uint4*)&Bsl[strow * FF_LDB + stks] = pfl;
            if (!(kh == 1 && nt == 15)) {
                const int nt2 = (nt + 1) & 15;
                const int kh2 = kh + (nt == 15);
                const size_t gi = (size_t)(nt2 * 16 + strow) * 256 + kh2 * 128 + stks;
                pfh = *(const uint4*)(woth + gi);
                pfl = *(const uint4*)(wotl + gi);
            }
            __syncthreads();
#pragma unroll
            for (int c4 = 0; c4 < 4; ++c4) {
                const int br = m16 * FF_LDB + c4 * 32 + quad * 8;
                const short8 bh = *(const short8*)&Bsh[br];
                const short8 bl = *(const short8*)&Bsl[br];
                acc[nt] = __builtin_amdgcn_mfma_f32_16x16x32_bf16(ah[c4], bh, acc[nt], 0, 0, 0);
                acc[nt] = __builtin_amdgcn_mfma_f32_16x16x32_bf16(ah[c4], bl, acc[nt], 0, 0, 0);
            }
        }
    }

    // epilogue: +bo, *mask, store out[b][s][e]
    const int sBase = s0 + wave * 16 + quad * 4;
    const int4 p4 = *(const int4*)(pos + (size_t)b * S_LEN + sBase);
    float msk[4];
    msk[0] = (p4.x != -1) ? 1.f : 0.f;
    msk[1] = (p4.y != -1) ? 1.f : 0.f;
    msk[2] = (p4.z != -1) ? 1.f : 0.f;
    msk[3] = (p4.w != -1) ? 1.f : 0.f;
#pragma unroll
    for (int nt = 0; nt < 16; ++nt) {
        const int col = nt * 16 + m16;
        const float bb = bo[col];
#pragma unroll
        for (int e = 0; e < 4; ++e) {
            out[((size_t)b * S_LEN + sBase + e) * 256 + col] = (acc[nt][e] + bb) * msk[e];
        }
    }
}

extern "C" void kernel_launch(void* const* d_in, const int* in_sizes, int n_in,
                              void* d_out, int out_size, void* d_ws, size_t ws_size,
                              hipStream_t stream) {
    const float* emb = (const float*)d_in[0];
    const int*   pos = (const int*)  d_in[1];
    const float* Wp  = (const float*)d_in[2];
    const float* cw  = (const float*)d_in[3];
    const float* cb  = (const float*)d_in[4];
    const float* W1  = (const float*)d_in[5];
    const float* b1  = (const float*)d_in[6];
    const float* lg  = (const float*)d_in[7];
    const float* lb  = (const float*)d_in[8];
    const float* W2  = (const float*)d_in[9];
    const float* b2  = (const float*)d_in[10];
    const float* ffs = (const float*)d_in[11];
    const float* Wo  = (const float*)d_in[12];
    const float* bo  = (const float*)d_in[13];

    float* ws   = (float*)d_ws;
    float* minp = ws + OFF_MINP;
    float* wpt  = ws + OFF_WPT;
    unsigned short* wth = (unsigned short*)(ws + OFF_WTH);
    unsigned short* wtl = (unsigned short*)(ws + OFF_WTL);
    float* c    = ws + OFF_C;
    float* hh   = ws + OFF_HH;
    float* vb   = ws + OFF_V;
    float* ub   = ws + OFF_U;

    // weight splits carved from the head of vb (V region otherwise unused)
    unsigned short* w1th = (unsigned short*)vb;
    unsigned short* w1tl = w1th + 256 * 256;
    unsigned short* w2th = w1tl + 256 * 256;
    unsigned short* w2tl = w2th + 512 * 256;
    unsigned short* woth = w2tl + 512 * 256;
    unsigned short* wotl = woth + 256 * 256;

    k_minpos<<<dim3(8), dim3(256), 0, stream>>>(pos, minp);
    k_wpt<<<dim3(24, 8), dim3(256), 0, stream>>>(Wp, wpt);
    k_weff<<<dim3(768), dim3(256), 0, stream>>>(wpt, cw, wth, wtl);
    k_tsplit<<<dim3(8, 8), dim3(256), 0, stream>>>(W1, 256, 256, w1th, w1tl);
    k_tsplit<<<dim3(16, 8), dim3(256), 0, stream>>>(W2, 256, 512, w2th, w2tl);
    k_tsplit<<<dim3(8, 8), dim3(256), 0, stream>>>(Wo, 256, 256, woth, wotl);
    k_convgemm<<<dim3(32, 6, 8), dim3(256), 0, stream>>>(emb, pos, wth, wtl, cb, c);
    k_ff<<<dim3(64, 8), dim3(256), 0, stream>>>(emb, pos, minp, w1th, w1tl, b1, lg, lb, w2th, w2tl, b2, ffs, hh);
    // u = z1 * (F1 conv (z0 * (F0 conv zs[2])))  — fused, v stays on-chip
    k_conv2x<<<dim3(256, 8), dim3(128), 0, stream>>>(c, hh, ub);
    k_out<<<dim3(64, 8), dim3(256), 0, stream>>>(ub, woth, wotl, bo, pos, (float*)d_out);
}